// Round 16
// baseline (486.240 us; speedup 1.0000x reference)
//
#include <hip/hip_runtime.h>

#define B_ 2
#define C_ 8
#define F_ 256
#define W_ 512
#define H_ 8
#define FW_ (F_*W_)        // 131072
#define CFW_ (C_*FW_)      // 1048576 = one batch of (C,F,W)
#define OBS_ (2*CFW_)      // out batch stride (B,16,F,W)

typedef unsigned short u16;

__device__ __forceinline__ u16 f2bf(float f){
  unsigned u = __float_as_uint(f);
  u += 0x7fffu + ((u>>16)&1u);
  return (u16)(u>>16);
}
__device__ __forceinline__ float bf2f(u16 u){
  return __uint_as_float((unsigned)u<<16);
}

typedef __attribute__((ext_vector_type(8))) short bf16x8;
typedef __attribute__((ext_vector_type(4))) float f32x4;

// ---------------- init: both halves of out = x ----------------
__global__ __launch_bounds__(256)
void init_out(const float* __restrict__ x, float* __restrict__ out){
  int i = blockIdx.x*256 + threadIdx.x;              // 2M
  int b = i >> 20;
  int r = i & (CFW_-1);
  float v = x[i];
  out[(size_t)b*OBS_ + r] = v;
  out[(size_t)b*OBS_ + CFW_ + r] = v;
}

__global__ void put_val(float* o, float v){ o[0] = v; }

// ---------------- bulk f32 -> bf16 conversion (4 weight arrays) --------------
__global__ __launch_bounds__(256)
void cvt4(const float* __restrict__ s0, const float* __restrict__ s1,
          const float* __restrict__ s2, const float* __restrict__ s3,
          u16* __restrict__ d0, u16* __restrict__ d1, u16* __restrict__ d2,
          u16* __restrict__ d3){
  int which = blockIdx.y;
  const float* s = which==0 ? s0 : which==1 ? s1 : which==2 ? s2 : s3;
  u16* d        = which==0 ? d0 : which==1 ? d1 : which==2 ? d2 : d3;
  int i = (blockIdx.x*256 + threadIdx.x)*4;          // 2048 blocks x 1024 elems
  float4 v = *(const float4*)(s + i);
  ushort4 o;
  o.x = f2bf(v.x); o.y = f2bf(v.y); o.z = f2bf(v.z); o.w = f2bf(v.w);
  *(ushort4*)(d + i) = o;
}

// ---------------- skip -> skip^T bf16 ([b][c][w][f]) via LDS 64x64 tile ------
// grid (8 w-tiles, 4 f-tiles, 16 = b*8+c), block 256
__global__ __launch_bounds__(256)
void cvtT(const float* __restrict__ src, u16* __restrict__ dst){
  __shared__ float Tin[64][65];
  int w0 = blockIdx.x*64, f0 = blockIdx.y*64;
  int bc = blockIdx.z; int b = bc >> 3, c = bc & 7;
  const float* s = src + (size_t)b*CFW_ + (size_t)c*FW_;
  int t = threadIdx.x;
  int r16 = t >> 4, c4 = (t & 15)*4;
  #pragma unroll
  for (int pass = 0; pass < 4; ++pass){
    int f = r16 + pass*16;
    float4 v = *(const float4*)(s + (size_t)(f0+f)*W_ + w0 + c4);
    Tin[f][c4+0] = v.x; Tin[f][c4+1] = v.y;
    Tin[f][c4+2] = v.z; Tin[f][c4+3] = v.w;
  }
  __syncthreads();
  u16* d = dst + (size_t)b*CFW_ + (size_t)c*FW_;     // [w][f] layout
  #pragma unroll
  for (int pass = 0; pass < 4; ++pass){
    int w = r16 + pass*16;
    ushort4 o;
    o.x = f2bf(Tin[c4+0][w]); o.y = f2bf(Tin[c4+1][w]);
    o.z = f2bf(Tin[c4+2][w]); o.w = f2bf(Tin[c4+3][w]);
    *(ushort4*)(d + (size_t)(w0+w)*F_ + f0 + c4) = o;
  }
}

// ---------------- LayerNorm over f -> TRANSPOSED bf16 z ([b][c][w][f]) -------
// grid (16, 8, 2), block 256 = 32 w-lanes x 8 f-slices
__global__ __launch_bounds__(256)
void ln32T(const float* __restrict__ X, long xbs, u16* __restrict__ Y, long ybs,
           const float* __restrict__ g, const float* __restrict__ bta){
  int wl = threadIdx.x & 31, fs = threadIdx.x >> 5;
  int w = blockIdx.x*32 + wl;
  int c = blockIdx.y;
  int b = blockIdx.z;
  const float* xb = X + (size_t)b*xbs + (size_t)c*FW_ + w;
  float v[32];
  float sum = 0.f, sq = 0.f;
  #pragma unroll
  for (int i = 0; i < 32; ++i){
    v[i] = xb[(size_t)(fs*32 + i)*W_];
    sum += v[i]; sq += v[i]*v[i];
  }
  __shared__ float Ss[8][32], Sq[8][32], Mu[32], Rs[32];
  Ss[fs][wl] = sum; Sq[fs][wl] = sq;
  __syncthreads();
  if (fs == 0){
    float s = 0.f, q = 0.f;
    #pragma unroll
    for (int j = 0; j < 8; ++j){ s += Ss[j][wl]; q += Sq[j][wl]; }
    float mu = s * (1.f/256.f);
    float var = q * (1.f/256.f) - mu*mu;
    Mu[wl] = mu; Rs[wl] = rsqrtf(var + 1e-5f);
  }
  __syncthreads();
  float mu = Mu[wl], rs = Rs[wl];
  u16* yb = Y + (size_t)b*ybs + ((size_t)c*W_ + w)*F_ + fs*32;
  #pragma unroll
  for (int i4 = 0; i4 < 8; ++i4){
    ushort4 o;
    int f = fs*32 + i4*4;
    o.x = f2bf((v[i4*4+0] - mu)*rs*g[c*F_ + f+0] + bta[c*F_ + f+0]);
    o.y = f2bf((v[i4*4+1] - mu)*rs*g[c*F_ + f+1] + bta[c*F_ + f+1]);
    o.z = f2bf((v[i4*4+2] - mu)*rs*g[c*F_ + f+2] + bta[c*F_ + f+2]);
    o.w = f2bf((v[i4*4+3] - mu)*rs*g[c*F_ + f+3] + bta[c*F_ + f+3]);
    *(ushort4*)(yb + i4*4) = o;
  }
}

// ---------------- fused QKV MFMA GEMM, all-bf16, TRANSPOSED A ----------------
// src is [b][c][w][f] bf16. grid (8 w-tiles, 4 g-tiles, 48), block 256.
__global__ __launch_bounds__(256)
void gemm_qkv_b(const u16* __restrict__ wqb, const u16* __restrict__ wkb,
                const u16* __restrict__ wvb,
                const u16* __restrict__ srcq, const u16* __restrict__ srckv,
                u16* __restrict__ T){
  int zid = blockIdx.z;
  int proj = zid >> 4;
  int bc = zid & 15; int b = bc >> 3, c = bc & 7;
  const u16* src = (proj == 0) ? srcq : srckv;
  const u16* Wm  = (proj == 0) ? wqb : (proj == 1 ? wkb : wvb);
  const u16* AxT = src + (size_t)b*CFW_ + (size_t)c*FW_;   // [w][f]
  const u16* Bw = Wm + (size_t)c*F_*F_;
  u16* Yb = T + (size_t)proj*2*CFW_ + (size_t)b*CFW_ + (size_t)c*FW_;

  int w0 = blockIdx.x * 64;
  int g0 = blockIdx.y * 64;
  int t = threadIdx.x, lane = t & 63, wv_ = t >> 6;
  int gq = lane >> 4, c16 = lane & 15;
  int wm = w0 + wv_*16 + c16;
  const f32x4 zero4 = {0.f,0.f,0.f,0.f};
  f32x4 acc[4] = {zero4, zero4, zero4, zero4};

  for (int k0 = 0; k0 < F_; k0 += 32){
    bf16x8 af = *(const bf16x8*)(AxT + (size_t)wm*F_ + k0 + 8*gq);
    #pragma unroll
    for (int nf = 0; nf < 4; ++nf){
      bf16x8 bfr = *(const bf16x8*)(Bw + (size_t)(g0 + nf*16 + c16)*F_ + k0 + 8*gq);
      acc[nf] = __builtin_amdgcn_mfma_f32_16x16x32_bf16(af, bfr, acc[nf], 0, 0, 0);
    }
  }
  int wout = w0 + wv_*16 + 4*gq;
  #pragma unroll
  for (int nf = 0; nf < 4; ++nf){
    ushort4 o;
    o.x = f2bf(acc[nf][0]); o.y = f2bf(acc[nf][1]);
    o.z = f2bf(acc[nf][2]); o.w = f2bf(acc[nf][3]);
    *(ushort4*)(Yb + (size_t)(g0 + nf*16 + c16)*W_ + wout) = o;
  }
}

// ---------------- Wo MFMA GEMM: h(f32) += aT(bf16) @ Wo(bf16) ----------------
// A is [b][c][w][f] bf16. grid (8, 4, 16 = b*8+c), block 256
__global__ __launch_bounds__(256)
void gemm_wo_b(const u16* __restrict__ wob, const u16* __restrict__ A,
               float* __restrict__ Y){
  int bc = blockIdx.z; int b = bc >> 3, c = bc & 7;
  const u16* AxT = A + (size_t)b*CFW_ + (size_t)c*FW_;     // [w][f]
  const u16* Bw = wob + (size_t)c*F_*F_;
  float* Yb = Y + (size_t)b*OBS_ + (size_t)c*FW_;
  int w0 = blockIdx.x * 64;
  int g0 = blockIdx.y * 64;
  int t = threadIdx.x, lane = t & 63, wv_ = t >> 6;
  int gq = lane >> 4, c16 = lane & 15;
  int wm = w0 + wv_*16 + c16;
  const f32x4 zero4 = {0.f,0.f,0.f,0.f};
  f32x4 acc[4] = {zero4, zero4, zero4, zero4};

  for (int k0 = 0; k0 < F_; k0 += 32){
    bf16x8 af = *(const bf16x8*)(AxT + (size_t)wm*F_ + k0 + 8*gq);
    #pragma unroll
    for (int nf = 0; nf < 4; ++nf){
      bf16x8 bfr = *(const bf16x8*)(Bw + (size_t)(g0 + nf*16 + c16)*F_ + k0 + 8*gq);
      acc[nf] = __builtin_amdgcn_mfma_f32_16x16x32_bf16(af, bfr, acc[nf], 0, 0, 0);
    }
  }
  int wout = w0 + wv_*16 + 4*gq;
  #pragma unroll
  for (int nf = 0; nf < 4; ++nf){
    float* y = Yb + (size_t)(g0 + nf*16 + c16)*W_ + wout;
    float4 o = *(float4*)y;
    o.x += acc[nf][0]; o.y += acc[nf][1]; o.z += acc[nf][2]; o.w += acc[nf][3];
    *(float4*)y = o;
  }
}

// ---------------- fused q/k/v 1x3 conv (+RoPE), LDS-staged, all-co ------------
// grid 768 = p*256 + b*128 + jf, block 256. Block computes all 8 co x 2 f x 512 w.
__global__ __launch_bounds__(256)
void conv_rope_lds(const u16* __restrict__ T,
                   const float* __restrict__ Kq3, const float* __restrict__ bq,
                   const float* __restrict__ Kk3, const float* __restrict__ bk,
                   const float* __restrict__ Kv3, const float* __restrict__ bv,
                   u16* __restrict__ Q, u16* __restrict__ K,
                   u16* __restrict__ V){
  __shared__ float Tin[16][514];                     // zero-padded halo
  __shared__ float Kc[192];                          // [co][ci][tap]
  int bx = blockIdx.x;
  int jf = bx & 127;
  int b  = (bx >> 7) & 1;
  int p  = bx >> 8;                                  // 0..2 (block-uniform)
  const float* K3   = p==0 ? Kq3 : (p==1 ? Kk3 : Kv3);
  const float* bias = p==0 ? bq  : (p==1 ? bk  : bv);
  const u16* Tb = T + (size_t)p*2*CFW_ + (size_t)b*CFW_;
  u16* O = (p==0 ? Q : (p==1 ? K : V)) + (size_t)b*CFW_;
  int f0 = jf*2;
  int t = threadIdx.x;

  if (t < 192) Kc[t] = K3[t];
  if (t < 16){ Tin[t][0] = 0.f; Tin[t][513] = 0.f; }
  for (int li = t; li < 16*128; li += 256){          // 128 ushort4 per row
    int row = li >> 7;                               // ci*2 + fsel
    int c4  = li & 127;
    int ci = row >> 1, fsel = row & 1;
    ushort4 v4 = *(const ushort4*)(Tb + ((size_t)ci*F_ + f0 + fsel)*W_ + c4*4);
    float* dst = &Tin[row][1 + c4*4];
    dst[0] = bf2f(v4.x); dst[1] = bf2f(v4.y);
    dst[2] = bf2f(v4.z); dst[3] = bf2f(v4.w);
  }
  __syncthreads();

  int co = t >> 5;                                   // 0..7
  int wg = t & 31;                                   // 0..31
  int wbase = wg*16;
  float bs = bias[co];
  float a0[16], a1[16];
  #pragma unroll
  for (int i = 0; i < 16; ++i){ a0[i] = bs; a1[i] = bs; }
  #pragma unroll
  for (int ci = 0; ci < 8; ++ci){
    const float* r0 = &Tin[ci*2+0][1 + wbase];
    const float* r1 = &Tin[ci*2+1][1 + wbase];
    float k0 = Kc[(co*8+ci)*3+0], k1 = Kc[(co*8+ci)*3+1], k2 = Kc[(co*8+ci)*3+2];
    #pragma unroll
    for (int i = 0; i < 16; ++i){
      a0[i] += k0*r0[i-1] + k1*r0[i] + k2*r0[i+1];
      a1[i] += k0*r1[i-1] + k1*r1[i] + k2*r1[i+1];
    }
  }
  size_t obase = ((size_t)co*F_ + f0)*W_ + wbase;
  if (p < 2){
    int j = jf & 15;                                 // freq index within head
    float inv = exp2f(-(float)j * 0.83048202372184f);  // 10000^(-j/16)
    float sv, cv, dsn, dcs;
    sincosf((float)wbase * inv, &sv, &cv);
    sincosf(inv, &dsn, &dcs);
    float scale = (p == 0) ? 0.0625f : 1.f;          // fold 1/sqrt(256) into q
    u16 o0[16], o1[16];
    #pragma unroll
    for (int i = 0; i < 16; ++i){
      o0[i] = f2bf((a0[i]*cv - a1[i]*sv)*scale);
      o1[i] = f2bf((a1[i]*cv + a0[i]*sv)*scale);
      float cn = cv*dcs - sv*dsn;                    // rotate by inv
      sv = sv*dcs + cv*dsn;
      cv = cn;
    }
    #pragma unroll
    for (int q4 = 0; q4 < 4; ++q4){
      *(ushort4*)(O + obase + q4*4)      = make_ushort4(o0[q4*4],o0[q4*4+1],o0[q4*4+2],o0[q4*4+3]);
      *(ushort4*)(O + obase + W_ + q4*4) = make_ushort4(o1[q4*4],o1[q4*4+1],o1[q4*4+2],o1[q4*4+3]);
    }
  } else {
    #pragma unroll
    for (int q4 = 0; q4 < 4; ++q4){
      ushort4 p0, p1;
      p0.x = f2bf(a0[q4*4+0]); p0.y = f2bf(a0[q4*4+1]);
      p0.z = f2bf(a0[q4*4+2]); p0.w = f2bf(a0[q4*4+3]);
      p1.x = f2bf(a1[q4*4+0]); p1.y = f2bf(a1[q4*4+1]);
      p1.z = f2bf(a1[q4*4+2]); p1.w = f2bf(a1[q4*4+3]);
      *(ushort4*)(O + obase + q4*4)      = p0;
      *(ushort4*)(O + obase + W_ + q4*4) = p1;
    }
  }
}

// ---------------- MFMA attention, bf16 I/O, writes a TRANSPOSED --------------
// grid (128 = b*64 + c*8 + h, 4 q-tiles), block 512 (8 waves).
// q is pre-scaled by 1/sqrt(256) at the producer. Output aT: [b][c][w][f].
__global__ __launch_bounds__(512)
void attn_mfma_b(const u16* __restrict__ q, const u16* __restrict__ k,
                 const u16* __restrict__ v, u16* __restrict__ aT){
  extern __shared__ __align__(16) unsigned char smem_dyn[];
  u16* ks = (u16*)smem_dyn;          // [512][40]
  u16* vs = ks + 512*40;             // [32][520]
  u16* ps = vs + 32*520;             // [8][16][136]
  int bx = blockIdx.x;
  int b = bx >> 6;
  int ch = bx & 63;
  int h = ch & 7, c = ch >> 3;
  size_t base = (size_t)b*CFW_ + ((size_t)c*F_ + h*32)*W_;
  int t = threadIdx.x;
  int lane = t & 63, wv = t >> 6;
  int g = lane >> 4, c16 = lane & 15;

  int q0 = blockIdx.y*128 + wv*16;
  union { bf16x8 v8; u16 u[8]; } aq;
  #pragma unroll
  for (int j = 0; j < 8; ++j)
    aq.u[j] = q[base + (size_t)(8*g + j)*W_ + q0 + c16];

  for (int d = 0; d < 32; ++d)
    ks[t*40 + d] = k[base + (size_t)d*W_ + t];       // t = m (512)
  {
    int m8 = (t & 63)*8;
    #pragma unroll
    for (int it = 0; it < 4; ++it){
      int d = (t >> 6) + it*8;
      *(uint4*)(vs + (size_t)d*520 + m8) = *(const uint4*)(v + base + (size_t)d*W_ + m8);
    }
  }
  __syncthreads();

  u16* pw = ps + (size_t)wv*16*136;

  float mrun[4] = {-3e38f,-3e38f,-3e38f,-3e38f};
  float lrun[4] = {0.f,0.f,0.f,0.f};
  const f32x4 zero4 = {0.f,0.f,0.f,0.f};
  f32x4 outacc[2] = {zero4, zero4};

  for (int kt = 0; kt < 4; ++kt){
    f32x4 sv[8];
    #pragma unroll
    for (int mi = 0; mi < 8; ++mi){
      int m0 = kt*128 + mi*16;
      bf16x8 kb8 = *(const bf16x8*)(ks + (size_t)(m0 + c16)*40 + 8*g);
      sv[mi] = __builtin_amdgcn_mfma_f32_16x16x32_bf16(aq.v8, kb8, zero4, 0, 0, 0);
    }
    float pmax[4];
    #pragma unroll
    for (int r = 0; r < 4; ++r){
      float m = sv[0][r];
      #pragma unroll
      for (int mi = 1; mi < 8; ++mi) m = fmaxf(m, sv[mi][r]);
      pmax[r] = m;
    }
    #pragma unroll
    for (int mask = 1; mask <= 8; mask <<= 1){
      #pragma unroll
      for (int r = 0; r < 4; ++r)
        pmax[r] = fmaxf(pmax[r], __shfl_xor(pmax[r], mask));
    }
    float corr[4];
    #pragma unroll
    for (int r = 0; r < 4; ++r){
      float mn = fmaxf(mrun[r], pmax[r]);
      corr[r] = __expf(mrun[r] - mn);
      mrun[r] = mn;
      lrun[r] *= corr[r];
    }
    #pragma unroll
    for (int mi = 0; mi < 8; ++mi){
      #pragma unroll
      for (int r = 0; r < 4; ++r){
        float p = __expf(sv[mi][r] - mrun[r]);
        lrun[r] += p;
        pw[(size_t)(4*g + r)*136 + mi*16 + c16] = f2bf(p);
      }
    }
    f32x4 cv = {corr[0], corr[1], corr[2], corr[3]};
    outacc[0] *= cv;
    outacc[1] *= cv;
    #pragma unroll
    for (int mc = 0; mc < 4; ++mc){
      bf16x8 pa  = *(const bf16x8*)(pw + (size_t)c16*136 + mc*32 + 8*g);
      bf16x8 vb0 = *(const bf16x8*)(vs + (size_t)c16*520      + kt*128 + mc*32 + 8*g);
      bf16x8 vb1 = *(const bf16x8*)(vs + (size_t)(16+c16)*520 + kt*128 + mc*32 + 8*g);
      outacc[0] = __builtin_amdgcn_mfma_f32_16x16x32_bf16(pa, vb0, outacc[0], 0, 0, 0);
      outacc[1] = __builtin_amdgcn_mfma_f32_16x16x32_bf16(pa, vb1, outacc[1], 0, 0, 0);
    }
  }
  float L[4];
  #pragma unroll
  for (int r = 0; r < 4; ++r){
    float s = lrun[r];
    #pragma unroll
    for (int mask = 1; mask <= 8; mask <<= 1) s += __shfl_xor(s, mask);
    L[r] = s;
  }
  // aT[b][c][w][f]: w = q0+4g+r, f = h*32 + dt*16 + c16
  size_t tbase = (size_t)b*CFW_ + (size_t)c*FW_;
  #pragma unroll
  for (int dt = 0; dt < 2; ++dt){
    #pragma unroll
    for (int r = 0; r < 4; ++r)
      aT[tbase + (size_t)(q0 + 4*g + r)*F_ + h*32 + dt*16 + c16]
        = f2bf(outacc[dt][r] / L[r]);
  }
}

// ---------------- FUSED conv block: h += conv7(LN2(sqrelu(conv11(LN1 h)) + conv7(LN1 h)))
// grid (16 w-tiles of 32, 8 c, 2 b), block 256 = 32 wl x 8 fs. In-place on h.
__global__ __launch_bounds__(256)
void convblock(float* __restrict__ Hp,
               const float* __restrict__ g1, const float* __restrict__ b1,
               const float* __restrict__ k11, const float* __restrict__ b11,
               const float* __restrict__ k7,  const float* __restrict__ b7,
               const float* __restrict__ g2, const float* __restrict__ b2,
               const float* __restrict__ k2w, const float* __restrict__ b2c){
  __shared__ float Z[256][32];
  __shared__ float S2[256][32];
  __shared__ float Ss[8][32], Sq[8][32], Mu[32], Rs[32];
  int wl = threadIdx.x & 31, fs = threadIdx.x >> 5;
  int w = blockIdx.x*32 + wl;
  int c = blockIdx.y, b = blockIdx.z;
  float* hcol = Hp + (size_t)b*OBS_ + (size_t)c*FW_ + w;

  float v[32];
  float sum = 0.f, sq = 0.f;
  #pragma unroll
  for (int i = 0; i < 32; ++i){
    v[i] = hcol[(size_t)(fs*32 + i)*W_];
    sum += v[i]; sq += v[i]*v[i];
  }
  Ss[fs][wl] = sum; Sq[fs][wl] = sq;
  __syncthreads();
  if (fs == 0){
    float s = 0.f, q = 0.f;
    #pragma unroll
    for (int j = 0; j < 8; ++j){ s += Ss[j][wl]; q += Sq[j][wl]; }
    float mu = s * (1.f/256.f);
    Mu[wl] = mu; Rs[wl] = rsqrtf(q * (1.f/256.f) - mu*mu + 1e-5f);
  }
  __syncthreads();
  {
    float mu = Mu[wl], rs = Rs[wl];
    #pragma unroll
    for (int i = 0; i < 32; ++i){
      int f = fs*32 + i;
      Z[f][wl] = (v[i] - mu)*rs*g1[c*F_ + f] + b1[c*F_ + f];
    }
  }
  __syncthreads();

  // s = sq_relu(conv11(Z)) + conv7(Z) along f (zero-padded)
  float sarr[32];
  float sum2 = 0.f, sq2 = 0.f;
  #pragma unroll
  for (int i = 0; i < 32; ++i){
    int f = fs*32 + i;
    float a = b11[c];
    #pragma unroll
    for (int d = 0; d < 11; ++d){
      int ff = f - 5 + d;
      if (ff >= 0 && ff < F_) a += k11[c*11 + d]*Z[ff][wl];
    }
    float bb = b7[c];
    #pragma unroll
    for (int d = 0; d < 7; ++d){
      int ff = f - 3 + d;
      if (ff >= 0 && ff < F_) bb += k7[c*7 + d]*Z[ff][wl];
    }
    float ra = a > 0.f ? a*a : 0.f;
    sarr[i] = ra + bb;
    sum2 += sarr[i]; sq2 += sarr[i]*sarr[i];
  }
  __syncthreads();                  // all Z reads done; Ss/Sq reusable
  Ss[fs][wl] = sum2; Sq[fs][wl] = sq2;
  __syncthreads();
  if (fs == 0){
    float s = 0.f, q = 0.f;
    #pragma unroll
    for (int j = 0; j < 8; ++j){ s += Ss[j][wl]; q += Sq[j][wl]; }
    float mu = s * (1.f/256.f);
    Mu[wl] = mu; Rs[wl] = rsqrtf(q * (1.f/256.f) - mu*mu + 1e-5f);
  }
  __syncthreads();
  {
    float mu = Mu[wl], rs = Rs[wl];
    #pragma unroll
    for (int i = 0; i < 32; ++i){
      int f = fs*32 + i;
      S2[f][wl] = (sarr[i] - mu)*rs*g2[c*F_ + f] + b2[c*F_ + f];
    }
  }
  __syncthreads();

  // h += conv7(S2) + bias
  #pragma unroll
  for (int i = 0; i < 32; ++i){
    int f = fs*32 + i;
    float acc = b2c[c];
    #pragma unroll
    for (int d = 0; d < 7; ++d){
      int ff = f - 3 + d;
      if (ff >= 0 && ff < F_) acc += k2w[c*7 + d]*S2[ff][wl];
    }
    hcol[(size_t)f*W_] = v[i] + acc;
  }
}

// ---------------- FUSED FF: h += w4 @ sq_relu(w3 @ LN5(h)) ----------------
// grid (16, 8, 2), block 256 = 32 wl x 8 fs. In-place on h.
__global__ __launch_bounds__(256)
void ff_ln(float* __restrict__ Hp,
           const float* __restrict__ g, const float* __restrict__ bta,
           const float* __restrict__ w3, const float* __restrict__ w4){
  int wl = threadIdx.x & 31, fs = threadIdx.x >> 5;
  int w = blockIdx.x*32 + wl;
  int c = blockIdx.y, b = blockIdx.z;
  float* hcol = Hp + (size_t)b*OBS_ + (size_t)c*FW_ + w;
  float v[32];
  float sum = 0.f, sq = 0.f;
  #pragma unroll
  for (int i = 0; i < 32; ++i){
    v[i] = hcol[(size_t)(fs*32 + i)*W_];
    sum += v[i]; sq += v[i]*v[i];
  }
  __shared__ float Ss[8][32], Sq[8][32], Mu[32], Rs[32];
  Ss[fs][wl] = sum; Sq[fs][wl] = sq;
  __syncthreads();
  if (fs == 0){
    float s = 0.f, q = 0.f;
    #pragma unroll
    for (int j = 0; j < 8; ++j){ s += Ss[j][wl]; q += Sq[j][wl]; }
    float mu = s * (1.f/256.f);
    Mu[wl] = mu; Rs[wl] = rsqrtf(q * (1.f/256.f) - mu*mu + 1e-5f);
  }
  __syncthreads();
  float mu = Mu[wl], rs = Rs[wl];
  float u[4] = {0.f,0.f,0.f,0.f};
  #pragma unroll
  for (int i = 0; i < 32; ++i){
    int f = fs*32 + i;
    float z = (v[i] - mu)*rs*g[c*F_ + f] + bta[c*F_ + f];
    #pragma unroll
    for (int e = 0; e < 4; ++e) u[e] += w3[(c*4 + e)*F_ + f]*z;
  }
  __shared__ float Us[8][4][32];
  #pragma unroll
  for (int e = 0; e < 4; ++e) Us[fs][e][wl] = u[e];
  __syncthreads();
  float uf[4];
  #pragma unroll
  for (int e = 0; e < 4; ++e){
    float s = 0.f;
    #pragma unroll
    for (int j = 0; j < 8; ++j) s += Us[j][e][wl];
    float rr = s > 0.f ? s : 0.f;
    uf[e] = rr*rr;
  }
  #pragma unroll
  for (int i = 0; i < 32; ++i){
    int f = fs*32 + i;
    const float* w4r = w4 + (c*F_ + f)*4;
    hcol[(size_t)f*W_] = v[i] + w4r[0]*uf[0] + w4r[1]*uf[1] + w4r[2]*uf[2] + w4r[3]*uf[3];
  }
}

extern "C" void kernel_launch(void* const* d_in, const int* in_sizes, int n_in,
                              void* d_out, int out_size, void* d_ws, size_t ws_size,
                              hipStream_t stream){
  const float* x    = (const float*)d_in[0];
  const float* skip = (const float*)d_in[1];
  const float* Wq   = (const float*)d_in[2];
  const float* Kq   = (const float*)d_in[3];
  const float* bq   = (const float*)d_in[4];
  const float* Wk   = (const float*)d_in[5];
  const float* Kk   = (const float*)d_in[6];
  const float* bk   = (const float*)d_in[7];
  const float* Wv   = (const float*)d_in[8];
  const float* Kv   = (const float*)d_in[9];
  const float* bv   = (const float*)d_in[10];
  const float* Wo   = (const float*)d_in[11];
  const float* ng   = (const float*)d_in[12];
  const float* nb   = (const float*)d_in[13];
  const float* c1aw = (const float*)d_in[14];
  const float* c1ab = (const float*)d_in[15];
  const float* c1bw = (const float*)d_in[16];
  const float* c1bb = (const float*)d_in[17];
  const float* c2w  = (const float*)d_in[18];
  const float* c2b  = (const float*)d_in[19];
  const float* w3   = (const float*)d_in[20];
  const float* w4   = (const float*)d_in[21];

  float* out = (float*)d_out;
  float* hp  = out + CFW_;           // h at hp + b*OBS_ + c*FW_

  // ws layout (MiB offsets): bf16 weights 0..16, skipT 16, zT 20, t 24..36,
  // q 36, k 40, v 44  (f32 scratch no longer needed)
  char* wsb = (char*)d_ws;
  u16* WQb  = (u16*)(wsb);
  u16* WKb  = (u16*)(wsb + ((size_t)4  << 20));
  u16* WVb  = (u16*)(wsb + ((size_t)8  << 20));
  u16* WOb  = (u16*)(wsb + ((size_t)12 << 20));
  u16* skT  = (u16*)(wsb + ((size_t)16 << 20));  // skip^T bf16 [b][c][w][f]
  u16* zT   = (u16*)(wsb + ((size_t)20 << 20));  // z^T bf16 [b][c][w][f]
  u16* tqkv = (u16*)(wsb + ((size_t)24 << 20));  // t: 3 proj x 2 b
  u16* qbB  = (u16*)(wsb + ((size_t)36 << 20));
  u16* kbB  = (u16*)(wsb + ((size_t)40 << 20));
  u16* vbB  = (u16*)(wsb + ((size_t)44 << 20));
  u16* aT   = tqkv;                  // attn out (transposed) aliases t

  float code = 0.f;
  if (n_in != 22) code += 20000.f;
  if (out_size != 4194304) code += 80000.f;
  if (ws_size < ((size_t)48 << 20)) code += 160000.f;

  dim3 gGemmQKV(8, 4, 48);
  dim3 gGemmWo(8, 4, 16);
  dim3 gLn(16, 8, 2);
  dim3 gAttn(128, 4);
  dim3 gCvtT(8, 4, 16);
  const int attn_lds_bytes = (512*40 + 32*520 + 8*16*136) * 2;  // 109056

  init_out<<<8192, 256, 0, stream>>>(x, out);
  cvt4<<<dim3(2048, 4), 256, 0, stream>>>(Wq, Wk, Wv, Wo, WQb, WKb, WVb, WOb);
  cvtT<<<gCvtT, 256, 0, stream>>>(skip, skT);

  auto do_attn = [&](int i, const u16* srcq, const u16* srckv){
    size_t wo16 = (size_t)i*C_*F_*F_;          // per-attn weight offset (u16)
    gemm_qkv_b<<<gGemmQKV, 256, 0, stream>>>(WQb + wo16, WKb + wo16, WVb + wo16,
                                             srcq, srckv, tqkv);
    conv_rope_lds<<<768, 256, 0, stream>>>(
        tqkv, Kq + i*C_*C_*3, bq + i*C_, Kk + i*C_*C_*3, bk + i*C_,
        Kv + i*C_*C_*3, bv + i*C_, qbB, kbB, vbB);
    attn_mfma_b<<<gAttn, 512, attn_lds_bytes, stream>>>(qbB, kbB, vbB, aT);
    gemm_wo_b<<<gGemmWo, 256, 0, stream>>>(WOb + wo16, aT, hp);
  };

  // z = LN0(x); h = x + att0(z,z) + att1(z,skip)
  ln32T<<<gLn, 256, 0, stream>>>(x, CFW_, zT, CFW_, ng + 0*C_*F_, nb + 0*C_*F_);
  do_attn(0, zT, zT);
  do_attn(1, zT, skT);

  // fused conv block (in-place on h)
  convblock<<<gLn, 256, 0, stream>>>(hp, ng + 1*C_*F_, nb + 1*C_*F_,
                                     c1aw, c1ab, c1bw, c1bb,
                                     ng + 2*C_*F_, nb + 2*C_*F_, c2w, c2b);

  // att2 (self on LN3(h))
  ln32T<<<gLn, 256, 0, stream>>>(hp, OBS_, zT, CFW_, ng + 3*C_*F_, nb + 3*C_*F_);
  do_attn(2, zT, zT);

  // att3 (LN4(h) vs skip)
  ln32T<<<gLn, 256, 0, stream>>>(hp, OBS_, zT, CFW_, ng + 4*C_*F_, nb + 4*C_*F_);
  do_attn(3, zT, skT);

  // fused FF (in-place on h)
  ff_ln<<<gLn, 256, 0, stream>>>(hp, ng + 5*C_*F_, nb + 5*C_*F_, w3, w4);

  if (code != 0.f) put_val<<<1, 1, 0, stream>>>(out, code);
}

// Round 17
// 440.874 us; speedup vs baseline: 1.1029x; 1.1029x over previous
//
#include <hip/hip_runtime.h>

#define B_ 2
#define C_ 8
#define F_ 256
#define W_ 512
#define H_ 8
#define FW_ (F_*W_)        // 131072
#define CFW_ (C_*FW_)      // 1048576 = one batch of (C,F,W)
#define OBS_ (2*CFW_)      // out batch stride (B,16,F,W)

typedef unsigned short u16;

__device__ __forceinline__ u16 f2bf(float f){
  unsigned u = __float_as_uint(f);
  u += 0x7fffu + ((u>>16)&1u);
  return (u16)(u>>16);
}
__device__ __forceinline__ float bf2f(u16 u){
  return __uint_as_float((unsigned)u<<16);
}

typedef __attribute__((ext_vector_type(8))) short bf16x8;
typedef __attribute__((ext_vector_type(4))) float f32x4;

// ---------------- init: both halves of out = x ----------------
__global__ __launch_bounds__(256)
void init_out(const float* __restrict__ x, float* __restrict__ out){
  int i = blockIdx.x*256 + threadIdx.x;              // 2M
  int b = i >> 20;
  int r = i & (CFW_-1);
  float v = x[i];
  out[(size_t)b*OBS_ + r] = v;
  out[(size_t)b*OBS_ + CFW_ + r] = v;
}

__global__ void put_val(float* o, float v){ o[0] = v; }

// ---------------- bulk f32 -> bf16 conversion (4 weight arrays) --------------
__global__ __launch_bounds__(256)
void cvt4(const float* __restrict__ s0, const float* __restrict__ s1,
          const float* __restrict__ s2, const float* __restrict__ s3,
          u16* __restrict__ d0, u16* __restrict__ d1, u16* __restrict__ d2,
          u16* __restrict__ d3){
  int which = blockIdx.y;
  const float* s = which==0 ? s0 : which==1 ? s1 : which==2 ? s2 : s3;
  u16* d        = which==0 ? d0 : which==1 ? d1 : which==2 ? d2 : d3;
  int i = (blockIdx.x*256 + threadIdx.x)*4;          // 2048 blocks x 1024 elems
  float4 v = *(const float4*)(s + i);
  ushort4 o;
  o.x = f2bf(v.x); o.y = f2bf(v.y); o.z = f2bf(v.z); o.w = f2bf(v.w);
  *(ushort4*)(d + i) = o;
}

// ---------------- skip -> skip^T bf16 ([b][c][w][f]) via LDS 64x64 tile ------
// grid (8 w-tiles, 4 f-tiles, 16 = b*8+c), block 256
__global__ __launch_bounds__(256)
void cvtT(const float* __restrict__ src, u16* __restrict__ dst){
  __shared__ float Tin[64][65];
  int w0 = blockIdx.x*64, f0 = blockIdx.y*64;
  int bc = blockIdx.z; int b = bc >> 3, c = bc & 7;
  const float* s = src + (size_t)b*CFW_ + (size_t)c*FW_;
  int t = threadIdx.x;
  int r16 = t >> 4, c4 = (t & 15)*4;
  #pragma unroll
  for (int pass = 0; pass < 4; ++pass){
    int f = r16 + pass*16;
    float4 v = *(const float4*)(s + (size_t)(f0+f)*W_ + w0 + c4);
    Tin[f][c4+0] = v.x; Tin[f][c4+1] = v.y;
    Tin[f][c4+2] = v.z; Tin[f][c4+3] = v.w;
  }
  __syncthreads();
  u16* d = dst + (size_t)b*CFW_ + (size_t)c*FW_;     // [w][f] layout
  #pragma unroll
  for (int pass = 0; pass < 4; ++pass){
    int w = r16 + pass*16;
    ushort4 o;
    o.x = f2bf(Tin[c4+0][w]); o.y = f2bf(Tin[c4+1][w]);
    o.z = f2bf(Tin[c4+2][w]); o.w = f2bf(Tin[c4+3][w]);
    *(ushort4*)(d + (size_t)(w0+w)*F_ + f0 + c4) = o;
  }
}

// ---------------- LayerNorm over f -> TRANSPOSED bf16 z ([b][c][w][f]) -------
// grid (16, 8, 2), block 256 = 32 w-lanes x 8 f-slices
__global__ __launch_bounds__(256)
void ln32T(const float* __restrict__ X, long xbs, u16* __restrict__ Y, long ybs,
           const float* __restrict__ g, const float* __restrict__ bta){
  int wl = threadIdx.x & 31, fs = threadIdx.x >> 5;
  int w = blockIdx.x*32 + wl;
  int c = blockIdx.y;
  int b = blockIdx.z;
  const float* xb = X + (size_t)b*xbs + (size_t)c*FW_ + w;
  float v[32];
  float sum = 0.f, sq = 0.f;
  #pragma unroll
  for (int i = 0; i < 32; ++i){
    v[i] = xb[(size_t)(fs*32 + i)*W_];
    sum += v[i]; sq += v[i]*v[i];
  }
  __shared__ float Ss[8][32], Sq[8][32], Mu[32], Rs[32];
  Ss[fs][wl] = sum; Sq[fs][wl] = sq;
  __syncthreads();
  if (fs == 0){
    float s = 0.f, q = 0.f;
    #pragma unroll
    for (int j = 0; j < 8; ++j){ s += Ss[j][wl]; q += Sq[j][wl]; }
    float mu = s * (1.f/256.f);
    float var = q * (1.f/256.f) - mu*mu;
    Mu[wl] = mu; Rs[wl] = rsqrtf(var + 1e-5f);
  }
  __syncthreads();
  float mu = Mu[wl], rs = Rs[wl];
  u16* yb = Y + (size_t)b*ybs + ((size_t)c*W_ + w)*F_ + fs*32;
  #pragma unroll
  for (int i4 = 0; i4 < 8; ++i4){
    ushort4 o;
    int f = fs*32 + i4*4;
    o.x = f2bf((v[i4*4+0] - mu)*rs*g[c*F_ + f+0] + bta[c*F_ + f+0]);
    o.y = f2bf((v[i4*4+1] - mu)*rs*g[c*F_ + f+1] + bta[c*F_ + f+1]);
    o.z = f2bf((v[i4*4+2] - mu)*rs*g[c*F_ + f+2] + bta[c*F_ + f+2]);
    o.w = f2bf((v[i4*4+3] - mu)*rs*g[c*F_ + f+3] + bta[c*F_ + f+3]);
    *(ushort4*)(yb + i4*4) = o;
  }
}

// ---------------- LayerNorm over f -> f32 out (conv path) ----------------
// grid (16, 8, 2), block 256 = 32 w-lanes x 8 f-slices
__global__ __launch_bounds__(256)
void ln32f(const float* __restrict__ X, long xbs, float* __restrict__ Y, long ybs,
           const float* __restrict__ g, const float* __restrict__ bta){
  int wl = threadIdx.x & 31, fs = threadIdx.x >> 5;
  int w = blockIdx.x*32 + wl;
  int c = blockIdx.y;
  int b = blockIdx.z;
  const float* xb = X + (size_t)b*xbs + (size_t)c*FW_ + w;
  float v[32];
  float sum = 0.f, sq = 0.f;
  #pragma unroll
  for (int i = 0; i < 32; ++i){
    v[i] = xb[(size_t)(fs*32 + i)*W_];
    sum += v[i]; sq += v[i]*v[i];
  }
  __shared__ float Ss[8][32], Sq[8][32], Mu[32], Rs[32];
  Ss[fs][wl] = sum; Sq[fs][wl] = sq;
  __syncthreads();
  if (fs == 0){
    float s = 0.f, q = 0.f;
    #pragma unroll
    for (int j = 0; j < 8; ++j){ s += Ss[j][wl]; q += Sq[j][wl]; }
    float mu = s * (1.f/256.f);
    float var = q * (1.f/256.f) - mu*mu;
    Mu[wl] = mu; Rs[wl] = rsqrtf(var + 1e-5f);
  }
  __syncthreads();
  float mu = Mu[wl], rs = Rs[wl];
  float* yb = Y + (size_t)b*ybs + (size_t)c*FW_ + w;
  #pragma unroll
  for (int i = 0; i < 32; ++i){
    int f = fs*32 + i;
    yb[(size_t)f*W_] = (v[i] - mu)*rs*g[c*F_ + f] + bta[c*F_ + f];
  }
}

// ---------------- fused QKV MFMA GEMM, all-bf16, TRANSPOSED A ----------------
// src is [b][c][w][f] bf16. grid (8 w-tiles, 4 g-tiles, 48), block 256.
__global__ __launch_bounds__(256)
void gemm_qkv_b(const u16* __restrict__ wqb, const u16* __restrict__ wkb,
                const u16* __restrict__ wvb,
                const u16* __restrict__ srcq, const u16* __restrict__ srckv,
                u16* __restrict__ T){
  int zid = blockIdx.z;
  int proj = zid >> 4;
  int bc = zid & 15; int b = bc >> 3, c = bc & 7;
  const u16* src = (proj == 0) ? srcq : srckv;
  const u16* Wm  = (proj == 0) ? wqb : (proj == 1 ? wkb : wvb);
  const u16* AxT = src + (size_t)b*CFW_ + (size_t)c*FW_;   // [w][f]
  const u16* Bw = Wm + (size_t)c*F_*F_;
  u16* Yb = T + (size_t)proj*2*CFW_ + (size_t)b*CFW_ + (size_t)c*FW_;

  int w0 = blockIdx.x * 64;
  int g0 = blockIdx.y * 64;
  int t = threadIdx.x, lane = t & 63, wv_ = t >> 6;
  int gq = lane >> 4, c16 = lane & 15;
  int wm = w0 + wv_*16 + c16;
  const f32x4 zero4 = {0.f,0.f,0.f,0.f};
  f32x4 acc[4] = {zero4, zero4, zero4, zero4};

  for (int k0 = 0; k0 < F_; k0 += 32){
    bf16x8 af = *(const bf16x8*)(AxT + (size_t)wm*F_ + k0 + 8*gq);
    #pragma unroll
    for (int nf = 0; nf < 4; ++nf){
      bf16x8 bfr = *(const bf16x8*)(Bw + (size_t)(g0 + nf*16 + c16)*F_ + k0 + 8*gq);
      acc[nf] = __builtin_amdgcn_mfma_f32_16x16x32_bf16(af, bfr, acc[nf], 0, 0, 0);
    }
  }
  int wout = w0 + wv_*16 + 4*gq;
  #pragma unroll
  for (int nf = 0; nf < 4; ++nf){
    ushort4 o;
    o.x = f2bf(acc[nf][0]); o.y = f2bf(acc[nf][1]);
    o.z = f2bf(acc[nf][2]); o.w = f2bf(acc[nf][3]);
    *(ushort4*)(Yb + (size_t)(g0 + nf*16 + c16)*W_ + wout) = o;
  }
}

// ---------------- Wo MFMA GEMM: h(f32) += aT(bf16) @ Wo(bf16) ----------------
// A is [b][c][w][f] bf16. grid (8, 4, 16 = b*8+c), block 256
__global__ __launch_bounds__(256)
void gemm_wo_b(const u16* __restrict__ wob, const u16* __restrict__ A,
               float* __restrict__ Y){
  int bc = blockIdx.z; int b = bc >> 3, c = bc & 7;
  const u16* AxT = A + (size_t)b*CFW_ + (size_t)c*FW_;     // [w][f]
  const u16* Bw = wob + (size_t)c*F_*F_;
  float* Yb = Y + (size_t)b*OBS_ + (size_t)c*FW_;
  int w0 = blockIdx.x * 64;
  int g0 = blockIdx.y * 64;
  int t = threadIdx.x, lane = t & 63, wv_ = t >> 6;
  int gq = lane >> 4, c16 = lane & 15;
  int wm = w0 + wv_*16 + c16;
  const f32x4 zero4 = {0.f,0.f,0.f,0.f};
  f32x4 acc[4] = {zero4, zero4, zero4, zero4};

  for (int k0 = 0; k0 < F_; k0 += 32){
    bf16x8 af = *(const bf16x8*)(AxT + (size_t)wm*F_ + k0 + 8*gq);
    #pragma unroll
    for (int nf = 0; nf < 4; ++nf){
      bf16x8 bfr = *(const bf16x8*)(Bw + (size_t)(g0 + nf*16 + c16)*F_ + k0 + 8*gq);
      acc[nf] = __builtin_amdgcn_mfma_f32_16x16x32_bf16(af, bfr, acc[nf], 0, 0, 0);
    }
  }
  int wout = w0 + wv_*16 + 4*gq;
  #pragma unroll
  for (int nf = 0; nf < 4; ++nf){
    float* y = Yb + (size_t)(g0 + nf*16 + c16)*W_ + wout;
    float4 o = *(float4*)y;
    o.x += acc[nf][0]; o.y += acc[nf][1]; o.z += acc[nf][2]; o.w += acc[nf][3];
    *(float4*)y = o;
  }
}

// ---------------- fused q/k/v 1x3 conv (+RoPE), LDS-staged, all-co ------------
// grid 768 = p*256 + b*128 + jf, block 256. Block computes all 8 co x 2 f x 512 w.
__global__ __launch_bounds__(256)
void conv_rope_lds(const u16* __restrict__ T,
                   const float* __restrict__ Kq3, const float* __restrict__ bq,
                   const float* __restrict__ Kk3, const float* __restrict__ bk,
                   const float* __restrict__ Kv3, const float* __restrict__ bv,
                   u16* __restrict__ Q, u16* __restrict__ K,
                   u16* __restrict__ V){
  __shared__ float Tin[16][514];                     // zero-padded halo
  __shared__ float Kc[192];                          // [co][ci][tap]
  int bx = blockIdx.x;
  int jf = bx & 127;
  int b  = (bx >> 7) & 1;
  int p  = bx >> 8;                                  // 0..2 (block-uniform)
  const float* K3   = p==0 ? Kq3 : (p==1 ? Kk3 : Kv3);
  const float* bias = p==0 ? bq  : (p==1 ? bk  : bv);
  const u16* Tb = T + (size_t)p*2*CFW_ + (size_t)b*CFW_;
  u16* O = (p==0 ? Q : (p==1 ? K : V)) + (size_t)b*CFW_;
  int f0 = jf*2;
  int t = threadIdx.x;

  if (t < 192) Kc[t] = K3[t];
  if (t < 16){ Tin[t][0] = 0.f; Tin[t][513] = 0.f; }
  for (int li = t; li < 16*128; li += 256){          // 128 ushort4 per row
    int row = li >> 7;                               // ci*2 + fsel
    int c4  = li & 127;
    int ci = row >> 1, fsel = row & 1;
    ushort4 v4 = *(const ushort4*)(Tb + ((size_t)ci*F_ + f0 + fsel)*W_ + c4*4);
    float* dst = &Tin[row][1 + c4*4];
    dst[0] = bf2f(v4.x); dst[1] = bf2f(v4.y);
    dst[2] = bf2f(v4.z); dst[3] = bf2f(v4.w);
  }
  __syncthreads();

  int co = t >> 5;                                   // 0..7
  int wg = t & 31;                                   // 0..31
  int wbase = wg*16;
  float bs = bias[co];
  float a0[16], a1[16];
  #pragma unroll
  for (int i = 0; i < 16; ++i){ a0[i] = bs; a1[i] = bs; }
  #pragma unroll
  for (int ci = 0; ci < 8; ++ci){
    const float* r0 = &Tin[ci*2+0][1 + wbase];
    const float* r1 = &Tin[ci*2+1][1 + wbase];
    float k0 = Kc[(co*8+ci)*3+0], k1 = Kc[(co*8+ci)*3+1], k2 = Kc[(co*8+ci)*3+2];
    #pragma unroll
    for (int i = 0; i < 16; ++i){
      a0[i] += k0*r0[i-1] + k1*r0[i] + k2*r0[i+1];
      a1[i] += k0*r1[i-1] + k1*r1[i] + k2*r1[i+1];
    }
  }
  size_t obase = ((size_t)co*F_ + f0)*W_ + wbase;
  if (p < 2){
    int j = jf & 15;                                 // freq index within head
    float inv = exp2f(-(float)j * 0.83048202372184f);  // 10000^(-j/16)
    float sv, cv, dsn, dcs;
    sincosf((float)wbase * inv, &sv, &cv);
    sincosf(inv, &dsn, &dcs);
    float scale = (p == 0) ? 0.0625f : 1.f;          // fold 1/sqrt(256) into q
    u16 o0[16], o1[16];
    #pragma unroll
    for (int i = 0; i < 16; ++i){
      o0[i] = f2bf((a0[i]*cv - a1[i]*sv)*scale);
      o1[i] = f2bf((a1[i]*cv + a0[i]*sv)*scale);
      float cn = cv*dcs - sv*dsn;                    // rotate by inv
      sv = sv*dcs + cv*dsn;
      cv = cn;
    }
    #pragma unroll
    for (int q4 = 0; q4 < 4; ++q4){
      *(ushort4*)(O + obase + q4*4)      = make_ushort4(o0[q4*4],o0[q4*4+1],o0[q4*4+2],o0[q4*4+3]);
      *(ushort4*)(O + obase + W_ + q4*4) = make_ushort4(o1[q4*4],o1[q4*4+1],o1[q4*4+2],o1[q4*4+3]);
    }
  } else {
    #pragma unroll
    for (int q4 = 0; q4 < 4; ++q4){
      ushort4 p0, p1;
      p0.x = f2bf(a0[q4*4+0]); p0.y = f2bf(a0[q4*4+1]);
      p0.z = f2bf(a0[q4*4+2]); p0.w = f2bf(a0[q4*4+3]);
      p1.x = f2bf(a1[q4*4+0]); p1.y = f2bf(a1[q4*4+1]);
      p1.z = f2bf(a1[q4*4+2]); p1.w = f2bf(a1[q4*4+3]);
      *(ushort4*)(O + obase + q4*4)      = p0;
      *(ushort4*)(O + obase + W_ + q4*4) = p1;
    }
  }
}

// ---------------- MFMA attention, bf16 I/O, writes a TRANSPOSED --------------
// grid (128 = b*64 + c*8 + h, 4 q-tiles), block 512 (8 waves).
// q is pre-scaled by 1/sqrt(256) at the producer. Output aT: [b][c][w][f].
__global__ __launch_bounds__(512)
void attn_mfma_b(const u16* __restrict__ q, const u16* __restrict__ k,
                 const u16* __restrict__ v, u16* __restrict__ aT){
  extern __shared__ __align__(16) unsigned char smem_dyn[];
  u16* ks = (u16*)smem_dyn;          // [512][40]
  u16* vs = ks + 512*40;             // [32][520]
  u16* ps = vs + 32*520;             // [8][16][136]
  int bx = blockIdx.x;
  int b = bx >> 6;
  int ch = bx & 63;
  int h = ch & 7, c = ch >> 3;
  size_t base = (size_t)b*CFW_ + ((size_t)c*F_ + h*32)*W_;
  int t = threadIdx.x;
  int lane = t & 63, wv = t >> 6;
  int g = lane >> 4, c16 = lane & 15;

  int q0 = blockIdx.y*128 + wv*16;
  union { bf16x8 v8; u16 u[8]; } aq;
  #pragma unroll
  for (int j = 0; j < 8; ++j)
    aq.u[j] = q[base + (size_t)(8*g + j)*W_ + q0 + c16];

  for (int d = 0; d < 32; ++d)
    ks[t*40 + d] = k[base + (size_t)d*W_ + t];       // t = m (512)
  {
    int m8 = (t & 63)*8;
    #pragma unroll
    for (int it = 0; it < 4; ++it){
      int d = (t >> 6) + it*8;
      *(uint4*)(vs + (size_t)d*520 + m8) = *(const uint4*)(v + base + (size_t)d*W_ + m8);
    }
  }
  __syncthreads();

  u16* pw = ps + (size_t)wv*16*136;

  float mrun[4] = {-3e38f,-3e38f,-3e38f,-3e38f};
  float lrun[4] = {0.f,0.f,0.f,0.f};
  const f32x4 zero4 = {0.f,0.f,0.f,0.f};
  f32x4 outacc[2] = {zero4, zero4};

  for (int kt = 0; kt < 4; ++kt){
    f32x4 sv[8];
    #pragma unroll
    for (int mi = 0; mi < 8; ++mi){
      int m0 = kt*128 + mi*16;
      bf16x8 kb8 = *(const bf16x8*)(ks + (size_t)(m0 + c16)*40 + 8*g);
      sv[mi] = __builtin_amdgcn_mfma_f32_16x16x32_bf16(aq.v8, kb8, zero4, 0, 0, 0);
    }
    float pmax[4];
    #pragma unroll
    for (int r = 0; r < 4; ++r){
      float m = sv[0][r];
      #pragma unroll
      for (int mi = 1; mi < 8; ++mi) m = fmaxf(m, sv[mi][r]);
      pmax[r] = m;
    }
    #pragma unroll
    for (int mask = 1; mask <= 8; mask <<= 1){
      #pragma unroll
      for (int r = 0; r < 4; ++r)
        pmax[r] = fmaxf(pmax[r], __shfl_xor(pmax[r], mask));
    }
    float corr[4];
    #pragma unroll
    for (int r = 0; r < 4; ++r){
      float mn = fmaxf(mrun[r], pmax[r]);
      corr[r] = __expf(mrun[r] - mn);
      mrun[r] = mn;
      lrun[r] *= corr[r];
    }
    #pragma unroll
    for (int mi = 0; mi < 8; ++mi){
      #pragma unroll
      for (int r = 0; r < 4; ++r){
        float p = __expf(sv[mi][r] - mrun[r]);
        lrun[r] += p;
        pw[(size_t)(4*g + r)*136 + mi*16 + c16] = f2bf(p);
      }
    }
    f32x4 cv = {corr[0], corr[1], corr[2], corr[3]};
    outacc[0] *= cv;
    outacc[1] *= cv;
    #pragma unroll
    for (int mc = 0; mc < 4; ++mc){
      bf16x8 pa  = *(const bf16x8*)(pw + (size_t)c16*136 + mc*32 + 8*g);
      bf16x8 vb0 = *(const bf16x8*)(vs + (size_t)c16*520      + kt*128 + mc*32 + 8*g);
      bf16x8 vb1 = *(const bf16x8*)(vs + (size_t)(16+c16)*520 + kt*128 + mc*32 + 8*g);
      outacc[0] = __builtin_amdgcn_mfma_f32_16x16x32_bf16(pa, vb0, outacc[0], 0, 0, 0);
      outacc[1] = __builtin_amdgcn_mfma_f32_16x16x32_bf16(pa, vb1, outacc[1], 0, 0, 0);
    }
  }
  float L[4];
  #pragma unroll
  for (int r = 0; r < 4; ++r){
    float s = lrun[r];
    #pragma unroll
    for (int mask = 1; mask <= 8; mask <<= 1) s += __shfl_xor(s, mask);
    L[r] = s;
  }
  // aT[b][c][w][f]: w = q0+4g+r, f = h*32 + dt*16 + c16
  size_t tbase = (size_t)b*CFW_ + (size_t)c*FW_;
  #pragma unroll
  for (int dt = 0; dt < 2; ++dt){
    #pragma unroll
    for (int r = 0; r < 4; ++r)
      aT[tbase + (size_t)(q0 + 4*g + r)*F_ + h*32 + dt*16 + c16]
        = f2bf(outacc[dt][r] / L[r]);
  }
}

// ---------------- depthwise feature convs (f32, batch-strided) ----------------
// grid (2, 256, 16 = b*8+c)
__global__ __launch_bounds__(256)
void dw_fuse_b(const float* __restrict__ Z, long zbs,
               const float* __restrict__ k11, const float* __restrict__ b11,
               const float* __restrict__ k7,  const float* __restrict__ b7,
               float* __restrict__ S, long sbs){
  int w = blockIdx.x*256 + threadIdx.x;
  int f = blockIdx.y;
  int bc = blockIdx.z; int b = bc >> 3, c = bc & 7;
  const float* zb = Z + (size_t)b*zbs + (size_t)c*FW_;
  float a = b11[c];
  #pragma unroll
  for (int i = 0; i < 11; ++i){
    int ff = f - 5 + i;
    if (ff >= 0 && ff < F_) a += k11[c*11 + i]*zb[(size_t)ff*W_ + w];
  }
  float bb = b7[c];
  #pragma unroll
  for (int i = 0; i < 7; ++i){
    int ff = f - 3 + i;
    if (ff >= 0 && ff < F_) bb += k7[c*7 + i]*zb[(size_t)ff*W_ + w];
  }
  float ra = a > 0.f ? a*a : 0.f;
  S[(size_t)b*sbs + ((size_t)c*F_ + f)*W_ + w] = ra + bb;
}

__global__ __launch_bounds__(256)
void conv7_add_b(const float* __restrict__ T, long tbs,
                 const float* __restrict__ k7, const float* __restrict__ b7,
                 float* __restrict__ Hp, long hbs){
  int w = blockIdx.x*256 + threadIdx.x;
  int f = blockIdx.y;
  int bc = blockIdx.z; int b = bc >> 3, c = bc & 7;
  const float* tb = T + (size_t)b*tbs + (size_t)c*FW_;
  float acc = b7[c];
  #pragma unroll
  for (int i = 0; i < 7; ++i){
    int ff = f - 3 + i;
    if (ff >= 0 && ff < F_) acc += k7[c*7 + i]*tb[(size_t)ff*W_ + w];
  }
  Hp[(size_t)b*hbs + ((size_t)c*F_ + f)*W_ + w] += acc;
}

// ---------------- FUSED FF: h += w4 @ sq_relu(w3 @ LN5(h)) ----------------
// grid (16, 8, 2), block 256 = 32 wl x 8 fs. In-place on h.
__global__ __launch_bounds__(256)
void ff_ln(float* __restrict__ Hp,
           const float* __restrict__ g, const float* __restrict__ bta,
           const float* __restrict__ w3, const float* __restrict__ w4){
  int wl = threadIdx.x & 31, fs = threadIdx.x >> 5;
  int w = blockIdx.x*32 + wl;
  int c = blockIdx.y, b = blockIdx.z;
  float* hcol = Hp + (size_t)b*OBS_ + (size_t)c*FW_ + w;
  float v[32];
  float sum = 0.f, sq = 0.f;
  #pragma unroll
  for (int i = 0; i < 32; ++i){
    v[i] = hcol[(size_t)(fs*32 + i)*W_];
    sum += v[i]; sq += v[i]*v[i];
  }
  __shared__ float Ss[8][32], Sq[8][32], Mu[32], Rs[32];
  Ss[fs][wl] = sum; Sq[fs][wl] = sq;
  __syncthreads();
  if (fs == 0){
    float s = 0.f, q = 0.f;
    #pragma unroll
    for (int j = 0; j < 8; ++j){ s += Ss[j][wl]; q += Sq[j][wl]; }
    float mu = s * (1.f/256.f);
    Mu[wl] = mu; Rs[wl] = rsqrtf(q * (1.f/256.f) - mu*mu + 1e-5f);
  }
  __syncthreads();
  float mu = Mu[wl], rs = Rs[wl];
  float u[4] = {0.f,0.f,0.f,0.f};
  #pragma unroll
  for (int i = 0; i < 32; ++i){
    int f = fs*32 + i;
    float z = (v[i] - mu)*rs*g[c*F_ + f] + bta[c*F_ + f];
    #pragma unroll
    for (int e = 0; e < 4; ++e) u[e] += w3[(c*4 + e)*F_ + f]*z;
  }
  __shared__ float Us[8][4][32];
  #pragma unroll
  for (int e = 0; e < 4; ++e) Us[fs][e][wl] = u[e];
  __syncthreads();
  float uf[4];
  #pragma unroll
  for (int e = 0; e < 4; ++e){
    float s = 0.f;
    #pragma unroll
    for (int j = 0; j < 8; ++j) s += Us[j][e][wl];
    float rr = s > 0.f ? s : 0.f;
    uf[e] = rr*rr;
  }
  #pragma unroll
  for (int i = 0; i < 32; ++i){
    int f = fs*32 + i;
    const float* w4r = w4 + (c*F_ + f)*4;
    hcol[(size_t)f*W_] = v[i] + w4r[0]*uf[0] + w4r[1]*uf[1] + w4r[2]*uf[2] + w4r[3]*uf[3];
  }
}

extern "C" void kernel_launch(void* const* d_in, const int* in_sizes, int n_in,
                              void* d_out, int out_size, void* d_ws, size_t ws_size,
                              hipStream_t stream){
  const float* x    = (const float*)d_in[0];
  const float* skip = (const float*)d_in[1];
  const float* Wq   = (const float*)d_in[2];
  const float* Kq   = (const float*)d_in[3];
  const float* bq   = (const float*)d_in[4];
  const float* Wk   = (const float*)d_in[5];
  const float* Kk   = (const float*)d_in[6];
  const float* bk   = (const float*)d_in[7];
  const float* Wv   = (const float*)d_in[8];
  const float* Kv   = (const float*)d_in[9];
  const float* bv   = (const float*)d_in[10];
  const float* Wo   = (const float*)d_in[11];
  const float* ng   = (const float*)d_in[12];
  const float* nb   = (const float*)d_in[13];
  const float* c1aw = (const float*)d_in[14];
  const float* c1ab = (const float*)d_in[15];
  const float* c1bw = (const float*)d_in[16];
  const float* c1bb = (const float*)d_in[17];
  const float* c2w  = (const float*)d_in[18];
  const float* c2b  = (const float*)d_in[19];
  const float* w3   = (const float*)d_in[20];
  const float* w4   = (const float*)d_in[21];

  float* out = (float*)d_out;
  float* hp  = out + CFW_;           // h at hp + b*OBS_ + c*FW_

  // ws layout (MiB offsets): bf16 weights 0..16, skipT 16, zT 20, t 24..36,
  // q 36, k 40, v 44, f32 zf 48, sf 56  (total 64 MiB)
  char* wsb = (char*)d_ws;
  u16* WQb  = (u16*)(wsb);
  u16* WKb  = (u16*)(wsb + ((size_t)4  << 20));
  u16* WVb  = (u16*)(wsb + ((size_t)8  << 20));
  u16* WOb  = (u16*)(wsb + ((size_t)12 << 20));
  u16* skT  = (u16*)(wsb + ((size_t)16 << 20));  // skip^T bf16 [b][c][w][f]
  u16* zT   = (u16*)(wsb + ((size_t)20 << 20));  // z^T bf16 [b][c][w][f]
  u16* tqkv = (u16*)(wsb + ((size_t)24 << 20));  // t: 3 proj x 2 b
  u16* qbB  = (u16*)(wsb + ((size_t)36 << 20));
  u16* kbB  = (u16*)(wsb + ((size_t)40 << 20));
  u16* vbB  = (u16*)(wsb + ((size_t)44 << 20));
  float* zf = (float*)(wsb + ((size_t)48 << 20));
  float* sf = (float*)(wsb + ((size_t)56 << 20));
  u16* aT   = tqkv;                  // attn out (transposed) aliases t

  float code = 0.f;
  if (n_in != 22) code += 20000.f;
  if (out_size != 4194304) code += 80000.f;
  if (ws_size < ((size_t)64 << 20)) code += 160000.f;

  dim3 gGemmQKV(8, 4, 48);
  dim3 gGemmWo(8, 4, 16);
  dim3 gLn(16, 8, 2);
  dim3 gPix(2, F_, 16);
  dim3 gAttn(128, 4);
  dim3 gCvtT(8, 4, 16);
  const int attn_lds_bytes = (512*40 + 32*520 + 8*16*136) * 2;  // 109056

  init_out<<<8192, 256, 0, stream>>>(x, out);
  cvt4<<<dim3(2048, 4), 256, 0, stream>>>(Wq, Wk, Wv, Wo, WQb, WKb, WVb, WOb);
  cvtT<<<gCvtT, 256, 0, stream>>>(skip, skT);

  auto do_attn = [&](int i, const u16* srcq, const u16* srckv){
    size_t wo16 = (size_t)i*C_*F_*F_;          // per-attn weight offset (u16)
    gemm_qkv_b<<<gGemmQKV, 256, 0, stream>>>(WQb + wo16, WKb + wo16, WVb + wo16,
                                             srcq, srckv, tqkv);
    conv_rope_lds<<<768, 256, 0, stream>>>(
        tqkv, Kq + i*C_*C_*3, bq + i*C_, Kk + i*C_*C_*3, bk + i*C_,
        Kv + i*C_*C_*3, bv + i*C_, qbB, kbB, vbB);
    attn_mfma_b<<<gAttn, 512, attn_lds_bytes, stream>>>(qbB, kbB, vbB, aT);
    gemm_wo_b<<<gGemmWo, 256, 0, stream>>>(WOb + wo16, aT, hp);
  };

  // z = LN0(x); h = x + att0(z,z) + att1(z,skip)
  ln32T<<<gLn, 256, 0, stream>>>(x, CFW_, zT, CFW_, ng + 0*C_*F_, nb + 0*C_*F_);
  do_attn(0, zT, zT);
  do_attn(1, zT, skT);

  // conv block (separate, high-occupancy kernels)
  ln32f<<<gLn, 256, 0, stream>>>(hp, OBS_, zf, CFW_, ng + 1*C_*F_, nb + 1*C_*F_);
  dw_fuse_b<<<gPix, 256, 0, stream>>>(zf, CFW_, c1aw, c1ab, c1bw, c1bb, sf, CFW_);
  ln32f<<<gLn, 256, 0, stream>>>(sf, CFW_, zf, CFW_, ng + 2*C_*F_, nb + 2*C_*F_);
  conv7_add_b<<<gPix, 256, 0, stream>>>(zf, CFW_, c2w, c2b, hp, OBS_);

  // att2 (self on LN3(h))
  ln32T<<<gLn, 256, 0, stream>>>(hp, OBS_, zT, CFW_, ng + 3*C_*F_, nb + 3*C_*F_);
  do_attn(2, zT, zT);

  // att3 (LN4(h) vs skip)
  ln32T<<<gLn, 256, 0, stream>>>(hp, OBS_, zT, CFW_, ng + 4*C_*F_, nb + 4*C_*F_);
  do_attn(3, zT, skT);

  // fused FF (in-place on h)
  ff_ln<<<gLn, 256, 0, stream>>>(hp, ng + 5*C_*F_, nb + 5*C_*F_, w3, w4);

  if (code != 0.f) put_val<<<1, 1, 0, stream>>>(out, code);
}

// Round 18
// 430.916 us; speedup vs baseline: 1.1284x; 1.0231x over previous
//
#include <hip/hip_runtime.h>

#define B_ 2
#define C_ 8
#define F_ 256
#define W_ 512
#define H_ 8
#define FW_ (F_*W_)        // 131072
#define CFW_ (C_*FW_)      // 1048576 = one batch of (C,F,W)
#define OBS_ (2*CFW_)      // out batch stride (B,16,F,W)

typedef unsigned short u16;

__device__ __forceinline__ u16 f2bf(float f){
  unsigned u = __float_as_uint(f);
  u += 0x7fffu + ((u>>16)&1u);
  return (u16)(u>>16);
}
__device__ __forceinline__ float bf2f(u16 u){
  return __uint_as_float((unsigned)u<<16);
}

typedef __attribute__((ext_vector_type(8))) short bf16x8;
typedef __attribute__((ext_vector_type(4))) float f32x4;

// ---------------- init: both halves of out = x ----------------
__global__ __launch_bounds__(256)
void init_out(const float* __restrict__ x, float* __restrict__ out){
  int i = blockIdx.x*256 + threadIdx.x;              // 2M
  int b = i >> 20;
  int r = i & (CFW_-1);
  float v = x[i];
  out[(size_t)b*OBS_ + r] = v;
  out[(size_t)b*OBS_ + CFW_ + r] = v;
}

__global__ void put_val(float* o, float v){ o[0] = v; }

// ---------------- bulk f32 -> bf16 conversion (4 weight arrays) --------------
__global__ __launch_bounds__(256)
void cvt4(const float* __restrict__ s0, const float* __restrict__ s1,
          const float* __restrict__ s2, const float* __restrict__ s3,
          u16* __restrict__ d0, u16* __restrict__ d1, u16* __restrict__ d2,
          u16* __restrict__ d3){
  int which = blockIdx.y;
  const float* s = which==0 ? s0 : which==1 ? s1 : which==2 ? s2 : s3;
  u16* d        = which==0 ? d0 : which==1 ? d1 : which==2 ? d2 : d3;
  int i = (blockIdx.x*256 + threadIdx.x)*4;          // 2048 blocks x 1024 elems
  float4 v = *(const float4*)(s + i);
  ushort4 o;
  o.x = f2bf(v.x); o.y = f2bf(v.y); o.z = f2bf(v.z); o.w = f2bf(v.w);
  *(ushort4*)(d + i) = o;
}

// ---------------- skip -> skip^T bf16 ([b][c][w][f]) via LDS 64x64 tile ------
// grid (8 w-tiles, 4 f-tiles, 16 = b*8+c), block 256
__global__ __launch_bounds__(256)
void cvtT(const float* __restrict__ src, u16* __restrict__ dst){
  __shared__ float Tin[64][65];
  int w0 = blockIdx.x*64, f0 = blockIdx.y*64;
  int bc = blockIdx.z; int b = bc >> 3, c = bc & 7;
  const float* s = src + (size_t)b*CFW_ + (size_t)c*FW_;
  int t = threadIdx.x;
  int r16 = t >> 4, c4 = (t & 15)*4;
  #pragma unroll
  for (int pass = 0; pass < 4; ++pass){
    int f = r16 + pass*16;
    float4 v = *(const float4*)(s + (size_t)(f0+f)*W_ + w0 + c4);
    Tin[f][c4+0] = v.x; Tin[f][c4+1] = v.y;
    Tin[f][c4+2] = v.z; Tin[f][c4+3] = v.w;
  }
  __syncthreads();
  u16* d = dst + (size_t)b*CFW_ + (size_t)c*FW_;     // [w][f] layout
  #pragma unroll
  for (int pass = 0; pass < 4; ++pass){
    int w = r16 + pass*16;
    ushort4 o;
    o.x = f2bf(Tin[c4+0][w]); o.y = f2bf(Tin[c4+1][w]);
    o.z = f2bf(Tin[c4+2][w]); o.w = f2bf(Tin[c4+3][w]);
    *(ushort4*)(d + (size_t)(w0+w)*F_ + f0 + c4) = o;
  }
}

// ---------------- LayerNorm over f -> TRANSPOSED bf16 z ([b][c][w][f]) -------
// grid (16, 8, 2), block 256 = 32 w-lanes x 8 f-slices
__global__ __launch_bounds__(256)
void ln32T(const float* __restrict__ X, long xbs, u16* __restrict__ Y, long ybs,
           const float* __restrict__ g, const float* __restrict__ bta){
  int wl = threadIdx.x & 31, fs = threadIdx.x >> 5;
  int w = blockIdx.x*32 + wl;
  int c = blockIdx.y;
  int b = blockIdx.z;
  const float* xb = X + (size_t)b*xbs + (size_t)c*FW_ + w;
  float v[32];
  float sum = 0.f, sq = 0.f;
  #pragma unroll
  for (int i = 0; i < 32; ++i){
    v[i] = xb[(size_t)(fs*32 + i)*W_];
    sum += v[i]; sq += v[i]*v[i];
  }
  __shared__ float Ss[8][32], Sq[8][32], Mu[32], Rs[32];
  Ss[fs][wl] = sum; Sq[fs][wl] = sq;
  __syncthreads();
  if (fs == 0){
    float s = 0.f, q = 0.f;
    #pragma unroll
    for (int j = 0; j < 8; ++j){ s += Ss[j][wl]; q += Sq[j][wl]; }
    float mu = s * (1.f/256.f);
    float var = q * (1.f/256.f) - mu*mu;
    Mu[wl] = mu; Rs[wl] = rsqrtf(var + 1e-5f);
  }
  __syncthreads();
  float mu = Mu[wl], rs = Rs[wl];
  u16* yb = Y + (size_t)b*ybs + ((size_t)c*W_ + w)*F_ + fs*32;
  #pragma unroll
  for (int i4 = 0; i4 < 8; ++i4){
    ushort4 o;
    int f = fs*32 + i4*4;
    o.x = f2bf((v[i4*4+0] - mu)*rs*g[c*F_ + f+0] + bta[c*F_ + f+0]);
    o.y = f2bf((v[i4*4+1] - mu)*rs*g[c*F_ + f+1] + bta[c*F_ + f+1]);
    o.z = f2bf((v[i4*4+2] - mu)*rs*g[c*F_ + f+2] + bta[c*F_ + f+2]);
    o.w = f2bf((v[i4*4+3] - mu)*rs*g[c*F_ + f+3] + bta[c*F_ + f+3]);
    *(ushort4*)(yb + i4*4) = o;
  }
}

// ---------------- LayerNorm over f -> f32 out (conv path) ----------------
// grid (16, 8, 2), block 256 = 32 w-lanes x 8 f-slices
__global__ __launch_bounds__(256)
void ln32f(const float* __restrict__ X, long xbs, float* __restrict__ Y, long ybs,
           const float* __restrict__ g, const float* __restrict__ bta){
  int wl = threadIdx.x & 31, fs = threadIdx.x >> 5;
  int w = blockIdx.x*32 + wl;
  int c = blockIdx.y;
  int b = blockIdx.z;
  const float* xb = X + (size_t)b*xbs + (size_t)c*FW_ + w;
  float v[32];
  float sum = 0.f, sq = 0.f;
  #pragma unroll
  for (int i = 0; i < 32; ++i){
    v[i] = xb[(size_t)(fs*32 + i)*W_];
    sum += v[i]; sq += v[i]*v[i];
  }
  __shared__ float Ss[8][32], Sq[8][32], Mu[32], Rs[32];
  Ss[fs][wl] = sum; Sq[fs][wl] = sq;
  __syncthreads();
  if (fs == 0){
    float s = 0.f, q = 0.f;
    #pragma unroll
    for (int j = 0; j < 8; ++j){ s += Ss[j][wl]; q += Sq[j][wl]; }
    float mu = s * (1.f/256.f);
    float var = q * (1.f/256.f) - mu*mu;
    Mu[wl] = mu; Rs[wl] = rsqrtf(var + 1e-5f);
  }
  __syncthreads();
  float mu = Mu[wl], rs = Rs[wl];
  float* yb = Y + (size_t)b*ybs + (size_t)c*FW_ + w;
  #pragma unroll
  for (int i = 0; i < 32; ++i){
    int f = fs*32 + i;
    yb[(size_t)f*W_] = (v[i] - mu)*rs*g[c*F_ + f] + bta[c*F_ + f];
  }
}

// ---------------- fused QKV MFMA GEMM, multi-attention ----------------
// grid (8 w-tiles, 4 g-tiles, 48*natt), block 256. att = zid/48.
// srcq (z^T) shared by both attentions; kv source per attention.
__global__ __launch_bounds__(256)
void gemm_qkv_m(const u16* __restrict__ wqb, const u16* __restrict__ wkb,
                const u16* __restrict__ wvb,
                const u16* __restrict__ srcq,
                const u16* __restrict__ kv0, const u16* __restrict__ kv1,
                u16* __restrict__ T, int i0, int i1){
  int zid = blockIdx.z;
  int att = (zid >= 48) ? 1 : 0;
  int rest = zid - att*48;
  int proj = rest >> 4;
  int bc = rest & 15; int b = bc >> 3, c = bc & 7;
  int wi = att ? i1 : i0;
  const u16* src = (proj == 0) ? srcq : (att ? kv1 : kv0);
  const u16* Wm  = (proj == 0) ? wqb : (proj == 1 ? wkb : wvb);
  const u16* AxT = src + (size_t)b*CFW_ + (size_t)c*FW_;   // [w][f]
  const u16* Bw = Wm + (size_t)wi*C_*F_*F_ + (size_t)c*F_*F_;
  u16* Yb = T + ((size_t)(att*3 + proj)*2 + b)*CFW_ + (size_t)c*FW_;

  int w0 = blockIdx.x * 64;
  int g0 = blockIdx.y * 64;
  int t = threadIdx.x, lane = t & 63, wv_ = t >> 6;
  int gq = lane >> 4, c16 = lane & 15;
  int wm = w0 + wv_*16 + c16;
  const f32x4 zero4 = {0.f,0.f,0.f,0.f};
  f32x4 acc[4] = {zero4, zero4, zero4, zero4};

  for (int k0 = 0; k0 < F_; k0 += 32){
    bf16x8 af = *(const bf16x8*)(AxT + (size_t)wm*F_ + k0 + 8*gq);
    #pragma unroll
    for (int nf = 0; nf < 4; ++nf){
      bf16x8 bfr = *(const bf16x8*)(Bw + (size_t)(g0 + nf*16 + c16)*F_ + k0 + 8*gq);
      acc[nf] = __builtin_amdgcn_mfma_f32_16x16x32_bf16(af, bfr, acc[nf], 0, 0, 0);
    }
  }
  int wout = w0 + wv_*16 + 4*gq;
  #pragma unroll
  for (int nf = 0; nf < 4; ++nf){
    ushort4 o;
    o.x = f2bf(acc[nf][0]); o.y = f2bf(acc[nf][1]);
    o.z = f2bf(acc[nf][2]); o.w = f2bf(acc[nf][3]);
    *(ushort4*)(Yb + (size_t)(g0 + nf*16 + c16)*W_ + wout) = o;
  }
}

// ---------------- Wo MFMA GEMM, multi-attention accumulate -------------------
// h(f32) += sum_att aT[att] @ Wo[i_att]. grid (8, 4, 16), block 256.
__global__ __launch_bounds__(256)
void gemm_wo_m(const u16* __restrict__ wob, const u16* __restrict__ A,
               float* __restrict__ Y, int i0, int i1, int natt){
  int bc = blockIdx.z; int b = bc >> 3, c = bc & 7;
  float* Yb = Y + (size_t)b*OBS_ + (size_t)c*FW_;
  int w0 = blockIdx.x * 64;
  int g0 = blockIdx.y * 64;
  int t = threadIdx.x, lane = t & 63, wv_ = t >> 6;
  int gq = lane >> 4, c16 = lane & 15;
  int wm = w0 + wv_*16 + c16;
  const f32x4 zero4 = {0.f,0.f,0.f,0.f};
  f32x4 acc[4] = {zero4, zero4, zero4, zero4};

  for (int att = 0; att < natt; ++att){
    const u16* AxT = A + ((size_t)(att*2) + b)*CFW_ + (size_t)c*FW_;  // [w][f]
    const u16* Bw = wob + (size_t)(att ? i1 : i0)*C_*F_*F_ + (size_t)c*F_*F_;
    for (int k0 = 0; k0 < F_; k0 += 32){
      bf16x8 af = *(const bf16x8*)(AxT + (size_t)wm*F_ + k0 + 8*gq);
      #pragma unroll
      for (int nf = 0; nf < 4; ++nf){
        bf16x8 bfr = *(const bf16x8*)(Bw + (size_t)(g0 + nf*16 + c16)*F_ + k0 + 8*gq);
        acc[nf] = __builtin_amdgcn_mfma_f32_16x16x32_bf16(af, bfr, acc[nf], 0, 0, 0);
      }
    }
  }
  int wout = w0 + wv_*16 + 4*gq;
  #pragma unroll
  for (int nf = 0; nf < 4; ++nf){
    float* y = Yb + (size_t)(g0 + nf*16 + c16)*W_ + wout;
    float4 o = *(float4*)y;
    o.x += acc[nf][0]; o.y += acc[nf][1]; o.z += acc[nf][2]; o.w += acc[nf][3];
    *(float4*)y = o;
  }
}

// ---------------- fused q/k/v 1x3 conv (+RoPE), LDS-staged, multi-att --------
// grid 768*natt, block 256. bx -> (att, p, b, jf).
__global__ __launch_bounds__(256)
void conv_rope_m(const u16* __restrict__ T,
                 const float* __restrict__ Kq3, const float* __restrict__ bq,
                 const float* __restrict__ Kk3, const float* __restrict__ bk,
                 const float* __restrict__ Kv3, const float* __restrict__ bv,
                 u16* __restrict__ Q, u16* __restrict__ K,
                 u16* __restrict__ V, int i0, int i1){
  __shared__ float Tin[16][514];                     // zero-padded halo
  __shared__ float Kc[192];                          // [co][ci][tap]
  int bx = blockIdx.x;
  int att = (bx >= 768) ? 1 : 0;
  int r = bx - att*768;
  int jf = r & 127;
  int b  = (r >> 7) & 1;
  int p  = r >> 8;                                   // 0..2 (block-uniform)
  int wi = att ? i1 : i0;
  const float* K3   = (p==0 ? Kq3 : (p==1 ? Kk3 : Kv3)) + (size_t)wi*C_*C_*3;
  const float* bias = (p==0 ? bq  : (p==1 ? bk  : bv)) + (size_t)wi*C_;
  const u16* Tb = T + ((size_t)(att*3 + p)*2 + b)*CFW_;
  u16* O = (p==0 ? Q : (p==1 ? K : V)) + ((size_t)att*2 + b)*CFW_;
  int f0 = jf*2;
  int t = threadIdx.x;

  if (t < 192) Kc[t] = K3[t];
  if (t < 16){ Tin[t][0] = 0.f; Tin[t][513] = 0.f; }
  for (int li = t; li < 16*128; li += 256){          // 128 ushort4 per row
    int row = li >> 7;                               // ci*2 + fsel
    int c4  = li & 127;
    int ci = row >> 1, fsel = row & 1;
    ushort4 v4 = *(const ushort4*)(Tb + ((size_t)ci*F_ + f0 + fsel)*W_ + c4*4);
    float* dst = &Tin[row][1 + c4*4];
    dst[0] = bf2f(v4.x); dst[1] = bf2f(v4.y);
    dst[2] = bf2f(v4.z); dst[3] = bf2f(v4.w);
  }
  __syncthreads();

  int co = t >> 5;                                   // 0..7
  int wg = t & 31;                                   // 0..31
  int wbase = wg*16;
  float bs = bias[co];
  float a0[16], a1[16];
  #pragma unroll
  for (int i = 0; i < 16; ++i){ a0[i] = bs; a1[i] = bs; }
  #pragma unroll
  for (int ci = 0; ci < 8; ++ci){
    const float* r0 = &Tin[ci*2+0][1 + wbase];
    const float* r1 = &Tin[ci*2+1][1 + wbase];
    float k0 = Kc[(co*8+ci)*3+0], k1 = Kc[(co*8+ci)*3+1], k2 = Kc[(co*8+ci)*3+2];
    #pragma unroll
    for (int i = 0; i < 16; ++i){
      a0[i] += k0*r0[i-1] + k1*r0[i] + k2*r0[i+1];
      a1[i] += k0*r1[i-1] + k1*r1[i] + k2*r1[i+1];
    }
  }
  size_t obase = ((size_t)co*F_ + f0)*W_ + wbase;
  if (p < 2){
    int j = jf & 15;                                 // freq index within head
    float inv = exp2f(-(float)j * 0.83048202372184f);  // 10000^(-j/16)
    float sv, cv, dsn, dcs;
    sincosf((float)wbase * inv, &sv, &cv);
    sincosf(inv, &dsn, &dcs);
    float scale = (p == 0) ? 0.0625f : 1.f;          // fold 1/sqrt(256) into q
    u16 o0[16], o1[16];
    #pragma unroll
    for (int i = 0; i < 16; ++i){
      o0[i] = f2bf((a0[i]*cv - a1[i]*sv)*scale);
      o1[i] = f2bf((a1[i]*cv + a0[i]*sv)*scale);
      float cn = cv*dcs - sv*dsn;                    // rotate by inv
      sv = sv*dcs + cv*dsn;
      cv = cn;
    }
    #pragma unroll
    for (int q4 = 0; q4 < 4; ++q4){
      *(ushort4*)(O + obase + q4*4)      = make_ushort4(o0[q4*4],o0[q4*4+1],o0[q4*4+2],o0[q4*4+3]);
      *(ushort4*)(O + obase + W_ + q4*4) = make_ushort4(o1[q4*4],o1[q4*4+1],o1[q4*4+2],o1[q4*4+3]);
    }
  } else {
    #pragma unroll
    for (int q4 = 0; q4 < 4; ++q4){
      ushort4 p0, p1;
      p0.x = f2bf(a0[q4*4+0]); p0.y = f2bf(a0[q4*4+1]);
      p0.z = f2bf(a0[q4*4+2]); p0.w = f2bf(a0[q4*4+3]);
      p1.x = f2bf(a1[q4*4+0]); p1.y = f2bf(a1[q4*4+1]);
      p1.z = f2bf(a1[q4*4+2]); p1.w = f2bf(a1[q4*4+3]);
      *(ushort4*)(O + obase + q4*4)      = p0;
      *(ushort4*)(O + obase + W_ + q4*4) = p1;
    }
  }
}

// ---------------- MFMA attention, multi-att, writes a TRANSPOSED -------------
// grid (128*natt, 4), block 512 (8 waves). att = bx>>7.
__global__ __launch_bounds__(512)
void attn_m(const u16* __restrict__ q, const u16* __restrict__ k,
            const u16* __restrict__ v, u16* __restrict__ aT){
  extern __shared__ __align__(16) unsigned char smem_dyn[];
  u16* ks = (u16*)smem_dyn;          // [512][40]
  u16* vs = ks + 512*40;             // [32][520]
  u16* ps = vs + 32*520;             // [8][16][136]
  int bx = blockIdx.x;
  int att = bx >> 7;
  int rb = bx & 127;
  int b = rb >> 6;
  int ch = rb & 63;
  int h = ch & 7, c = ch >> 3;
  size_t slot = ((size_t)att*2 + b)*CFW_;
  size_t base = slot + ((size_t)c*F_ + h*32)*W_;
  int t = threadIdx.x;
  int lane = t & 63, wv = t >> 6;
  int g = lane >> 4, c16 = lane & 15;

  int q0 = blockIdx.y*128 + wv*16;
  union { bf16x8 v8; u16 u[8]; } aq;
  #pragma unroll
  for (int j = 0; j < 8; ++j)
    aq.u[j] = q[base + (size_t)(8*g + j)*W_ + q0 + c16];

  for (int d = 0; d < 32; ++d)
    ks[t*40 + d] = k[base + (size_t)d*W_ + t];       // t = m (512)
  {
    int m8 = (t & 63)*8;
    #pragma unroll
    for (int it = 0; it < 4; ++it){
      int d = (t >> 6) + it*8;
      *(uint4*)(vs + (size_t)d*520 + m8) = *(const uint4*)(v + base + (size_t)d*W_ + m8);
    }
  }
  __syncthreads();

  u16* pw = ps + (size_t)wv*16*136;

  float mrun[4] = {-3e38f,-3e38f,-3e38f,-3e38f};
  float lrun[4] = {0.f,0.f,0.f,0.f};
  const f32x4 zero4 = {0.f,0.f,0.f,0.f};
  f32x4 outacc[2] = {zero4, zero4};

  for (int kt = 0; kt < 4; ++kt){
    f32x4 sv[8];
    #pragma unroll
    for (int mi = 0; mi < 8; ++mi){
      int m0 = kt*128 + mi*16;
      bf16x8 kb8 = *(const bf16x8*)(ks + (size_t)(m0 + c16)*40 + 8*g);
      sv[mi] = __builtin_amdgcn_mfma_f32_16x16x32_bf16(aq.v8, kb8, zero4, 0, 0, 0);
    }
    float pmax[4];
    #pragma unroll
    for (int r = 0; r < 4; ++r){
      float m = sv[0][r];
      #pragma unroll
      for (int mi = 1; mi < 8; ++mi) m = fmaxf(m, sv[mi][r]);
      pmax[r] = m;
    }
    #pragma unroll
    for (int mask = 1; mask <= 8; mask <<= 1){
      #pragma unroll
      for (int r = 0; r < 4; ++r)
        pmax[r] = fmaxf(pmax[r], __shfl_xor(pmax[r], mask));
    }
    float corr[4];
    #pragma unroll
    for (int r = 0; r < 4; ++r){
      float mn = fmaxf(mrun[r], pmax[r]);
      corr[r] = __expf(mrun[r] - mn);
      mrun[r] = mn;
      lrun[r] *= corr[r];
    }
    #pragma unroll
    for (int mi = 0; mi < 8; ++mi){
      #pragma unroll
      for (int r = 0; r < 4; ++r){
        float p = __expf(sv[mi][r] - mrun[r]);
        lrun[r] += p;
        pw[(size_t)(4*g + r)*136 + mi*16 + c16] = f2bf(p);
      }
    }
    f32x4 cv = {corr[0], corr[1], corr[2], corr[3]};
    outacc[0] *= cv;
    outacc[1] *= cv;
    #pragma unroll
    for (int mc = 0; mc < 4; ++mc){
      bf16x8 pa  = *(const bf16x8*)(pw + (size_t)c16*136 + mc*32 + 8*g);
      bf16x8 vb0 = *(const bf16x8*)(vs + (size_t)c16*520      + kt*128 + mc*32 + 8*g);
      bf16x8 vb1 = *(const bf16x8*)(vs + (size_t)(16+c16)*520 + kt*128 + mc*32 + 8*g);
      outacc[0] = __builtin_amdgcn_mfma_f32_16x16x32_bf16(pa, vb0, outacc[0], 0, 0, 0);
      outacc[1] = __builtin_amdgcn_mfma_f32_16x16x32_bf16(pa, vb1, outacc[1], 0, 0, 0);
    }
  }
  float L[4];
  #pragma unroll
  for (int r = 0; r < 4; ++r){
    float s = lrun[r];
    #pragma unroll
    for (int mask = 1; mask <= 8; mask <<= 1) s += __shfl_xor(s, mask);
    L[r] = s;
  }
  // aT slot [att*2+b] layout [c][w][f]
  size_t tbase = slot + (size_t)c*FW_;
  #pragma unroll
  for (int dt = 0; dt < 2; ++dt){
    #pragma unroll
    for (int r = 0; r < 4; ++r)
      aT[tbase + (size_t)(q0 + 4*g + r)*F_ + h*32 + dt*16 + c16]
        = f2bf(outacc[dt][r] / L[r]);
  }
}

// ---------------- depthwise feature convs (f32, batch-strided) ----------------
// grid (2, 256, 16 = b*8+c)
__global__ __launch_bounds__(256)
void dw_fuse_b(const float* __restrict__ Z, long zbs,
               const float* __restrict__ k11, const float* __restrict__ b11,
               const float* __restrict__ k7,  const float* __restrict__ b7,
               float* __restrict__ S, long sbs){
  int w = blockIdx.x*256 + threadIdx.x;
  int f = blockIdx.y;
  int bc = blockIdx.z; int b = bc >> 3, c = bc & 7;
  const float* zb = Z + (size_t)b*zbs + (size_t)c*FW_;
  float a = b11[c];
  #pragma unroll
  for (int i = 0; i < 11; ++i){
    int ff = f - 5 + i;
    if (ff >= 0 && ff < F_) a += k11[c*11 + i]*zb[(size_t)ff*W_ + w];
  }
  float bb = b7[c];
  #pragma unroll
  for (int i = 0; i < 7; ++i){
    int ff = f - 3 + i;
    if (ff >= 0 && ff < F_) bb += k7[c*7 + i]*zb[(size_t)ff*W_ + w];
  }
  float ra = a > 0.f ? a*a : 0.f;
  S[(size_t)b*sbs + ((size_t)c*F_ + f)*W_ + w] = ra + bb;
}

__global__ __launch_bounds__(256)
void conv7_add_b(const float* __restrict__ T, long tbs,
                 const float* __restrict__ k7, const float* __restrict__ b7,
                 float* __restrict__ Hp, long hbs){
  int w = blockIdx.x*256 + threadIdx.x;
  int f = blockIdx.y;
  int bc = blockIdx.z; int b = bc >> 3, c = bc & 7;
  const float* tb = T + (size_t)b*tbs + (size_t)c*FW_;
  float acc = b7[c];
  #pragma unroll
  for (int i = 0; i < 7; ++i){
    int ff = f - 3 + i;
    if (ff >= 0 && ff < F_) acc += k7[c*7 + i]*tb[(size_t)ff*W_ + w];
  }
  Hp[(size_t)b*hbs + ((size_t)c*F_ + f)*W_ + w] += acc;
}

// ---------------- FUSED FF: h += w4 @ sq_relu(w3 @ LN5(h)) ----------------
// grid (16, 8, 2), block 256 = 32 wl x 8 fs. In-place on h.
__global__ __launch_bounds__(256)
void ff_ln(float* __restrict__ Hp,
           const float* __restrict__ g, const float* __restrict__ bta,
           const float* __restrict__ w3, const float* __restrict__ w4){
  int wl = threadIdx.x & 31, fs = threadIdx.x >> 5;
  int w = blockIdx.x*32 + wl;
  int c = blockIdx.y, b = blockIdx.z;
  float* hcol = Hp + (size_t)b*OBS_ + (size_t)c*FW_ + w;
  float v[32];
  float sum = 0.f, sq = 0.f;
  #pragma unroll
  for (int i = 0; i < 32; ++i){
    v[i] = hcol[(size_t)(fs*32 + i)*W_];
    sum += v[i]; sq += v[i]*v[i];
  }
  __shared__ float Ss[8][32], Sq[8][32], Mu[32], Rs[32];
  Ss[fs][wl] = sum; Sq[fs][wl] = sq;
  __syncthreads();
  if (fs == 0){
    float s = 0.f, q = 0.f;
    #pragma unroll
    for (int j = 0; j < 8; ++j){ s += Ss[j][wl]; q += Sq[j][wl]; }
    float mu = s * (1.f/256.f);
    Mu[wl] = mu; Rs[wl] = rsqrtf(q * (1.f/256.f) - mu*mu + 1e-5f);
  }
  __syncthreads();
  float mu = Mu[wl], rs = Rs[wl];
  float u[4] = {0.f,0.f,0.f,0.f};
  #pragma unroll
  for (int i = 0; i < 32; ++i){
    int f = fs*32 + i;
    float z = (v[i] - mu)*rs*g[c*F_ + f] + bta[c*F_ + f];
    #pragma unroll
    for (int e = 0; e < 4; ++e) u[e] += w3[(c*4 + e)*F_ + f]*z;
  }
  __shared__ float Us[8][4][32];
  #pragma unroll
  for (int e = 0; e < 4; ++e) Us[fs][e][wl] = u[e];
  __syncthreads();
  float uf[4];
  #pragma unroll
  for (int e = 0; e < 4; ++e){
    float s = 0.f;
    #pragma unroll
    for (int j = 0; j < 8; ++j) s += Us[j][e][wl];
    float rr = s > 0.f ? s : 0.f;
    uf[e] = rr*rr;
  }
  #pragma unroll
  for (int i = 0; i < 32; ++i){
    int f = fs*32 + i;
    const float* w4r = w4 + (c*F_ + f)*4;
    hcol[(size_t)f*W_] = v[i] + w4r[0]*uf[0] + w4r[1]*uf[1] + w4r[2]*uf[2] + w4r[3]*uf[3];
  }
}

extern "C" void kernel_launch(void* const* d_in, const int* in_sizes, int n_in,
                              void* d_out, int out_size, void* d_ws, size_t ws_size,
                              hipStream_t stream){
  const float* x    = (const float*)d_in[0];
  const float* skip = (const float*)d_in[1];
  const float* Wq   = (const float*)d_in[2];
  const float* Kq   = (const float*)d_in[3];
  const float* bq   = (const float*)d_in[4];
  const float* Wk   = (const float*)d_in[5];
  const float* Kk   = (const float*)d_in[6];
  const float* bk   = (const float*)d_in[7];
  const float* Wv   = (const float*)d_in[8];
  const float* Kv   = (const float*)d_in[9];
  const float* bv   = (const float*)d_in[10];
  const float* Wo   = (const float*)d_in[11];
  const float* ng   = (const float*)d_in[12];
  const float* nb   = (const float*)d_in[13];
  const float* c1aw = (const float*)d_in[14];
  const float* c1ab = (const float*)d_in[15];
  const float* c1bw = (const float*)d_in[16];
  const float* c1bb = (const float*)d_in[17];
  const float* c2w  = (const float*)d_in[18];
  const float* c2b  = (const float*)d_in[19];
  const float* w3   = (const float*)d_in[20];
  const float* w4   = (const float*)d_in[21];

  float* out = (float*)d_out;
  float* hp  = out + CFW_;           // h at hp + b*OBS_ + c*FW_

  // ws layout (MiB): W 0..16, skT 16, zT 20, t 24..48 (6 slots x 2b),
  // q 48..56, k 56..64, v 64..72 (2 att x 2 b each), zf 72, sf 80 => 88 MiB
  char* wsb = (char*)d_ws;
  u16* WQb  = (u16*)(wsb);
  u16* WKb  = (u16*)(wsb + ((size_t)4  << 20));
  u16* WVb  = (u16*)(wsb + ((size_t)8  << 20));
  u16* WOb  = (u16*)(wsb + ((size_t)12 << 20));
  u16* skT  = (u16*)(wsb + ((size_t)16 << 20));  // skip^T bf16 [b][c][w][f]
  u16* zT   = (u16*)(wsb + ((size_t)20 << 20));  // z^T bf16 [b][c][w][f]
  u16* tqkv = (u16*)(wsb + ((size_t)24 << 20));  // t: (att*3+p)*2+b slots
  u16* qbB  = (u16*)(wsb + ((size_t)48 << 20));
  u16* kbB  = (u16*)(wsb + ((size_t)56 << 20));
  u16* vbB  = (u16*)(wsb + ((size_t)64 << 20));
  float* zf = (float*)(wsb + ((size_t)72 << 20));
  float* sf = (float*)(wsb + ((size_t)80 << 20));
  u16* aT   = tqkv;                  // attn out slots (att*2+b), aliases dead t

  float code = 0.f;
  if (n_in != 22) code += 20000.f;
  if (out_size != 4194304) code += 80000.f;
  if (ws_size < ((size_t)88 << 20)) code += 160000.f;

  dim3 gLn(16, 8, 2);
  dim3 gPix(2, F_, 16);
  dim3 gCvtT(8, 4, 16);
  const int attn_lds_bytes = (512*40 + 32*520 + 8*16*136) * 2;  // 109056

  init_out<<<8192, 256, 0, stream>>>(x, out);
  cvt4<<<dim3(2048, 4), 256, 0, stream>>>(Wq, Wk, Wv, Wo, WQb, WKb, WVb, WOb);
  cvtT<<<gCvtT, 256, 0, stream>>>(skip, skT);

  auto do_attn = [&](int i0, const u16* kv0, int i1, const u16* kv1, int natt){
    gemm_qkv_m<<<dim3(8, 4, 48*natt), 256, 0, stream>>>(
        WQb, WKb, WVb, zT, kv0, kv1, tqkv, i0, i1);
    conv_rope_m<<<768*natt, 256, 0, stream>>>(
        tqkv, Kq, bq, Kk, bk, Kv, bv, qbB, kbB, vbB, i0, i1);
    attn_m<<<dim3(128*natt, 4), 512, attn_lds_bytes, stream>>>(qbB, kbB, vbB, aT);
    gemm_wo_m<<<dim3(8, 4, 16), 256, 0, stream>>>(WOb, aT, hp, i0, i1, natt);
  };

  // z = LN0(x); h = x + att0(z,z) + att1(z,skip)  [att0 ∥ att1 merged]
  ln32T<<<gLn, 256, 0, stream>>>(x, CFW_, zT, CFW_, ng + 0*C_*F_, nb + 0*C_*F_);
  do_attn(0, zT, 1, skT, 2);

  // conv block (separate, high-occupancy kernels)
  ln32f<<<gLn, 256, 0, stream>>>(hp, OBS_, zf, CFW_, ng + 1*C_*F_, nb + 1*C_*F_);
  dw_fuse_b<<<gPix, 256, 0, stream>>>(zf, CFW_, c1aw, c1ab, c1bw, c1bb, sf, CFW_);
  ln32f<<<gLn, 256, 0, stream>>>(sf, CFW_, zf, CFW_, ng + 2*C_*F_, nb + 2*C_*F_);
  conv7_add_b<<<gPix, 256, 0, stream>>>(zf, CFW_, c2w, c2b, hp, OBS_);

  // att2 (self on LN3(h))
  ln32T<<<gLn, 256, 0, stream>>>(hp, OBS_, zT, CFW_, ng + 3*C_*F_, nb + 3*C_*F_);
  do_attn(2, zT, 2, zT, 1);

  // att3 (LN4(h) vs skip)
  ln32T<<<gLn, 256, 0, stream>>>(hp, OBS_, zT, CFW_, ng + 4*C_*F_, nb + 4*C_*F_);
  do_attn(3, skT, 3, skT, 1);

  // fused FF (in-place on h)
  ff_ln<<<gLn, 256, 0, stream>>>(hp, ng + 5*C_*F_, nb + 5*C_*F_, w3, w4);

  if (code != 0.f) put_val<<<1, 1, 0, stream>>>(out, code);
}

// Round 19
// 390.366 us; speedup vs baseline: 1.2456x; 1.1039x over previous
//
#include <hip/hip_runtime.h>

#define B_ 2
#define C_ 8
#define F_ 256
#define W_ 512
#define H_ 8
#define FW_ (F_*W_)        // 131072
#define CFW_ (C_*FW_)      // 1048576 = one batch of (C,F,W)
#define OBS_ (2*CFW_)      // out batch stride (B,16,F,W)

typedef unsigned short u16;

__device__ __forceinline__ u16 f2bf(float f){
  unsigned u = __float_as_uint(f);
  u += 0x7fffu + ((u>>16)&1u);
  return (u16)(u>>16);
}
__device__ __forceinline__ float bf2f(u16 u){
  return __uint_as_float((unsigned)u<<16);
}

typedef __attribute__((ext_vector_type(8))) short bf16x8;
typedef __attribute__((ext_vector_type(4))) float f32x4;

// ---------------- init: both halves of out = x ----------------
__global__ __launch_bounds__(256)
void init_out(const float* __restrict__ x, float* __restrict__ out){
  int i = blockIdx.x*256 + threadIdx.x;              // 2M
  int b = i >> 20;
  int r = i & (CFW_-1);
  float v = x[i];
  out[(size_t)b*OBS_ + r] = v;
  out[(size_t)b*OBS_ + CFW_ + r] = v;
}

__global__ void put_val(float* o, float v){ o[0] = v; }

// ---------------- bulk f32 -> bf16 conversion (4 weight arrays) --------------
__global__ __launch_bounds__(256)
void cvt4(const float* __restrict__ s0, const float* __restrict__ s1,
          const float* __restrict__ s2, const float* __restrict__ s3,
          u16* __restrict__ d0, u16* __restrict__ d1, u16* __restrict__ d2,
          u16* __restrict__ d3){
  int which = blockIdx.y;
  const float* s = which==0 ? s0 : which==1 ? s1 : which==2 ? s2 : s3;
  u16* d        = which==0 ? d0 : which==1 ? d1 : which==2 ? d2 : d3;
  int i = (blockIdx.x*256 + threadIdx.x)*4;          // 2048 blocks x 1024 elems
  float4 v = *(const float4*)(s + i);
  ushort4 o;
  o.x = f2bf(v.x); o.y = f2bf(v.y); o.z = f2bf(v.z); o.w = f2bf(v.w);
  *(ushort4*)(d + i) = o;
}

// ---------------- skip -> skip^T bf16 ([b][c][w][f]) via LDS 64x64 tile ------
// grid (8 w-tiles, 4 f-tiles, 16 = b*8+c), block 256
__global__ __launch_bounds__(256)
void cvtT(const float* __restrict__ src, u16* __restrict__ dst){
  __shared__ float Tin[64][65];
  int w0 = blockIdx.x*64, f0 = blockIdx.y*64;
  int bc = blockIdx.z; int b = bc >> 3, c = bc & 7;
  const float* s = src + (size_t)b*CFW_ + (size_t)c*FW_;
  int t = threadIdx.x;
  int r16 = t >> 4, c4 = (t & 15)*4;
  #pragma unroll
  for (int pass = 0; pass < 4; ++pass){
    int f = r16 + pass*16;
    float4 v = *(const float4*)(s + (size_t)(f0+f)*W_ + w0 + c4);
    Tin[f][c4+0] = v.x; Tin[f][c4+1] = v.y;
    Tin[f][c4+2] = v.z; Tin[f][c4+3] = v.w;
  }
  __syncthreads();
  u16* d = dst + (size_t)b*CFW_ + (size_t)c*FW_;     // [w][f] layout
  #pragma unroll
  for (int pass = 0; pass < 4; ++pass){
    int w = r16 + pass*16;
    ushort4 o;
    o.x = f2bf(Tin[c4+0][w]); o.y = f2bf(Tin[c4+1][w]);
    o.z = f2bf(Tin[c4+2][w]); o.w = f2bf(Tin[c4+3][w]);
    *(ushort4*)(d + (size_t)(w0+w)*F_ + f0 + c4) = o;
  }
}

// ---------------- LayerNorm over f -> TRANSPOSED bf16 z ([b][c][w][f]) -------
// grid (16, 8, 2), block 256 = 32 w-lanes x 8 f-slices
__global__ __launch_bounds__(256)
void ln32T(const float* __restrict__ X, long xbs, u16* __restrict__ Y, long ybs,
           const float* __restrict__ g, const float* __restrict__ bta){
  int wl = threadIdx.x & 31, fs = threadIdx.x >> 5;
  int w = blockIdx.x*32 + wl;
  int c = blockIdx.y;
  int b = blockIdx.z;
  const float* xb = X + (size_t)b*xbs + (size_t)c*FW_ + w;
  float v[32];
  float sum = 0.f, sq = 0.f;
  #pragma unroll
  for (int i = 0; i < 32; ++i){
    v[i] = xb[(size_t)(fs*32 + i)*W_];
    sum += v[i]; sq += v[i]*v[i];
  }
  __shared__ float Ss[8][32], Sq[8][32], Mu[32], Rs[32];
  Ss[fs][wl] = sum; Sq[fs][wl] = sq;
  __syncthreads();
  if (fs == 0){
    float s = 0.f, q = 0.f;
    #pragma unroll
    for (int j = 0; j < 8; ++j){ s += Ss[j][wl]; q += Sq[j][wl]; }
    float mu = s * (1.f/256.f);
    float var = q * (1.f/256.f) - mu*mu;
    Mu[wl] = mu; Rs[wl] = rsqrtf(var + 1e-5f);
  }
  __syncthreads();
  float mu = Mu[wl], rs = Rs[wl];
  u16* yb = Y + (size_t)b*ybs + ((size_t)c*W_ + w)*F_ + fs*32;
  #pragma unroll
  for (int i4 = 0; i4 < 8; ++i4){
    ushort4 o;
    int f = fs*32 + i4*4;
    o.x = f2bf((v[i4*4+0] - mu)*rs*g[c*F_ + f+0] + bta[c*F_ + f+0]);
    o.y = f2bf((v[i4*4+1] - mu)*rs*g[c*F_ + f+1] + bta[c*F_ + f+1]);
    o.z = f2bf((v[i4*4+2] - mu)*rs*g[c*F_ + f+2] + bta[c*F_ + f+2]);
    o.w = f2bf((v[i4*4+3] - mu)*rs*g[c*F_ + f+3] + bta[c*F_ + f+3]);
    *(ushort4*)(yb + i4*4) = o;
  }
}

// ---------------- LayerNorm over f -> f32 out (conv path) ----------------
// grid (16, 8, 2), block 256 = 32 w-lanes x 8 f-slices
__global__ __launch_bounds__(256)
void ln32f(const float* __restrict__ X, long xbs, float* __restrict__ Y, long ybs,
           const float* __restrict__ g, const float* __restrict__ bta){
  int wl = threadIdx.x & 31, fs = threadIdx.x >> 5;
  int w = blockIdx.x*32 + wl;
  int c = blockIdx.y;
  int b = blockIdx.z;
  const float* xb = X + (size_t)b*xbs + (size_t)c*FW_ + w;
  float v[32];
  float sum = 0.f, sq = 0.f;
  #pragma unroll
  for (int i = 0; i < 32; ++i){
    v[i] = xb[(size_t)(fs*32 + i)*W_];
    sum += v[i]; sq += v[i]*v[i];
  }
  __shared__ float Ss[8][32], Sq[8][32], Mu[32], Rs[32];
  Ss[fs][wl] = sum; Sq[fs][wl] = sq;
  __syncthreads();
  if (fs == 0){
    float s = 0.f, q = 0.f;
    #pragma unroll
    for (int j = 0; j < 8; ++j){ s += Ss[j][wl]; q += Sq[j][wl]; }
    float mu = s * (1.f/256.f);
    float var = q * (1.f/256.f) - mu*mu;
    Mu[wl] = mu; Rs[wl] = rsqrtf(var + 1e-5f);
  }
  __syncthreads();
  float mu = Mu[wl], rs = Rs[wl];
  float* yb = Y + (size_t)b*ybs + (size_t)c*FW_ + w;
  #pragma unroll
  for (int i = 0; i < 32; ++i){
    int f = fs*32 + i;
    yb[(size_t)f*W_] = (v[i] - mu)*rs*g[c*F_ + f] + bta[c*F_ + f];
  }
}

// ---------------- fused QKV MFMA GEMM, multi-attention, 128w tile ------------
// grid (W/128=4, F/64=4, 48*natt), block 256. att = zid/48.
// Each thread: 2 w-frags x 4 g-frags (B reused 2x), k-loop unrolled 2.
__global__ __launch_bounds__(256)
void gemm_qkv_m(const u16* __restrict__ wqb, const u16* __restrict__ wkb,
                const u16* __restrict__ wvb,
                const u16* __restrict__ srcq,
                const u16* __restrict__ kv0, const u16* __restrict__ kv1,
                u16* __restrict__ T, int i0, int i1){
  int zid = blockIdx.z;
  int att = (zid >= 48) ? 1 : 0;
  int rest = zid - att*48;
  int proj = rest >> 4;
  int bc = rest & 15; int b = bc >> 3, c = bc & 7;
  int wi = att ? i1 : i0;
  const u16* src = (proj == 0) ? srcq : (att ? kv1 : kv0);
  const u16* Wm  = (proj == 0) ? wqb : (proj == 1 ? wkb : wvb);
  const u16* AxT = src + (size_t)b*CFW_ + (size_t)c*FW_;   // [w][f]
  const u16* Bw = Wm + (size_t)wi*C_*F_*F_ + (size_t)c*F_*F_;
  u16* Yb = T + ((size_t)(att*3 + proj)*2 + b)*CFW_ + (size_t)c*FW_;

  int w0 = blockIdx.x * 128;
  int g0 = blockIdx.y * 64;
  int t = threadIdx.x, lane = t & 63, wv_ = t >> 6;
  int gq = lane >> 4, c16 = lane & 15;
  int wm = w0 + wv_*16 + c16;
  const u16* Ap0 = AxT + (size_t)wm*F_ + 8*gq;
  const u16* Ap1 = Ap0 + (size_t)64*F_;
  const u16* Bp  = Bw + (size_t)(g0 + c16)*F_ + 8*gq;
  const f32x4 zero4 = {0.f,0.f,0.f,0.f};
  f32x4 acc0[4] = {zero4, zero4, zero4, zero4};
  f32x4 acc1[4] = {zero4, zero4, zero4, zero4};

  #pragma unroll 2
  for (int k0 = 0; k0 < F_; k0 += 32){
    bf16x8 a0 = *(const bf16x8*)(Ap0 + k0);
    bf16x8 a1 = *(const bf16x8*)(Ap1 + k0);
    #pragma unroll
    for (int nf = 0; nf < 4; ++nf){
      bf16x8 bfr = *(const bf16x8*)(Bp + (size_t)nf*16*F_ + k0);
      acc0[nf] = __builtin_amdgcn_mfma_f32_16x16x32_bf16(a0, bfr, acc0[nf], 0, 0, 0);
      acc1[nf] = __builtin_amdgcn_mfma_f32_16x16x32_bf16(a1, bfr, acc1[nf], 0, 0, 0);
    }
  }
  int wout = w0 + wv_*16 + 4*gq;
  #pragma unroll
  for (int nf = 0; nf < 4; ++nf){
    u16* yrow = Yb + (size_t)(g0 + nf*16 + c16)*W_;
    ushort4 o0, o1;
    o0.x = f2bf(acc0[nf][0]); o0.y = f2bf(acc0[nf][1]);
    o0.z = f2bf(acc0[nf][2]); o0.w = f2bf(acc0[nf][3]);
    o1.x = f2bf(acc1[nf][0]); o1.y = f2bf(acc1[nf][1]);
    o1.z = f2bf(acc1[nf][2]); o1.w = f2bf(acc1[nf][3]);
    *(ushort4*)(yrow + wout)      = o0;
    *(ushort4*)(yrow + wout + 64) = o1;
  }
}

// ---------------- Wo MFMA GEMM, multi-attention accumulate -------------------
// h(f32) += sum_att aT[att] @ Wo[i_att]. grid (8, 4, 16), block 256.
__global__ __launch_bounds__(256)
void gemm_wo_m(const u16* __restrict__ wob, const u16* __restrict__ A,
               float* __restrict__ Y, int i0, int i1, int natt){
  int bc = blockIdx.z; int b = bc >> 3, c = bc & 7;
  float* Yb = Y + (size_t)b*OBS_ + (size_t)c*FW_;
  int w0 = blockIdx.x * 64;
  int g0 = blockIdx.y * 64;
  int t = threadIdx.x, lane = t & 63, wv_ = t >> 6;
  int gq = lane >> 4, c16 = lane & 15;
  int wm = w0 + wv_*16 + c16;
  const f32x4 zero4 = {0.f,0.f,0.f,0.f};
  f32x4 acc[4] = {zero4, zero4, zero4, zero4};

  for (int att = 0; att < natt; ++att){
    const u16* AxT = A + ((size_t)(att*2) + b)*CFW_ + (size_t)c*FW_;  // [w][f]
    const u16* Bw = wob + (size_t)(att ? i1 : i0)*C_*F_*F_ + (size_t)c*F_*F_;
    for (int k0 = 0; k0 < F_; k0 += 32){
      bf16x8 af = *(const bf16x8*)(AxT + (size_t)wm*F_ + k0 + 8*gq);
      #pragma unroll
      for (int nf = 0; nf < 4; ++nf){
        bf16x8 bfr = *(const bf16x8*)(Bw + (size_t)(g0 + nf*16 + c16)*F_ + k0 + 8*gq);
        acc[nf] = __builtin_amdgcn_mfma_f32_16x16x32_bf16(af, bfr, acc[nf], 0, 0, 0);
      }
    }
  }
  int wout = w0 + wv_*16 + 4*gq;
  #pragma unroll
  for (int nf = 0; nf < 4; ++nf){
    float* y = Yb + (size_t)(g0 + nf*16 + c16)*W_ + wout;
    float4 o = *(float4*)y;
    o.x += acc[nf][0]; o.y += acc[nf][1]; o.z += acc[nf][2]; o.w += acc[nf][3];
    *(float4*)y = o;
  }
}

// ---------------- fused q/k/v 1x3 conv (+RoPE), LDS-staged, multi-att --------
// grid 768*natt, block 256. bx -> (att, p, b, jf).
__global__ __launch_bounds__(256)
void conv_rope_m(const u16* __restrict__ T,
                 const float* __restrict__ Kq3, const float* __restrict__ bq,
                 const float* __restrict__ Kk3, const float* __restrict__ bk,
                 const float* __restrict__ Kv3, const float* __restrict__ bv,
                 u16* __restrict__ Q, u16* __restrict__ K,
                 u16* __restrict__ V, int i0, int i1){
  __shared__ float Tin[16][514];                     // zero-padded halo
  __shared__ float Kc[192];                          // [co][ci][tap]
  int bx = blockIdx.x;
  int att = (bx >= 768) ? 1 : 0;
  int r = bx - att*768;
  int jf = r & 127;
  int b  = (r >> 7) & 1;
  int p  = r >> 8;                                   // 0..2 (block-uniform)
  int wi = att ? i1 : i0;
  const float* K3   = (p==0 ? Kq3 : (p==1 ? Kk3 : Kv3)) + (size_t)wi*C_*C_*3;
  const float* bias = (p==0 ? bq  : (p==1 ? bk  : bv)) + (size_t)wi*C_;
  const u16* Tb = T + ((size_t)(att*3 + p)*2 + b)*CFW_;
  u16* O = (p==0 ? Q : (p==1 ? K : V)) + ((size_t)att*2 + b)*CFW_;
  int f0 = jf*2;
  int t = threadIdx.x;

  if (t < 192) Kc[t] = K3[t];
  if (t < 16){ Tin[t][0] = 0.f; Tin[t][513] = 0.f; }
  for (int li = t; li < 16*128; li += 256){          // 128 ushort4 per row
    int row = li >> 7;                               // ci*2 + fsel
    int c4  = li & 127;
    int ci = row >> 1, fsel = row & 1;
    ushort4 v4 = *(const ushort4*)(Tb + ((size_t)ci*F_ + f0 + fsel)*W_ + c4*4);
    float* dst = &Tin[row][1 + c4*4];
    dst[0] = bf2f(v4.x); dst[1] = bf2f(v4.y);
    dst[2] = bf2f(v4.z); dst[3] = bf2f(v4.w);
  }
  __syncthreads();

  int co = t >> 5;                                   // 0..7
  int wg = t & 31;                                   // 0..31
  int wbase = wg*16;
  float bs = bias[co];
  float a0[16], a1[16];
  #pragma unroll
  for (int i = 0; i < 16; ++i){ a0[i] = bs; a1[i] = bs; }
  #pragma unroll
  for (int ci = 0; ci < 8; ++ci){
    const float* r0 = &Tin[ci*2+0][1 + wbase];
    const float* r1 = &Tin[ci*2+1][1 + wbase];
    float k0 = Kc[(co*8+ci)*3+0], k1 = Kc[(co*8+ci)*3+1], k2 = Kc[(co*8+ci)*3+2];
    #pragma unroll
    for (int i = 0; i < 16; ++i){
      a0[i] += k0*r0[i-1] + k1*r0[i] + k2*r0[i+1];
      a1[i] += k0*r1[i-1] + k1*r1[i] + k2*r1[i+1];
    }
  }
  size_t obase = ((size_t)co*F_ + f0)*W_ + wbase;
  if (p < 2){
    int j = jf & 15;                                 // freq index within head
    float inv = exp2f(-(float)j * 0.83048202372184f);  // 10000^(-j/16)
    float sv, cv, dsn, dcs;
    sincosf((float)wbase * inv, &sv, &cv);
    sincosf(inv, &dsn, &dcs);
    float scale = (p == 0) ? 0.0625f : 1.f;          // fold 1/sqrt(256) into q
    u16 o0[16], o1[16];
    #pragma unroll
    for (int i = 0; i < 16; ++i){
      o0[i] = f2bf((a0[i]*cv - a1[i]*sv)*scale);
      o1[i] = f2bf((a1[i]*cv + a0[i]*sv)*scale);
      float cn = cv*dcs - sv*dsn;                    // rotate by inv
      sv = sv*dcs + cv*dsn;
      cv = cn;
    }
    #pragma unroll
    for (int q4 = 0; q4 < 4; ++q4){
      *(ushort4*)(O + obase + q4*4)      = make_ushort4(o0[q4*4],o0[q4*4+1],o0[q4*4+2],o0[q4*4+3]);
      *(ushort4*)(O + obase + W_ + q4*4) = make_ushort4(o1[q4*4],o1[q4*4+1],o1[q4*4+2],o1[q4*4+3]);
    }
  } else {
    #pragma unroll
    for (int q4 = 0; q4 < 4; ++q4){
      ushort4 p0, p1;
      p0.x = f2bf(a0[q4*4+0]); p0.y = f2bf(a0[q4*4+1]);
      p0.z = f2bf(a0[q4*4+2]); p0.w = f2bf(a0[q4*4+3]);
      p1.x = f2bf(a1[q4*4+0]); p1.y = f2bf(a1[q4*4+1]);
      p1.z = f2bf(a1[q4*4+2]); p1.w = f2bf(a1[q4*4+3]);
      *(ushort4*)(O + obase + q4*4)      = p0;
      *(ushort4*)(O + obase + W_ + q4*4) = p1;
    }
  }
}

// ---------------- MFMA attention, multi-att, writes a TRANSPOSED -------------
// grid (128*natt, 4), block 512 (8 waves). att = bx>>7.
__global__ __launch_bounds__(512)
void attn_m(const u16* __restrict__ q, const u16* __restrict__ k,
            const u16* __restrict__ v, u16* __restrict__ aT){
  extern __shared__ __align__(16) unsigned char smem_dyn[];
  u16* ks = (u16*)smem_dyn;          // [512][40]
  u16* vs = ks + 512*40;             // [32][520]
  u16* ps = vs + 32*520;             // [8][16][136]
  int bx = blockIdx.x;
  int att = bx >> 7;
  int rb = bx & 127;
  int b = rb >> 6;
  int ch = rb & 63;
  int h = ch & 7, c = ch >> 3;
  size_t slot = ((size_t)att*2 + b)*CFW_;
  size_t base = slot + ((size_t)c*F_ + h*32)*W_;
  int t = threadIdx.x;
  int lane = t & 63, wv = t >> 6;
  int g = lane >> 4, c16 = lane & 15;

  int q0 = blockIdx.y*128 + wv*16;
  union { bf16x8 v8; u16 u[8]; } aq;
  #pragma unroll
  for (int j = 0; j < 8; ++j)
    aq.u[j] = q[base + (size_t)(8*g + j)*W_ + q0 + c16];

  for (int d = 0; d < 32; ++d)
    ks[t*40 + d] = k[base + (size_t)d*W_ + t];       // t = m (512)
  {
    int m8 = (t & 63)*8;
    #pragma unroll
    for (int it = 0; it < 4; ++it){
      int d = (t >> 6) + it*8;
      *(uint4*)(vs + (size_t)d*520 + m8) = *(const uint4*)(v + base + (size_t)d*W_ + m8);
    }
  }
  __syncthreads();

  u16* pw = ps + (size_t)wv*16*136;

  float mrun[4] = {-3e38f,-3e38f,-3e38f,-3e38f};
  float lrun[4] = {0.f,0.f,0.f,0.f};
  const f32x4 zero4 = {0.f,0.f,0.f,0.f};
  f32x4 outacc[2] = {zero4, zero4};

  for (int kt = 0; kt < 4; ++kt){
    f32x4 sv[8];
    #pragma unroll
    for (int mi = 0; mi < 8; ++mi){
      int m0 = kt*128 + mi*16;
      bf16x8 kb8 = *(const bf16x8*)(ks + (size_t)(m0 + c16)*40 + 8*g);
      sv[mi] = __builtin_amdgcn_mfma_f32_16x16x32_bf16(aq.v8, kb8, zero4, 0, 0, 0);
    }
    float pmax[4];
    #pragma unroll
    for (int r = 0; r < 4; ++r){
      float m = sv[0][r];
      #pragma unroll
      for (int mi = 1; mi < 8; ++mi) m = fmaxf(m, sv[mi][r]);
      pmax[r] = m;
    }
    #pragma unroll
    for (int mask = 1; mask <= 8; mask <<= 1){
      #pragma unroll
      for (int r = 0; r < 4; ++r)
        pmax[r] = fmaxf(pmax[r], __shfl_xor(pmax[r], mask));
    }
    float corr[4];
    #pragma unroll
    for (int r = 0; r < 4; ++r){
      float mn = fmaxf(mrun[r], pmax[r]);
      corr[r] = __expf(mrun[r] - mn);
      mrun[r] = mn;
      lrun[r] *= corr[r];
    }
    #pragma unroll
    for (int mi = 0; mi < 8; ++mi){
      #pragma unroll
      for (int r = 0; r < 4; ++r){
        float p = __expf(sv[mi][r] - mrun[r]);
        lrun[r] += p;
        pw[(size_t)(4*g + r)*136 + mi*16 + c16] = f2bf(p);
      }
    }
    f32x4 cv = {corr[0], corr[1], corr[2], corr[3]};
    outacc[0] *= cv;
    outacc[1] *= cv;
    #pragma unroll
    for (int mc = 0; mc < 4; ++mc){
      bf16x8 pa  = *(const bf16x8*)(pw + (size_t)c16*136 + mc*32 + 8*g);
      bf16x8 vb0 = *(const bf16x8*)(vs + (size_t)c16*520      + kt*128 + mc*32 + 8*g);
      bf16x8 vb1 = *(const bf16x8*)(vs + (size_t)(16+c16)*520 + kt*128 + mc*32 + 8*g);
      outacc[0] = __builtin_amdgcn_mfma_f32_16x16x32_bf16(pa, vb0, outacc[0], 0, 0, 0);
      outacc[1] = __builtin_amdgcn_mfma_f32_16x16x32_bf16(pa, vb1, outacc[1], 0, 0, 0);
    }
  }
  float L[4];
  #pragma unroll
  for (int r = 0; r < 4; ++r){
    float s = lrun[r];
    #pragma unroll
    for (int mask = 1; mask <= 8; mask <<= 1) s += __shfl_xor(s, mask);
    L[r] = s;
  }
  // aT slot [att*2+b] layout [c][w][f]
  size_t tbase = slot + (size_t)c*FW_;
  #pragma unroll
  for (int dt = 0; dt < 2; ++dt){
    #pragma unroll
    for (int r = 0; r < 4; ++r)
      aT[tbase + (size_t)(q0 + 4*g + r)*F_ + h*32 + dt*16 + c16]
        = f2bf(outacc[dt][r] / L[r]);
  }
}

// ---------------- depthwise feature convs (f32, batch-strided) ----------------
// grid (2, 256, 16 = b*8+c)
__global__ __launch_bounds__(256)
void dw_fuse_b(const float* __restrict__ Z, long zbs,
               const float* __restrict__ k11, const float* __restrict__ b11,
               const float* __restrict__ k7,  const float* __restrict__ b7,
               float* __restrict__ S, long sbs){
  int w = blockIdx.x*256 + threadIdx.x;
  int f = blockIdx.y;
  int bc = blockIdx.z; int b = bc >> 3, c = bc & 7;
  const float* zb = Z + (size_t)b*zbs + (size_t)c*FW_;
  float a = b11[c];
  #pragma unroll
  for (int i = 0; i < 11; ++i){
    int ff = f - 5 + i;
    if (ff >= 0 && ff < F_) a += k11[c*11 + i]*zb[(size_t)ff*W_ + w];
  }
  float bb = b7[c];
  #pragma unroll
  for (int i = 0; i < 7; ++i){
    int ff = f - 3 + i;
    if (ff >= 0 && ff < F_) bb += k7[c*7 + i]*zb[(size_t)ff*W_ + w];
  }
  float ra = a > 0.f ? a*a : 0.f;
  S[(size_t)b*sbs + ((size_t)c*F_ + f)*W_ + w] = ra + bb;
}

__global__ __launch_bounds__(256)
void conv7_add_b(const float* __restrict__ T, long tbs,
                 const float* __restrict__ k7, const float* __restrict__ b7,
                 float* __restrict__ Hp, long hbs){
  int w = blockIdx.x*256 + threadIdx.x;
  int f = blockIdx.y;
  int bc = blockIdx.z; int b = bc >> 3, c = bc & 7;
  const float* tb = T + (size_t)b*tbs + (size_t)c*FW_;
  float acc = b7[c];
  #pragma unroll
  for (int i = 0; i < 7; ++i){
    int ff = f - 3 + i;
    if (ff >= 0 && ff < F_) acc += k7[c*7 + i]*tb[(size_t)ff*W_ + w];
  }
  Hp[(size_t)b*hbs + ((size_t)c*F_ + f)*W_ + w] += acc;
}

// ---------------- FUSED FF: h += w4 @ sq_relu(w3 @ LN5(h)) ----------------
// grid (16, 8, 2), block 256 = 32 wl x 8 fs. In-place on h.
__global__ __launch_bounds__(256)
void ff_ln(float* __restrict__ Hp,
           const float* __restrict__ g, const float* __restrict__ bta,
           const float* __restrict__ w3, const float* __restrict__ w4){
  int wl = threadIdx.x & 31, fs = threadIdx.x >> 5;
  int w = blockIdx.x*32 + wl;
  int c = blockIdx.y, b = blockIdx.z;
  float* hcol = Hp + (size_t)b*OBS_ + (size_t)c*FW_ + w;
  float v[32];
  float sum = 0.f, sq = 0.f;
  #pragma unroll
  for (int i = 0; i < 32; ++i){
    v[i] = hcol[(size_t)(fs*32 + i)*W_];
    sum += v[i]; sq += v[i]*v[i];
  }
  __shared__ float Ss[8][32], Sq[8][32], Mu[32], Rs[32];
  Ss[fs][wl] = sum; Sq[fs][wl] = sq;
  __syncthreads();
  if (fs == 0){
    float s = 0.f, q = 0.f;
    #pragma unroll
    for (int j = 0; j < 8; ++j){ s += Ss[j][wl]; q += Sq[j][wl]; }
    float mu = s * (1.f/256.f);
    Mu[wl] = mu; Rs[wl] = rsqrtf(q * (1.f/256.f) - mu*mu + 1e-5f);
  }
  __syncthreads();
  float mu = Mu[wl], rs = Rs[wl];
  float u[4] = {0.f,0.f,0.f,0.f};
  #pragma unroll
  for (int i = 0; i < 32; ++i){
    int f = fs*32 + i;
    float z = (v[i] - mu)*rs*g[c*F_ + f] + bta[c*F_ + f];
    #pragma unroll
    for (int e = 0; e < 4; ++e) u[e] += w3[(c*4 + e)*F_ + f]*z;
  }
  __shared__ float Us[8][4][32];
  #pragma unroll
  for (int e = 0; e < 4; ++e) Us[fs][e][wl] = u[e];
  __syncthreads();
  float uf[4];
  #pragma unroll
  for (int e = 0; e < 4; ++e){
    float s = 0.f;
    #pragma unroll
    for (int j = 0; j < 8; ++j) s += Us[j][e][wl];
    float rr = s > 0.f ? s : 0.f;
    uf[e] = rr*rr;
  }
  #pragma unroll
  for (int i = 0; i < 32; ++i){
    int f = fs*32 + i;
    const float* w4r = w4 + (c*F_ + f)*4;
    hcol[(size_t)f*W_] = v[i] + w4r[0]*uf[0] + w4r[1]*uf[1] + w4r[2]*uf[2] + w4r[3]*uf[3];
  }
}

extern "C" void kernel_launch(void* const* d_in, const int* in_sizes, int n_in,
                              void* d_out, int out_size, void* d_ws, size_t ws_size,
                              hipStream_t stream){
  const float* x    = (const float*)d_in[0];
  const float* skip = (const float*)d_in[1];
  const float* Wq   = (const float*)d_in[2];
  const float* Kq   = (const float*)d_in[3];
  const float* bq   = (const float*)d_in[4];
  const float* Wk   = (const float*)d_in[5];
  const float* Kk   = (const float*)d_in[6];
  const float* bk   = (const float*)d_in[7];
  const float* Wv   = (const float*)d_in[8];
  const float* Kv   = (const float*)d_in[9];
  const float* bv   = (const float*)d_in[10];
  const float* Wo   = (const float*)d_in[11];
  const float* ng   = (const float*)d_in[12];
  const float* nb   = (const float*)d_in[13];
  const float* c1aw = (const float*)d_in[14];
  const float* c1ab = (const float*)d_in[15];
  const float* c1bw = (const float*)d_in[16];
  const float* c1bb = (const float*)d_in[17];
  const float* c2w  = (const float*)d_in[18];
  const float* c2b  = (const float*)d_in[19];
  const float* w3   = (const float*)d_in[20];
  const float* w4   = (const float*)d_in[21];

  float* out = (float*)d_out;
  float* hp  = out + CFW_;           // h at hp + b*OBS_ + c*FW_

  // ws layout (MiB): W 0..16, skT 16, zT 20, t 24..48 (6 slots x 2b),
  // q 48..56, k 56..64, v 64..72 (2 att x 2 b each), zf 72, sf 80 => 88 MiB
  char* wsb = (char*)d_ws;
  u16* WQb  = (u16*)(wsb);
  u16* WKb  = (u16*)(wsb + ((size_t)4  << 20));
  u16* WVb  = (u16*)(wsb + ((size_t)8  << 20));
  u16* WOb  = (u16*)(wsb + ((size_t)12 << 20));
  u16* skT  = (u16*)(wsb + ((size_t)16 << 20));  // skip^T bf16 [b][c][w][f]
  u16* zT   = (u16*)(wsb + ((size_t)20 << 20));  // z^T bf16 [b][c][w][f]
  u16* tqkv = (u16*)(wsb + ((size_t)24 << 20));  // t: (att*3+p)*2+b slots
  u16* qbB  = (u16*)(wsb + ((size_t)48 << 20));
  u16* kbB  = (u16*)(wsb + ((size_t)56 << 20));
  u16* vbB  = (u16*)(wsb + ((size_t)64 << 20));
  float* zf = (float*)(wsb + ((size_t)72 << 20));
  float* sf = (float*)(wsb + ((size_t)80 << 20));
  u16* aT   = tqkv;                  // attn out slots (att*2+b), aliases dead t

  float code = 0.f;
  if (n_in != 22) code += 20000.f;
  if (out_size != 4194304) code += 80000.f;
  if (ws_size < ((size_t)88 << 20)) code += 160000.f;

  dim3 gLn(16, 8, 2);
  dim3 gPix(2, F_, 16);
  dim3 gCvtT(8, 4, 16);
  const int attn_lds_bytes = (512*40 + 32*520 + 8*16*136) * 2;  // 109056

  init_out<<<8192, 256, 0, stream>>>(x, out);
  cvt4<<<dim3(2048, 4), 256, 0, stream>>>(Wq, Wk, Wv, Wo, WQb, WKb, WVb, WOb);
  cvtT<<<gCvtT, 256, 0, stream>>>(skip, skT);

  auto do_attn = [&](int i0, const u16* kv0, int i1, const u16* kv1, int natt){
    gemm_qkv_m<<<dim3(4, 4, 48*natt), 256, 0, stream>>>(
        WQb, WKb, WVb, zT, kv0, kv1, tqkv, i0, i1);
    conv_rope_m<<<768*natt, 256, 0, stream>>>(
        tqkv, Kq, bq, Kk, bk, Kv, bv, qbB, kbB, vbB, i0, i1);
    attn_m<<<dim3(128*natt, 4), 512, attn_lds_bytes, stream>>>(qbB, kbB, vbB, aT);
    gemm_wo_m<<<dim3(8, 4, 16), 256, 0, stream>>>(WOb, aT, hp, i0, i1, natt);
  };

  // z = LN0(x); h = x + att0(z,z) + att1(z,skip)  [att0 ∥ att1 merged]
  ln32T<<<gLn, 256, 0, stream>>>(x, CFW_, zT, CFW_, ng + 0*C_*F_, nb + 0*C_*F_);
  do_attn(0, zT, 1, skT, 2);

  // conv block (separate, high-occupancy kernels)
  ln32f<<<gLn, 256, 0, stream>>>(hp, OBS_, zf, CFW_, ng + 1*C_*F_, nb + 1*C_*F_);
  dw_fuse_b<<<gPix, 256, 0, stream>>>(zf, CFW_, c1aw, c1ab, c1bw, c1bb, sf, CFW_);
  ln32f<<<gLn, 256, 0, stream>>>(sf, CFW_, zf, CFW_, ng + 2*C_*F_, nb + 2*C_*F_);
  conv7_add_b<<<gPix, 256, 0, stream>>>(zf, CFW_, c2w, c2b, hp, OBS_);

  // att2 (self on LN3(h))
  ln32T<<<gLn, 256, 0, stream>>>(hp, OBS_, zT, CFW_, ng + 3*C_*F_, nb + 3*C_*F_);
  do_attn(2, zT, 2, zT, 1);

  // att3 (LN4(h) vs skip)
  ln32T<<<gLn, 256, 0, stream>>>(hp, OBS_, zT, CFW_, ng + 4*C_*F_, nb + 4*C_*F_);
  do_attn(3, skT, 3, skT, 1);

  // fused FF (in-place on h)
  ff_ln<<<gLn, 256, 0, stream>>>(hp, ng + 5*C_*F_, nb + 5*C_*F_, w3, w4);

  if (code != 0.f) put_val<<<1, 1, 0, stream>>>(out, code);
}

// Round 20
// 383.937 us; speedup vs baseline: 1.2665x; 1.0167x over previous
//
#include <hip/hip_runtime.h>

#define B_ 2
#define C_ 8
#define F_ 256
#define W_ 512
#define H_ 8
#define FW_ (F_*W_)        // 131072
#define CFW_ (C_*FW_)      // 1048576 = one batch of (C,F,W)
#define OBS_ (2*CFW_)      // out batch stride (B,16,F,W)

typedef unsigned short u16;

__device__ __forceinline__ u16 f2bf(float f){
  unsigned u = __float_as_uint(f);
  u += 0x7fffu + ((u>>16)&1u);
  return (u16)(u>>16);
}
__device__ __forceinline__ float bf2f(u16 u){
  return __uint_as_float((unsigned)u<<16);
}

typedef __attribute__((ext_vector_type(8))) short bf16x8;
typedef __attribute__((ext_vector_type(4))) float f32x4;

// ---------------- init: both halves of out = x ----------------
__global__ __launch_bounds__(256)
void init_out(const float* __restrict__ x, float* __restrict__ out){
  int i = blockIdx.x*256 + threadIdx.x;              // 2M
  int b = i >> 20;
  int r = i & (CFW_-1);
  float v = x[i];
  out[(size_t)b*OBS_ + r] = v;
  out[(size_t)b*OBS_ + CFW_ + r] = v;
}

__global__ void put_val(float* o, float v){ o[0] = v; }

// ---------------- bulk f32 -> bf16 conversion (4 weight arrays) --------------
__global__ __launch_bounds__(256)
void cvt4(const float* __restrict__ s0, const float* __restrict__ s1,
          const float* __restrict__ s2, const float* __restrict__ s3,
          u16* __restrict__ d0, u16* __restrict__ d1, u16* __restrict__ d2,
          u16* __restrict__ d3){
  int which = blockIdx.y;
  const float* s = which==0 ? s0 : which==1 ? s1 : which==2 ? s2 : s3;
  u16* d        = which==0 ? d0 : which==1 ? d1 : which==2 ? d2 : d3;
  int i = (blockIdx.x*256 + threadIdx.x)*4;          // 2048 blocks x 1024 elems
  float4 v = *(const float4*)(s + i);
  ushort4 o;
  o.x = f2bf(v.x); o.y = f2bf(v.y); o.z = f2bf(v.z); o.w = f2bf(v.w);
  *(ushort4*)(d + i) = o;
}

// ---------------- skip -> skip^T bf16 ([b][c][w][f]) via LDS 64x64 tile ------
// grid (8 w-tiles, 4 f-tiles, 16 = b*8+c), block 256
__global__ __launch_bounds__(256)
void cvtT(const float* __restrict__ src, u16* __restrict__ dst){
  __shared__ float Tin[64][65];
  int w0 = blockIdx.x*64, f0 = blockIdx.y*64;
  int bc = blockIdx.z; int b = bc >> 3, c = bc & 7;
  const float* s = src + (size_t)b*CFW_ + (size_t)c*FW_;
  int t = threadIdx.x;
  int r16 = t >> 4, c4 = (t & 15)*4;
  #pragma unroll
  for (int pass = 0; pass < 4; ++pass){
    int f = r16 + pass*16;
    float4 v = *(const float4*)(s + (size_t)(f0+f)*W_ + w0 + c4);
    Tin[f][c4+0] = v.x; Tin[f][c4+1] = v.y;
    Tin[f][c4+2] = v.z; Tin[f][c4+3] = v.w;
  }
  __syncthreads();
  u16* d = dst + (size_t)b*CFW_ + (size_t)c*FW_;     // [w][f] layout
  #pragma unroll
  for (int pass = 0; pass < 4; ++pass){
    int w = r16 + pass*16;
    ushort4 o;
    o.x = f2bf(Tin[c4+0][w]); o.y = f2bf(Tin[c4+1][w]);
    o.z = f2bf(Tin[c4+2][w]); o.w = f2bf(Tin[c4+3][w]);
    *(ushort4*)(d + (size_t)(w0+w)*F_ + f0 + c4) = o;
  }
}

// ---------------- LayerNorm over f -> TRANSPOSED bf16 z ([b][c][w][f]) -------
// grid (16, 8, 2), block 256 = 32 w-lanes x 8 f-slices
__global__ __launch_bounds__(256)
void ln32T(const float* __restrict__ X, long xbs, u16* __restrict__ Y, long ybs,
           const float* __restrict__ g, const float* __restrict__ bta){
  int wl = threadIdx.x & 31, fs = threadIdx.x >> 5;
  int w = blockIdx.x*32 + wl;
  int c = blockIdx.y;
  int b = blockIdx.z;
  const float* xb = X + (size_t)b*xbs + (size_t)c*FW_ + w;
  float v[32];
  float sum = 0.f, sq = 0.f;
  #pragma unroll
  for (int i = 0; i < 32; ++i){
    v[i] = xb[(size_t)(fs*32 + i)*W_];
    sum += v[i]; sq += v[i]*v[i];
  }
  __shared__ float Ss[8][32], Sq[8][32], Mu[32], Rs[32];
  Ss[fs][wl] = sum; Sq[fs][wl] = sq;
  __syncthreads();
  if (fs == 0){
    float s = 0.f, q = 0.f;
    #pragma unroll
    for (int j = 0; j < 8; ++j){ s += Ss[j][wl]; q += Sq[j][wl]; }
    float mu = s * (1.f/256.f);
    float var = q * (1.f/256.f) - mu*mu;
    Mu[wl] = mu; Rs[wl] = rsqrtf(var + 1e-5f);
  }
  __syncthreads();
  float mu = Mu[wl], rs = Rs[wl];
  u16* yb = Y + (size_t)b*ybs + ((size_t)c*W_ + w)*F_ + fs*32;
  #pragma unroll
  for (int i4 = 0; i4 < 8; ++i4){
    ushort4 o;
    int f = fs*32 + i4*4;
    o.x = f2bf((v[i4*4+0] - mu)*rs*g[c*F_ + f+0] + bta[c*F_ + f+0]);
    o.y = f2bf((v[i4*4+1] - mu)*rs*g[c*F_ + f+1] + bta[c*F_ + f+1]);
    o.z = f2bf((v[i4*4+2] - mu)*rs*g[c*F_ + f+2] + bta[c*F_ + f+2]);
    o.w = f2bf((v[i4*4+3] - mu)*rs*g[c*F_ + f+3] + bta[c*F_ + f+3]);
    *(ushort4*)(yb + i4*4) = o;
  }
}

// ---------------- LayerNorm over f -> f32 out (conv path) ----------------
// grid (16, 8, 2), block 256 = 32 w-lanes x 8 f-slices
__global__ __launch_bounds__(256)
void ln32f(const float* __restrict__ X, long xbs, float* __restrict__ Y, long ybs,
           const float* __restrict__ g, const float* __restrict__ bta){
  int wl = threadIdx.x & 31, fs = threadIdx.x >> 5;
  int w = blockIdx.x*32 + wl;
  int c = blockIdx.y;
  int b = blockIdx.z;
  const float* xb = X + (size_t)b*xbs + (size_t)c*FW_ + w;
  float v[32];
  float sum = 0.f, sq = 0.f;
  #pragma unroll
  for (int i = 0; i < 32; ++i){
    v[i] = xb[(size_t)(fs*32 + i)*W_];
    sum += v[i]; sq += v[i]*v[i];
  }
  __shared__ float Ss[8][32], Sq[8][32], Mu[32], Rs[32];
  Ss[fs][wl] = sum; Sq[fs][wl] = sq;
  __syncthreads();
  if (fs == 0){
    float s = 0.f, q = 0.f;
    #pragma unroll
    for (int j = 0; j < 8; ++j){ s += Ss[j][wl]; q += Sq[j][wl]; }
    float mu = s * (1.f/256.f);
    float var = q * (1.f/256.f) - mu*mu;
    Mu[wl] = mu; Rs[wl] = rsqrtf(var + 1e-5f);
  }
  __syncthreads();
  float mu = Mu[wl], rs = Rs[wl];
  float* yb = Y + (size_t)b*ybs + (size_t)c*FW_ + w;
  #pragma unroll
  for (int i = 0; i < 32; ++i){
    int f = fs*32 + i;
    yb[(size_t)f*W_] = (v[i] - mu)*rs*g[c*F_ + f] + bta[c*F_ + f];
  }
}

// ---------------- fused QKV MFMA GEMM, multi-attention, 128w tile ------------
// grid (W/128=4, F/64=4, 48*natt), block 256. att = zid/48.
__global__ __launch_bounds__(256)
void gemm_qkv_m(const u16* __restrict__ wqb, const u16* __restrict__ wkb,
                const u16* __restrict__ wvb,
                const u16* __restrict__ srcq,
                const u16* __restrict__ kv0, const u16* __restrict__ kv1,
                u16* __restrict__ T, int i0, int i1){
  int zid = blockIdx.z;
  int att = (zid >= 48) ? 1 : 0;
  int rest = zid - att*48;
  int proj = rest >> 4;
  int bc = rest & 15; int b = bc >> 3, c = bc & 7;
  int wi = att ? i1 : i0;
  const u16* src = (proj == 0) ? srcq : (att ? kv1 : kv0);
  const u16* Wm  = (proj == 0) ? wqb : (proj == 1 ? wkb : wvb);
  const u16* AxT = src + (size_t)b*CFW_ + (size_t)c*FW_;   // [w][f]
  const u16* Bw = Wm + (size_t)wi*C_*F_*F_ + (size_t)c*F_*F_;
  u16* Yb = T + ((size_t)(att*3 + proj)*2 + b)*CFW_ + (size_t)c*FW_;

  int w0 = blockIdx.x * 128;
  int g0 = blockIdx.y * 64;
  int t = threadIdx.x, lane = t & 63, wv_ = t >> 6;
  int gq = lane >> 4, c16 = lane & 15;
  int wm = w0 + wv_*16 + c16;
  const u16* Ap0 = AxT + (size_t)wm*F_ + 8*gq;
  const u16* Ap1 = Ap0 + (size_t)64*F_;
  const u16* Bp  = Bw + (size_t)(g0 + c16)*F_ + 8*gq;
  const f32x4 zero4 = {0.f,0.f,0.f,0.f};
  f32x4 acc0[4] = {zero4, zero4, zero4, zero4};
  f32x4 acc1[4] = {zero4, zero4, zero4, zero4};

  #pragma unroll 2
  for (int k0 = 0; k0 < F_; k0 += 32){
    bf16x8 a0 = *(const bf16x8*)(Ap0 + k0);
    bf16x8 a1 = *(const bf16x8*)(Ap1 + k0);
    #pragma unroll
    for (int nf = 0; nf < 4; ++nf){
      bf16x8 bfr = *(const bf16x8*)(Bp + (size_t)nf*16*F_ + k0);
      acc0[nf] = __builtin_amdgcn_mfma_f32_16x16x32_bf16(a0, bfr, acc0[nf], 0, 0, 0);
      acc1[nf] = __builtin_amdgcn_mfma_f32_16x16x32_bf16(a1, bfr, acc1[nf], 0, 0, 0);
    }
  }
  int wout = w0 + wv_*16 + 4*gq;
  #pragma unroll
  for (int nf = 0; nf < 4; ++nf){
    u16* yrow = Yb + (size_t)(g0 + nf*16 + c16)*W_;
    ushort4 o0, o1;
    o0.x = f2bf(acc0[nf][0]); o0.y = f2bf(acc0[nf][1]);
    o0.z = f2bf(acc0[nf][2]); o0.w = f2bf(acc0[nf][3]);
    o1.x = f2bf(acc1[nf][0]); o1.y = f2bf(acc1[nf][1]);
    o1.z = f2bf(acc1[nf][2]); o1.w = f2bf(acc1[nf][3]);
    *(ushort4*)(yrow + wout)      = o0;
    *(ushort4*)(yrow + wout + 64) = o1;
  }
}

// ---------------- Wo MFMA GEMM, multi-attention accumulate -------------------
// h(f32) += sum_att aT[att] @ Wo[i_att]. grid (8, 4, 16), block 256.
__global__ __launch_bounds__(256)
void gemm_wo_m(const u16* __restrict__ wob, const u16* __restrict__ A,
               float* __restrict__ Y, int i0, int i1, int natt){
  int bc = blockIdx.z; int b = bc >> 3, c = bc & 7;
  float* Yb = Y + (size_t)b*OBS_ + (size_t)c*FW_;
  int w0 = blockIdx.x * 64;
  int g0 = blockIdx.y * 64;
  int t = threadIdx.x, lane = t & 63, wv_ = t >> 6;
  int gq = lane >> 4, c16 = lane & 15;
  int wm = w0 + wv_*16 + c16;
  const f32x4 zero4 = {0.f,0.f,0.f,0.f};
  f32x4 acc[4] = {zero4, zero4, zero4, zero4};

  for (int att = 0; att < natt; ++att){
    const u16* AxT = A + ((size_t)(att*2) + b)*CFW_ + (size_t)c*FW_;  // [w][f]
    const u16* Bw = wob + (size_t)(att ? i1 : i0)*C_*F_*F_ + (size_t)c*F_*F_;
    for (int k0 = 0; k0 < F_; k0 += 32){
      bf16x8 af = *(const bf16x8*)(AxT + (size_t)wm*F_ + k0 + 8*gq);
      #pragma unroll
      for (int nf = 0; nf < 4; ++nf){
        bf16x8 bfr = *(const bf16x8*)(Bw + (size_t)(g0 + nf*16 + c16)*F_ + k0 + 8*gq);
        acc[nf] = __builtin_amdgcn_mfma_f32_16x16x32_bf16(af, bfr, acc[nf], 0, 0, 0);
      }
    }
  }
  int wout = w0 + wv_*16 + 4*gq;
  #pragma unroll
  for (int nf = 0; nf < 4; ++nf){
    float* y = Yb + (size_t)(g0 + nf*16 + c16)*W_ + wout;
    float4 o = *(float4*)y;
    o.x += acc[nf][0]; o.y += acc[nf][1]; o.z += acc[nf][2]; o.w += acc[nf][3];
    *(float4*)y = o;
  }
}

// ---------------- fused q/k/v 1x3 conv (+RoPE), LDS-staged, multi-att --------
// grid 768*natt, block 256. bx -> (att, p, b, jf).
// Conflict-free LDS: float4-aligned staging (4-float halo) + interleaved w
// ownership (thread wg handles w = wg + 32*i) so reads hit distinct banks.
__global__ __launch_bounds__(256)
void conv_rope_m(const u16* __restrict__ T,
                 const float* __restrict__ Kq3, const float* __restrict__ bq,
                 const float* __restrict__ Kk3, const float* __restrict__ bk,
                 const float* __restrict__ Kv3, const float* __restrict__ bv,
                 u16* __restrict__ Q, u16* __restrict__ K,
                 u16* __restrict__ V, int i0, int i1){
  __shared__ float Tin[16][520];                     // data at [4..516), halo 3,516
  __shared__ float Kc[192];                          // [co][ci][tap]
  int bx = blockIdx.x;
  int att = (bx >= 768) ? 1 : 0;
  int r = bx - att*768;
  int jf = r & 127;
  int b  = (r >> 7) & 1;
  int p  = r >> 8;                                   // 0..2 (block-uniform)
  int wi = att ? i1 : i0;
  const float* K3   = (p==0 ? Kq3 : (p==1 ? Kk3 : Kv3)) + (size_t)wi*C_*C_*3;
  const float* bias = (p==0 ? bq  : (p==1 ? bk  : bv)) + (size_t)wi*C_;
  const u16* Tb = T + ((size_t)(att*3 + p)*2 + b)*CFW_;
  u16* O = (p==0 ? Q : (p==1 ? K : V)) + ((size_t)att*2 + b)*CFW_;
  int f0 = jf*2;
  int t = threadIdx.x;

  if (t < 192) Kc[t] = K3[t];
  if (t < 16){ Tin[t][3] = 0.f; Tin[t][516] = 0.f; }
  for (int li = t; li < 16*128; li += 256){          // 128 float4 per row
    int row = li >> 7;                               // ci*2 + fsel
    int c4  = li & 127;
    int ci = row >> 1, fsel = row & 1;
    ushort4 v4 = *(const ushort4*)(Tb + ((size_t)ci*F_ + f0 + fsel)*W_ + c4*4);
    float4 f4;
    f4.x = bf2f(v4.x); f4.y = bf2f(v4.y);
    f4.z = bf2f(v4.z); f4.w = bf2f(v4.w);
    *(float4*)&Tin[row][4 + c4*4] = f4;              // aligned, lane-contiguous
  }
  __syncthreads();

  int co = t >> 5;                                   // 0..7
  int wg = t & 31;                                   // 0..31; w = wg + 32*i
  float bs = bias[co];
  float a0[16], a1[16];
  #pragma unroll
  for (int i = 0; i < 16; ++i){ a0[i] = bs; a1[i] = bs; }
  #pragma unroll
  for (int ci = 0; ci < 8; ++ci){
    const float* r0 = &Tin[ci*2+0][4 + wg];
    const float* r1 = &Tin[ci*2+1][4 + wg];
    float k0 = Kc[(co*8+ci)*3+0], k1 = Kc[(co*8+ci)*3+1], k2 = Kc[(co*8+ci)*3+2];
    #pragma unroll
    for (int i = 0; i < 16; ++i){
      int off = 32*i;
      a0[i] += k0*r0[off-1] + k1*r0[off] + k2*r0[off+1];
      a1[i] += k0*r1[off-1] + k1*r1[off] + k2*r1[off+1];
    }
  }
  size_t ob0 = ((size_t)co*F_ + f0)*W_ + wg;
  size_t ob1 = ob0 + W_;
  if (p < 2){
    int j = jf & 15;                                 // freq index within head
    float inv = exp2f(-(float)j * 0.83048202372184f);  // 10000^(-j/16)
    float sv, cv, dsn, dcs;
    sincosf((float)wg * inv, &sv, &cv);
    sincosf(32.f * inv, &dsn, &dcs);                 // rotation step for w += 32
    float scale = (p == 0) ? 0.0625f : 1.f;          // fold 1/sqrt(256) into q
    #pragma unroll
    for (int i = 0; i < 16; ++i){
      O[ob0 + 32*i] = f2bf((a0[i]*cv - a1[i]*sv)*scale);
      O[ob1 + 32*i] = f2bf((a1[i]*cv + a0[i]*sv)*scale);
      float cn = cv*dcs - sv*dsn;                    // rotate by 32*inv
      sv = sv*dcs + cv*dsn;
      cv = cn;
    }
  } else {
    #pragma unroll
    for (int i = 0; i < 16; ++i){
      O[ob0 + 32*i] = f2bf(a0[i]);
      O[ob1 + 32*i] = f2bf(a1[i]);
    }
  }
}

// ---------------- MFMA attention, multi-att, writes a TRANSPOSED -------------
// grid (128*natt, 4), block 512 (8 waves). att = bx>>7.
__global__ __launch_bounds__(512)
void attn_m(const u16* __restrict__ q, const u16* __restrict__ k,
            const u16* __restrict__ v, u16* __restrict__ aT){
  extern __shared__ __align__(16) unsigned char smem_dyn[];
  u16* ks = (u16*)smem_dyn;          // [512][40]
  u16* vs = ks + 512*40;             // [32][520]
  u16* ps = vs + 32*520;             // [8][16][136]
  int bx = blockIdx.x;
  int att = bx >> 7;
  int rb = bx & 127;
  int b = rb >> 6;
  int ch = rb & 63;
  int h = ch & 7, c = ch >> 3;
  size_t slot = ((size_t)att*2 + b)*CFW_;
  size_t base = slot + ((size_t)c*F_ + h*32)*W_;
  int t = threadIdx.x;
  int lane = t & 63, wv = t >> 6;
  int g = lane >> 4, c16 = lane & 15;

  int q0 = blockIdx.y*128 + wv*16;
  union { bf16x8 v8; u16 u[8]; } aq;
  #pragma unroll
  for (int j = 0; j < 8; ++j)
    aq.u[j] = q[base + (size_t)(8*g + j)*W_ + q0 + c16];

  for (int d = 0; d < 32; ++d)
    ks[t*40 + d] = k[base + (size_t)d*W_ + t];       // t = m (512)
  {
    int m8 = (t & 63)*8;
    #pragma unroll
    for (int it = 0; it < 4; ++it){
      int d = (t >> 6) + it*8;
      *(uint4*)(vs + (size_t)d*520 + m8) = *(const uint4*)(v + base + (size_t)d*W_ + m8);
    }
  }
  __syncthreads();

  u16* pw = ps + (size_t)wv*16*136;

  float mrun[4] = {-3e38f,-3e38f,-3e38f,-3e38f};
  float lrun[4] = {0.f,0.f,0.f,0.f};
  const f32x4 zero4 = {0.f,0.f,0.f,0.f};
  f32x4 outacc[2] = {zero4, zero4};

  for (int kt = 0; kt < 4; ++kt){
    f32x4 sv[8];
    #pragma unroll
    for (int mi = 0; mi < 8; ++mi){
      int m0 = kt*128 + mi*16;
      bf16x8 kb8 = *(const bf16x8*)(ks + (size_t)(m0 + c16)*40 + 8*g);
      sv[mi] = __builtin_amdgcn_mfma_f32_16x16x32_bf16(aq.v8, kb8, zero4, 0, 0, 0);
    }
    float pmax[4];
    #pragma unroll
    for (int r = 0; r < 4; ++r){
      float m = sv[0][r];
      #pragma unroll
      for (int mi = 1; mi < 8; ++mi) m = fmaxf(m, sv[mi][r]);
      pmax[r] = m;
    }
    #pragma unroll
    for (int mask = 1; mask <= 8; mask <<= 1){
      #pragma unroll
      for (int r = 0; r < 4; ++r)
        pmax[r] = fmaxf(pmax[r], __shfl_xor(pmax[r], mask));
    }
    float corr[4];
    #pragma unroll
    for (int r = 0; r < 4; ++r){
      float mn = fmaxf(mrun[r], pmax[r]);
      corr[r] = __expf(mrun[r] - mn);
      mrun[r] = mn;
      lrun[r] *= corr[r];
    }
    #pragma unroll
    for (int mi = 0; mi < 8; ++mi){
      #pragma unroll
      for (int r = 0; r < 4; ++r){
        float p = __expf(sv[mi][r] - mrun[r]);
        lrun[r] += p;
        pw[(size_t)(4*g + r)*136 + mi*16 + c16] = f2bf(p);
      }
    }
    f32x4 cv = {corr[0], corr[1], corr[2], corr[3]};
    outacc[0] *= cv;
    outacc[1] *= cv;
    #pragma unroll
    for (int mc = 0; mc < 4; ++mc){
      bf16x8 pa  = *(const bf16x8*)(pw + (size_t)c16*136 + mc*32 + 8*g);
      bf16x8 vb0 = *(const bf16x8*)(vs + (size_t)c16*520      + kt*128 + mc*32 + 8*g);
      bf16x8 vb1 = *(const bf16x8*)(vs + (size_t)(16+c16)*520 + kt*128 + mc*32 + 8*g);
      outacc[0] = __builtin_amdgcn_mfma_f32_16x16x32_bf16(pa, vb0, outacc[0], 0, 0, 0);
      outacc[1] = __builtin_amdgcn_mfma_f32_16x16x32_bf16(pa, vb1, outacc[1], 0, 0, 0);
    }
  }
  float L[4];
  #pragma unroll
  for (int r = 0; r < 4; ++r){
    float s = lrun[r];
    #pragma unroll
    for (int mask = 1; mask <= 8; mask <<= 1) s += __shfl_xor(s, mask);
    L[r] = s;
  }
  // aT slot [att*2+b] layout [c][w][f]
  size_t tbase = slot + (size_t)c*FW_;
  #pragma unroll
  for (int dt = 0; dt < 2; ++dt){
    #pragma unroll
    for (int r = 0; r < 4; ++r)
      aT[tbase + (size_t)(q0 + 4*g + r)*F_ + h*32 + dt*16 + c16]
        = f2bf(outacc[dt][r] / L[r]);
  }
}

// ---------------- depthwise feature convs (f32, batch-strided) ----------------
// grid (2, 256, 16 = b*8+c)
__global__ __launch_bounds__(256)
void dw_fuse_b(const float* __restrict__ Z, long zbs,
               const float* __restrict__ k11, const float* __restrict__ b11,
               const float* __restrict__ k7,  const float* __restrict__ b7,
               float* __restrict__ S, long sbs){
  int w = blockIdx.x*256 + threadIdx.x;
  int f = blockIdx.y;
  int bc = blockIdx.z; int b = bc >> 3, c = bc & 7;
  const float* zb = Z + (size_t)b*zbs + (size_t)c*FW_;
  float a = b11[c];
  #pragma unroll
  for (int i = 0; i < 11; ++i){
    int ff = f - 5 + i;
    if (ff >= 0 && ff < F_) a += k11[c*11 + i]*zb[(size_t)ff*W_ + w];
  }
  float bb = b7[c];
  #pragma unroll
  for (int i = 0; i < 7; ++i){
    int ff = f - 3 + i;
    if (ff >= 0 && ff < F_) bb += k7[c*7 + i]*zb[(size_t)ff*W_ + w];
  }
  float ra = a > 0.f ? a*a : 0.f;
  S[(size_t)b*sbs + ((size_t)c*F_ + f)*W_ + w] = ra + bb;
}

__global__ __launch_bounds__(256)
void conv7_add_b(const float* __restrict__ T, long tbs,
                 const float* __restrict__ k7, const float* __restrict__ b7,
                 float* __restrict__ Hp, long hbs){
  int w = blockIdx.x*256 + threadIdx.x;
  int f = blockIdx.y;
  int bc = blockIdx.z; int b = bc >> 3, c = bc & 7;
  const float* tb = T + (size_t)b*tbs + (size_t)c*FW_;
  float acc = b7[c];
  #pragma unroll
  for (int i = 0; i < 7; ++i){
    int ff = f - 3 + i;
    if (ff >= 0 && ff < F_) acc += k7[c*7 + i]*tb[(size_t)ff*W_ + w];
  }
  Hp[(size_t)b*hbs + ((size_t)c*F_ + f)*W_ + w] += acc;
}

// ---------------- FUSED FF: h += w4 @ sq_relu(w3 @ LN5(h)) ----------------
// grid (16, 8, 2), block 256 = 32 wl x 8 fs. In-place on h.
__global__ __launch_bounds__(256)
void ff_ln(float* __restrict__ Hp,
           const float* __restrict__ g, const float* __restrict__ bta,
           const float* __restrict__ w3, const float* __restrict__ w4){
  int wl = threadIdx.x & 31, fs = threadIdx.x >> 5;
  int w = blockIdx.x*32 + wl;
  int c = blockIdx.y, b = blockIdx.z;
  float* hcol = Hp + (size_t)b*OBS_ + (size_t)c*FW_ + w;
  float v[32];
  float sum = 0.f, sq = 0.f;
  #pragma unroll
  for (int i = 0; i < 32; ++i){
    v[i] = hcol[(size_t)(fs*32 + i)*W_];
    sum += v[i]; sq += v[i]*v[i];
  }
  __shared__ float Ss[8][32], Sq[8][32], Mu[32], Rs[32];
  Ss[fs][wl] = sum; Sq[fs][wl] = sq;
  __syncthreads();
  if (fs == 0){
    float s = 0.f, q = 0.f;
    #pragma unroll
    for (int j = 0; j < 8; ++j){ s += Ss[j][wl]; q += Sq[j][wl]; }
    float mu = s * (1.f/256.f);
    Mu[wl] = mu; Rs[wl] = rsqrtf(q * (1.f/256.f) - mu*mu + 1e-5f);
  }
  __syncthreads();
  float mu = Mu[wl], rs = Rs[wl];
  float u[4] = {0.f,0.f,0.f,0.f};
  #pragma unroll
  for (int i = 0; i < 32; ++i){
    int f = fs*32 + i;
    float z = (v[i] - mu)*rs*g[c*F_ + f] + bta[c*F_ + f];
    #pragma unroll
    for (int e = 0; e < 4; ++e) u[e] += w3[(c*4 + e)*F_ + f]*z;
  }
  __shared__ float Us[8][4][32];
  #pragma unroll
  for (int e = 0; e < 4; ++e) Us[fs][e][wl] = u[e];
  __syncthreads();
  float uf[4];
  #pragma unroll
  for (int e = 0; e < 4; ++e){
    float s = 0.f;
    #pragma unroll
    for (int j = 0; j < 8; ++j) s += Us[j][e][wl];
    float rr = s > 0.f ? s : 0.f;
    uf[e] = rr*rr;
  }
  #pragma unroll
  for (int i = 0; i < 32; ++i){
    int f = fs*32 + i;
    const float* w4r = w4 + (c*F_ + f)*4;
    hcol[(size_t)f*W_] = v[i] + w4r[0]*uf[0] + w4r[1]*uf[1] + w4r[2]*uf[2] + w4r[3]*uf[3];
  }
}

extern "C" void kernel_launch(void* const* d_in, const int* in_sizes, int n_in,
                              void* d_out, int out_size, void* d_ws, size_t ws_size,
                              hipStream_t stream){
  const float* x    = (const float*)d_in[0];
  const float* skip = (const float*)d_in[1];
  const float* Wq   = (const float*)d_in[2];
  const float* Kq   = (const float*)d_in[3];
  const float* bq   = (const float*)d_in[4];
  const float* Wk   = (const float*)d_in[5];
  const float* Kk   = (const float*)d_in[6];
  const float* bk   = (const float*)d_in[7];
  const float* Wv   = (const float*)d_in[8];
  const float* Kv   = (const float*)d_in[9];
  const float* bv   = (const float*)d_in[10];
  const float* Wo   = (const float*)d_in[11];
  const float* ng   = (const float*)d_in[12];
  const float* nb   = (const float*)d_in[13];
  const float* c1aw = (const float*)d_in[14];
  const float* c1ab = (const float*)d_in[15];
  const float* c1bw = (const float*)d_in[16];
  const float* c1bb = (const float*)d_in[17];
  const float* c2w  = (const float*)d_in[18];
  const float* c2b  = (const float*)d_in[19];
  const float* w3   = (const float*)d_in[20];
  const float* w4   = (const float*)d_in[21];

  float* out = (float*)d_out;
  float* hp  = out + CFW_;           // h at hp + b*OBS_ + c*FW_

  // ws layout (MiB): W 0..16, skT 16, zT 20, t 24..48 (6 slots x 2b),
  // q 48..56, k 56..64, v 64..72 (2 att x 2 b each), zf 72, sf 80 => 88 MiB
  char* wsb = (char*)d_ws;
  u16* WQb  = (u16*)(wsb);
  u16* WKb  = (u16*)(wsb + ((size_t)4  << 20));
  u16* WVb  = (u16*)(wsb + ((size_t)8  << 20));
  u16* WOb  = (u16*)(wsb + ((size_t)12 << 20));
  u16* skT  = (u16*)(wsb + ((size_t)16 << 20));  // skip^T bf16 [b][c][w][f]
  u16* zT   = (u16*)(wsb + ((size_t)20 << 20));  // z^T bf16 [b][c][w][f]
  u16* tqkv = (u16*)(wsb + ((size_t)24 << 20));  // t: (att*3+p)*2+b slots
  u16* qbB  = (u16*)(wsb + ((size_t)48 << 20));
  u16* kbB  = (u16*)(wsb + ((size_t)56 << 20));
  u16* vbB  = (u16*)(wsb + ((size_t)64 << 20));
  float* zf = (float*)(wsb + ((size_t)72 << 20));
  float* sf = (float*)(wsb + ((size_t)80 << 20));
  u16* aT   = tqkv;                  // attn out slots (att*2+b), aliases dead t

  float code = 0.f;
  if (n_in != 22) code += 20000.f;
  if (out_size != 4194304) code += 80000.f;
  if (ws_size < ((size_t)88 << 20)) code += 160000.f;

  dim3 gLn(16, 8, 2);
  dim3 gPix(2, F_, 16);
  dim3 gCvtT(8, 4, 16);
  const int attn_lds_bytes = (512*40 + 32*520 + 8*16*136) * 2;  // 109056

  init_out<<<8192, 256, 0, stream>>>(x, out);
  cvt4<<<dim3(2048, 4), 256, 0, stream>>>(Wq, Wk, Wv, Wo, WQb, WKb, WVb, WOb);
  cvtT<<<gCvtT, 256, 0, stream>>>(skip, skT);

  auto do_attn = [&](int i0, const u16* kv0, int i1, const u16* kv1, int natt){
    gemm_qkv_m<<<dim3(4, 4, 48*natt), 256, 0, stream>>>(
        WQb, WKb, WVb, zT, kv0, kv1, tqkv, i0, i1);
    conv_rope_m<<<768*natt, 256, 0, stream>>>(
        tqkv, Kq, bq, Kk, bk, Kv, bv, qbB, kbB, vbB, i0, i1);
    attn_m<<<dim3(128*natt, 4), 512, attn_lds_bytes, stream>>>(qbB, kbB, vbB, aT);
    gemm_wo_m<<<dim3(8, 4, 16), 256, 0, stream>>>(WOb, aT, hp, i0, i1, natt);
  };

  // z = LN0(x); h = x + att0(z,z) + att1(z,skip)  [att0 ∥ att1 merged]
  ln32T<<<gLn, 256, 0, stream>>>(x, CFW_, zT, CFW_, ng + 0*C_*F_, nb + 0*C_*F_);
  do_attn(0, zT, 1, skT, 2);

  // conv block (separate, high-occupancy kernels)
  ln32f<<<gLn, 256, 0, stream>>>(hp, OBS_, zf, CFW_, ng + 1*C_*F_, nb + 1*C_*F_);
  dw_fuse_b<<<gPix, 256, 0, stream>>>(zf, CFW_, c1aw, c1ab, c1bw, c1bb, sf, CFW_);
  ln32f<<<gLn, 256, 0, stream>>>(sf, CFW_, zf, CFW_, ng + 2*C_*F_, nb + 2*C_*F_);
  conv7_add_b<<<gPix, 256, 0, stream>>>(zf, CFW_, c2w, c2b, hp, OBS_);

  // att2 (self on LN3(h))
  ln32T<<<gLn, 256, 0, stream>>>(hp, OBS_, zT, CFW_, ng + 3*C_*F_, nb + 3*C_*F_);
  do_attn(2, zT, 2, zT, 1);

  // att3 (LN4(h) vs skip)
  ln32T<<<gLn, 256, 0, stream>>>(hp, OBS_, zT, CFW_, ng + 4*C_*F_, nb + 4*C_*F_);
  do_attn(3, skT, 3, skT, 1);

  // fused FF (in-place on h)
  ff_ln<<<gLn, 256, 0, stream>>>(hp, ng + 5*C_*F_, nb + 5*C_*F_, w3, w4);

  if (code != 0.f) put_val<<<1, 1, 0, stream>>>(out, code);
}

// Round 21
// 361.430 us; speedup vs baseline: 1.3453x; 1.0623x over previous
//
#include <hip/hip_runtime.h>

#define B_ 2
#define C_ 8
#define F_ 256
#define W_ 512
#define H_ 8
#define FW_ (F_*W_)        // 131072
#define CFW_ (C_*FW_)      // 1048576 = one batch of (C,F,W)
#define OBS_ (2*CFW_)      // out batch stride (B,16,F,W)

typedef unsigned short u16;

__device__ __forceinline__ u16 f2bf(float f){
  unsigned u = __float_as_uint(f);
  u += 0x7fffu + ((u>>16)&1u);
  return (u16)(u>>16);
}
__device__ __forceinline__ float bf2f(u16 u){
  return __uint_as_float((unsigned)u<<16);
}

typedef __attribute__((ext_vector_type(8))) short bf16x8;
typedef __attribute__((ext_vector_type(4))) float f32x4;

// ---------------- init: both halves of out = x ----------------
__global__ __launch_bounds__(256)
void init_out(const float* __restrict__ x, float* __restrict__ out){
  int i = blockIdx.x*256 + threadIdx.x;              // 2M
  int b = i >> 20;
  int r = i & (CFW_-1);
  float v = x[i];
  out[(size_t)b*OBS_ + r] = v;
  out[(size_t)b*OBS_ + CFW_ + r] = v;
}

__global__ void put_val(float* o, float v){ o[0] = v; }

// ---------------- bulk f32 -> bf16 conversion (4 weight arrays) --------------
__global__ __launch_bounds__(256)
void cvt4(const float* __restrict__ s0, const float* __restrict__ s1,
          const float* __restrict__ s2, const float* __restrict__ s3,
          u16* __restrict__ d0, u16* __restrict__ d1, u16* __restrict__ d2,
          u16* __restrict__ d3){
  int which = blockIdx.y;
  const float* s = which==0 ? s0 : which==1 ? s1 : which==2 ? s2 : s3;
  u16* d        = which==0 ? d0 : which==1 ? d1 : which==2 ? d2 : d3;
  int i = (blockIdx.x*256 + threadIdx.x)*4;          // 2048 blocks x 1024 elems
  float4 v = *(const float4*)(s + i);
  ushort4 o;
  o.x = f2bf(v.x); o.y = f2bf(v.y); o.z = f2bf(v.z); o.w = f2bf(v.w);
  *(ushort4*)(d + i) = o;
}

// ---------------- skip -> skip^T bf16 ([b][c][w][f]) via LDS 64x64 tile ------
// grid (8 w-tiles, 4 f-tiles, 16 = b*8+c), block 256
__global__ __launch_bounds__(256)
void cvtT(const float* __restrict__ src, u16* __restrict__ dst){
  __shared__ float Tin[64][65];
  int w0 = blockIdx.x*64, f0 = blockIdx.y*64;
  int bc = blockIdx.z; int b = bc >> 3, c = bc & 7;
  const float* s = src + (size_t)b*CFW_ + (size_t)c*FW_;
  int t = threadIdx.x;
  int r16 = t >> 4, c4 = (t & 15)*4;
  #pragma unroll
  for (int pass = 0; pass < 4; ++pass){
    int f = r16 + pass*16;
    float4 v = *(const float4*)(s + (size_t)(f0+f)*W_ + w0 + c4);
    Tin[f][c4+0] = v.x; Tin[f][c4+1] = v.y;
    Tin[f][c4+2] = v.z; Tin[f][c4+3] = v.w;
  }
  __syncthreads();
  u16* d = dst + (size_t)b*CFW_ + (size_t)c*FW_;     // [w][f] layout
  #pragma unroll
  for (int pass = 0; pass < 4; ++pass){
    int w = r16 + pass*16;
    ushort4 o;
    o.x = f2bf(Tin[c4+0][w]); o.y = f2bf(Tin[c4+1][w]);
    o.z = f2bf(Tin[c4+2][w]); o.w = f2bf(Tin[c4+3][w]);
    *(ushort4*)(d + (size_t)(w0+w)*F_ + f0 + c4) = o;
  }
}

// ---------------- LayerNorm over f -> TRANSPOSED bf16 z ([b][c][w][f]) -------
// grid (16, 8, 2), block 256 = 32 w-lanes x 8 f-slices
__global__ __launch_bounds__(256)
void ln32T(const float* __restrict__ X, long xbs, u16* __restrict__ Y, long ybs,
           const float* __restrict__ g, const float* __restrict__ bta){
  int wl = threadIdx.x & 31, fs = threadIdx.x >> 5;
  int w = blockIdx.x*32 + wl;
  int c = blockIdx.y;
  int b = blockIdx.z;
  const float* xb = X + (size_t)b*xbs + (size_t)c*FW_ + w;
  float v[32];
  float sum = 0.f, sq = 0.f;
  #pragma unroll
  for (int i = 0; i < 32; ++i){
    v[i] = xb[(size_t)(fs*32 + i)*W_];
    sum += v[i]; sq += v[i]*v[i];
  }
  __shared__ float Ss[8][32], Sq[8][32], Mu[32], Rs[32];
  Ss[fs][wl] = sum; Sq[fs][wl] = sq;
  __syncthreads();
  if (fs == 0){
    float s = 0.f, q = 0.f;
    #pragma unroll
    for (int j = 0; j < 8; ++j){ s += Ss[j][wl]; q += Sq[j][wl]; }
    float mu = s * (1.f/256.f);
    float var = q * (1.f/256.f) - mu*mu;
    Mu[wl] = mu; Rs[wl] = rsqrtf(var + 1e-5f);
  }
  __syncthreads();
  float mu = Mu[wl], rs = Rs[wl];
  u16* yb = Y + (size_t)b*ybs + ((size_t)c*W_ + w)*F_ + fs*32;
  #pragma unroll
  for (int i4 = 0; i4 < 8; ++i4){
    ushort4 o;
    int f = fs*32 + i4*4;
    o.x = f2bf((v[i4*4+0] - mu)*rs*g[c*F_ + f+0] + bta[c*F_ + f+0]);
    o.y = f2bf((v[i4*4+1] - mu)*rs*g[c*F_ + f+1] + bta[c*F_ + f+1]);
    o.z = f2bf((v[i4*4+2] - mu)*rs*g[c*F_ + f+2] + bta[c*F_ + f+2]);
    o.w = f2bf((v[i4*4+3] - mu)*rs*g[c*F_ + f+3] + bta[c*F_ + f+3]);
    *(ushort4*)(yb + i4*4) = o;
  }
}

// ---------------- LayerNorm over f -> f32 out (conv path) ----------------
// grid (16, 8, 2), block 256 = 32 w-lanes x 8 f-slices
__global__ __launch_bounds__(256)
void ln32f(const float* __restrict__ X, long xbs, float* __restrict__ Y, long ybs,
           const float* __restrict__ g, const float* __restrict__ bta){
  int wl = threadIdx.x & 31, fs = threadIdx.x >> 5;
  int w = blockIdx.x*32 + wl;
  int c = blockIdx.y;
  int b = blockIdx.z;
  const float* xb = X + (size_t)b*xbs + (size_t)c*FW_ + w;
  float v[32];
  float sum = 0.f, sq = 0.f;
  #pragma unroll
  for (int i = 0; i < 32; ++i){
    v[i] = xb[(size_t)(fs*32 + i)*W_];
    sum += v[i]; sq += v[i]*v[i];
  }
  __shared__ float Ss[8][32], Sq[8][32], Mu[32], Rs[32];
  Ss[fs][wl] = sum; Sq[fs][wl] = sq;
  __syncthreads();
  if (fs == 0){
    float s = 0.f, q = 0.f;
    #pragma unroll
    for (int j = 0; j < 8; ++j){ s += Ss[j][wl]; q += Sq[j][wl]; }
    float mu = s * (1.f/256.f);
    float var = q * (1.f/256.f) - mu*mu;
    Mu[wl] = mu; Rs[wl] = rsqrtf(var + 1e-5f);
  }
  __syncthreads();
  float mu = Mu[wl], rs = Rs[wl];
  float* yb = Y + (size_t)b*ybs + (size_t)c*FW_ + w;
  #pragma unroll
  for (int i = 0; i < 32; ++i){
    int f = fs*32 + i;
    yb[(size_t)f*W_] = (v[i] - mu)*rs*g[c*F_ + f] + bta[c*F_ + f];
  }
}

// ---------------- fused QKV MFMA GEMM, multi-attention, 128w tile ------------
// grid (W/128=4, F/64=4, 48*natt), block 256. att = zid/48.
__global__ __launch_bounds__(256)
void gemm_qkv_m(const u16* __restrict__ wqb, const u16* __restrict__ wkb,
                const u16* __restrict__ wvb,
                const u16* __restrict__ srcq,
                const u16* __restrict__ kv0, const u16* __restrict__ kv1,
                u16* __restrict__ T, int i0, int i1){
  int zid = blockIdx.z;
  int att = (zid >= 48) ? 1 : 0;
  int rest = zid - att*48;
  int proj = rest >> 4;
  int bc = rest & 15; int b = bc >> 3, c = bc & 7;
  int wi = att ? i1 : i0;
  const u16* src = (proj == 0) ? srcq : (att ? kv1 : kv0);
  const u16* Wm  = (proj == 0) ? wqb : (proj == 1 ? wkb : wvb);
  const u16* AxT = src + (size_t)b*CFW_ + (size_t)c*FW_;   // [w][f]
  const u16* Bw = Wm + (size_t)wi*C_*F_*F_ + (size_t)c*F_*F_;
  u16* Yb = T + ((size_t)(att*3 + proj)*2 + b)*CFW_ + (size_t)c*FW_;

  int w0 = blockIdx.x * 128;
  int g0 = blockIdx.y * 64;
  int t = threadIdx.x, lane = t & 63, wv_ = t >> 6;
  int gq = lane >> 4, c16 = lane & 15;
  int wm = w0 + wv_*16 + c16;
  const u16* Ap0 = AxT + (size_t)wm*F_ + 8*gq;
  const u16* Ap1 = Ap0 + (size_t)64*F_;
  const u16* Bp  = Bw + (size_t)(g0 + c16)*F_ + 8*gq;
  const f32x4 zero4 = {0.f,0.f,0.f,0.f};
  f32x4 acc0[4] = {zero4, zero4, zero4, zero4};
  f32x4 acc1[4] = {zero4, zero4, zero4, zero4};

  #pragma unroll 2
  for (int k0 = 0; k0 < F_; k0 += 32){
    bf16x8 a0 = *(const bf16x8*)(Ap0 + k0);
    bf16x8 a1 = *(const bf16x8*)(Ap1 + k0);
    #pragma unroll
    for (int nf = 0; nf < 4; ++nf){
      bf16x8 bfr = *(const bf16x8*)(Bp + (size_t)nf*16*F_ + k0);
      acc0[nf] = __builtin_amdgcn_mfma_f32_16x16x32_bf16(a0, bfr, acc0[nf], 0, 0, 0);
      acc1[nf] = __builtin_amdgcn_mfma_f32_16x16x32_bf16(a1, bfr, acc1[nf], 0, 0, 0);
    }
  }
  int wout = w0 + wv_*16 + 4*gq;
  #pragma unroll
  for (int nf = 0; nf < 4; ++nf){
    u16* yrow = Yb + (size_t)(g0 + nf*16 + c16)*W_;
    ushort4 o0, o1;
    o0.x = f2bf(acc0[nf][0]); o0.y = f2bf(acc0[nf][1]);
    o0.z = f2bf(acc0[nf][2]); o0.w = f2bf(acc0[nf][3]);
    o1.x = f2bf(acc1[nf][0]); o1.y = f2bf(acc1[nf][1]);
    o1.z = f2bf(acc1[nf][2]); o1.w = f2bf(acc1[nf][3]);
    *(ushort4*)(yrow + wout)      = o0;
    *(ushort4*)(yrow + wout + 64) = o1;
  }
}

// ---------------- Wo MFMA GEMM, multi-attention accumulate -------------------
// h(f32) += sum_att aT[att] @ Wo[i_att]. grid (8, 4, 16), block 256.
__global__ __launch_bounds__(256)
void gemm_wo_m(const u16* __restrict__ wob, const u16* __restrict__ A,
               float* __restrict__ Y, int i0, int i1, int natt){
  int bc = blockIdx.z; int b = bc >> 3, c = bc & 7;
  float* Yb = Y + (size_t)b*OBS_ + (size_t)c*FW_;
  int w0 = blockIdx.x * 64;
  int g0 = blockIdx.y * 64;
  int t = threadIdx.x, lane = t & 63, wv_ = t >> 6;
  int gq = lane >> 4, c16 = lane & 15;
  int wm = w0 + wv_*16 + c16;
  const f32x4 zero4 = {0.f,0.f,0.f,0.f};
  f32x4 acc[4] = {zero4, zero4, zero4, zero4};

  for (int att = 0; att < natt; ++att){
    const u16* AxT = A + ((size_t)(att*2) + b)*CFW_ + (size_t)c*FW_;  // [w][f]
    const u16* Bw = wob + (size_t)(att ? i1 : i0)*C_*F_*F_ + (size_t)c*F_*F_;
    for (int k0 = 0; k0 < F_; k0 += 32){
      bf16x8 af = *(const bf16x8*)(AxT + (size_t)wm*F_ + k0 + 8*gq);
      #pragma unroll
      for (int nf = 0; nf < 4; ++nf){
        bf16x8 bfr = *(const bf16x8*)(Bw + (size_t)(g0 + nf*16 + c16)*F_ + k0 + 8*gq);
        acc[nf] = __builtin_amdgcn_mfma_f32_16x16x32_bf16(af, bfr, acc[nf], 0, 0, 0);
      }
    }
  }
  int wout = w0 + wv_*16 + 4*gq;
  #pragma unroll
  for (int nf = 0; nf < 4; ++nf){
    float* y = Yb + (size_t)(g0 + nf*16 + c16)*W_ + wout;
    float4 o = *(float4*)y;
    o.x += acc[nf][0]; o.y += acc[nf][1]; o.z += acc[nf][2]; o.w += acc[nf][3];
    *(float4*)y = o;
  }
}

// ---------------- fused q/k/v 1x3 conv (+RoPE), LDS-staged, multi-att --------
// grid 768*natt, block 512 (8 waves). bx -> (att, p, b, jf).
// Thread (co = t>>6, wg2 = t&63) computes w = wg2 + 64*i, i<8, for 2 f's.
// LDS reads: lanes span 64 consecutive floats -> 2 lanes/bank (free).
__global__ __launch_bounds__(512)
void conv_rope_m(const u16* __restrict__ T,
                 const float* __restrict__ Kq3, const float* __restrict__ bq,
                 const float* __restrict__ Kk3, const float* __restrict__ bk,
                 const float* __restrict__ Kv3, const float* __restrict__ bv,
                 u16* __restrict__ Q, u16* __restrict__ K,
                 u16* __restrict__ V, int i0, int i1){
  __shared__ float Tin[16][520];                     // data at [4..516), halo 3,516
  __shared__ float Kc[192];                          // [co][ci][tap]
  int bx = blockIdx.x;
  int att = (bx >= 768) ? 1 : 0;
  int r = bx - att*768;
  int jf = r & 127;
  int b  = (r >> 7) & 1;
  int p  = r >> 8;                                   // 0..2 (block-uniform)
  int wi = att ? i1 : i0;
  const float* K3   = (p==0 ? Kq3 : (p==1 ? Kk3 : Kv3)) + (size_t)wi*C_*C_*3;
  const float* bias = (p==0 ? bq  : (p==1 ? bk  : bv)) + (size_t)wi*C_;
  const u16* Tb = T + ((size_t)(att*3 + p)*2 + b)*CFW_;
  u16* O = (p==0 ? Q : (p==1 ? K : V)) + ((size_t)att*2 + b)*CFW_;
  int f0 = jf*2;
  int t = threadIdx.x;

  if (t < 192) Kc[t] = K3[t];
  if (t < 16){ Tin[t][3] = 0.f; Tin[t][516] = 0.f; }
  for (int li = t; li < 16*128; li += 512){          // 128 float4 per row
    int row = li >> 7;                               // ci*2 + fsel
    int c4  = li & 127;
    int ci = row >> 1, fsel = row & 1;
    ushort4 v4 = *(const ushort4*)(Tb + ((size_t)ci*F_ + f0 + fsel)*W_ + c4*4);
    float4 f4;
    f4.x = bf2f(v4.x); f4.y = bf2f(v4.y);
    f4.z = bf2f(v4.z); f4.w = bf2f(v4.w);
    *(float4*)&Tin[row][4 + c4*4] = f4;              // aligned, lane-contiguous
  }
  __syncthreads();

  int co  = t >> 6;                                  // 0..7
  int wg2 = t & 63;                                  // 0..63; w = wg2 + 64*i
  float bs = bias[co];
  float a0[8], a1[8];
  #pragma unroll
  for (int i = 0; i < 8; ++i){ a0[i] = bs; a1[i] = bs; }
  #pragma unroll
  for (int ci = 0; ci < 8; ++ci){
    const float* r0 = &Tin[ci*2+0][4 + wg2];
    const float* r1 = &Tin[ci*2+1][4 + wg2];
    float k0 = Kc[(co*8+ci)*3+0], k1 = Kc[(co*8+ci)*3+1], k2 = Kc[(co*8+ci)*3+2];
    #pragma unroll
    for (int i = 0; i < 8; ++i){
      int off = 64*i;
      a0[i] += k0*r0[off-1] + k1*r0[off] + k2*r0[off+1];
      a1[i] += k0*r1[off-1] + k1*r1[off] + k2*r1[off+1];
    }
  }
  size_t ob0 = ((size_t)co*F_ + f0)*W_ + wg2;
  size_t ob1 = ob0 + W_;
  if (p < 2){
    int j = jf & 15;                                 // freq index within head
    float inv = exp2f(-(float)j * 0.83048202372184f);  // 10000^(-j/16)
    float sv, cv, dsn, dcs;
    sincosf((float)wg2 * inv, &sv, &cv);
    sincosf(64.f * inv, &dsn, &dcs);                 // rotation step for w += 64
    float scale = (p == 0) ? 0.0625f : 1.f;          // fold 1/sqrt(256) into q
    #pragma unroll
    for (int i = 0; i < 8; ++i){
      O[ob0 + 64*i] = f2bf((a0[i]*cv - a1[i]*sv)*scale);
      O[ob1 + 64*i] = f2bf((a1[i]*cv + a0[i]*sv)*scale);
      float cn = cv*dcs - sv*dsn;                    // rotate by 64*inv
      sv = sv*dcs + cv*dsn;
      cv = cn;
    }
  } else {
    #pragma unroll
    for (int i = 0; i < 8; ++i){
      O[ob0 + 64*i] = f2bf(a0[i]);
      O[ob1 + 64*i] = f2bf(a1[i]);
    }
  }
}

// ---------------- MFMA attention, multi-att, writes a TRANSPOSED -------------
// grid (128*natt, 4), block 512 (8 waves). att = bx>>7.
__global__ __launch_bounds__(512)
void attn_m(const u16* __restrict__ q, const u16* __restrict__ k,
            const u16* __restrict__ v, u16* __restrict__ aT){
  extern __shared__ __align__(16) unsigned char smem_dyn[];
  u16* ks = (u16*)smem_dyn;          // [512][40]
  u16* vs = ks + 512*40;             // [32][520]
  u16* ps = vs + 32*520;             // [8][16][136]
  int bx = blockIdx.x;
  int att = bx >> 7;
  int rb = bx & 127;
  int b = rb >> 6;
  int ch = rb & 63;
  int h = ch & 7, c = ch >> 3;
  size_t slot = ((size_t)att*2 + b)*CFW_;
  size_t base = slot + ((size_t)c*F_ + h*32)*W_;
  int t = threadIdx.x;
  int lane = t & 63, wv = t >> 6;
  int g = lane >> 4, c16 = lane & 15;

  int q0 = blockIdx.y*128 + wv*16;
  union { bf16x8 v8; u16 u[8]; } aq;
  #pragma unroll
  for (int j = 0; j < 8; ++j)
    aq.u[j] = q[base + (size_t)(8*g + j)*W_ + q0 + c16];

  for (int d = 0; d < 32; ++d)
    ks[t*40 + d] = k[base + (size_t)d*W_ + t];       // t = m (512)
  {
    int m8 = (t & 63)*8;
    #pragma unroll
    for (int it = 0; it < 4; ++it){
      int d = (t >> 6) + it*8;
      *(uint4*)(vs + (size_t)d*520 + m8) = *(const uint4*)(v + base + (size_t)d*W_ + m8);
    }
  }
  __syncthreads();

  u16* pw = ps + (size_t)wv*16*136;

  float mrun[4] = {-3e38f,-3e38f,-3e38f,-3e38f};
  float lrun[4] = {0.f,0.f,0.f,0.f};
  const f32x4 zero4 = {0.f,0.f,0.f,0.f};
  f32x4 outacc[2] = {zero4, zero4};

  for (int kt = 0; kt < 4; ++kt){
    f32x4 sv[8];
    #pragma unroll
    for (int mi = 0; mi < 8; ++mi){
      int m0 = kt*128 + mi*16;
      bf16x8 kb8 = *(const bf16x8*)(ks + (size_t)(m0 + c16)*40 + 8*g);
      sv[mi] = __builtin_amdgcn_mfma_f32_16x16x32_bf16(aq.v8, kb8, zero4, 0, 0, 0);
    }
    float pmax[4];
    #pragma unroll
    for (int r = 0; r < 4; ++r){
      float m = sv[0][r];
      #pragma unroll
      for (int mi = 1; mi < 8; ++mi) m = fmaxf(m, sv[mi][r]);
      pmax[r] = m;
    }
    #pragma unroll
    for (int mask = 1; mask <= 8; mask <<= 1){
      #pragma unroll
      for (int r = 0; r < 4; ++r)
        pmax[r] = fmaxf(pmax[r], __shfl_xor(pmax[r], mask));
    }
    float corr[4];
    #pragma unroll
    for (int r = 0; r < 4; ++r){
      float mn = fmaxf(mrun[r], pmax[r]);
      corr[r] = __expf(mrun[r] - mn);
      mrun[r] = mn;
      lrun[r] *= corr[r];
    }
    #pragma unroll
    for (int mi = 0; mi < 8; ++mi){
      #pragma unroll
      for (int r = 0; r < 4; ++r){
        float p = __expf(sv[mi][r] - mrun[r]);
        lrun[r] += p;
        pw[(size_t)(4*g + r)*136 + mi*16 + c16] = f2bf(p);
      }
    }
    f32x4 cv = {corr[0], corr[1], corr[2], corr[3]};
    outacc[0] *= cv;
    outacc[1] *= cv;
    #pragma unroll
    for (int mc = 0; mc < 4; ++mc){
      bf16x8 pa  = *(const bf16x8*)(pw + (size_t)c16*136 + mc*32 + 8*g);
      bf16x8 vb0 = *(const bf16x8*)(vs + (size_t)c16*520      + kt*128 + mc*32 + 8*g);
      bf16x8 vb1 = *(const bf16x8*)(vs + (size_t)(16+c16)*520 + kt*128 + mc*32 + 8*g);
      outacc[0] = __builtin_amdgcn_mfma_f32_16x16x32_bf16(pa, vb0, outacc[0], 0, 0, 0);
      outacc[1] = __builtin_amdgcn_mfma_f32_16x16x32_bf16(pa, vb1, outacc[1], 0, 0, 0);
    }
  }
  float L[4];
  #pragma unroll
  for (int r = 0; r < 4; ++r){
    float s = lrun[r];
    #pragma unroll
    for (int mask = 1; mask <= 8; mask <<= 1) s += __shfl_xor(s, mask);
    L[r] = s;
  }
  // aT slot [att*2+b] layout [c][w][f]
  size_t tbase = slot + (size_t)c*FW_;
  #pragma unroll
  for (int dt = 0; dt < 2; ++dt){
    #pragma unroll
    for (int r = 0; r < 4; ++r)
      aT[tbase + (size_t)(q0 + 4*g + r)*F_ + h*32 + dt*16 + c16]
        = f2bf(outacc[dt][r] / L[r]);
  }
}

// ---------------- depthwise feature convs (f32, batch-strided) ----------------
// grid (2, 256, 16 = b*8+c)
__global__ __launch_bounds__(256)
void dw_fuse_b(const float* __restrict__ Z, long zbs,
               const float* __restrict__ k11, const float* __restrict__ b11,
               const float* __restrict__ k7,  const float* __restrict__ b7,
               float* __restrict__ S, long sbs){
  int w = blockIdx.x*256 + threadIdx.x;
  int f = blockIdx.y;
  int bc = blockIdx.z; int b = bc >> 3, c = bc & 7;
  const float* zb = Z + (size_t)b*zbs + (size_t)c*FW_;
  float a = b11[c];
  #pragma unroll
  for (int i = 0; i < 11; ++i){
    int ff = f - 5 + i;
    if (ff >= 0 && ff < F_) a += k11[c*11 + i]*zb[(size_t)ff*W_ + w];
  }
  float bb = b7[c];
  #pragma unroll
  for (int i = 0; i < 7; ++i){
    int ff = f - 3 + i;
    if (ff >= 0 && ff < F_) bb += k7[c*7 + i]*zb[(size_t)ff*W_ + w];
  }
  float ra = a > 0.f ? a*a : 0.f;
  S[(size_t)b*sbs + ((size_t)c*F_ + f)*W_ + w] = ra + bb;
}

__global__ __launch_bounds__(256)
void conv7_add_b(const float* __restrict__ T, long tbs,
                 const float* __restrict__ k7, const float* __restrict__ b7,
                 float* __restrict__ Hp, long hbs){
  int w = blockIdx.x*256 + threadIdx.x;
  int f = blockIdx.y;
  int bc = blockIdx.z; int b = bc >> 3, c = bc & 7;
  const float* tb = T + (size_t)b*tbs + (size_t)c*FW_;
  float acc = b7[c];
  #pragma unroll
  for (int i = 0; i < 7; ++i){
    int ff = f - 3 + i;
    if (ff >= 0 && ff < F_) acc += k7[c*7 + i]*tb[(size_t)ff*W_ + w];
  }
  Hp[(size_t)b*hbs + ((size_t)c*F_ + f)*W_ + w] += acc;
}

// ---------------- FUSED FF: h += w4 @ sq_relu(w3 @ LN5(h)) ----------------
// grid (16, 8, 2), block 256 = 32 wl x 8 fs. In-place on h.
__global__ __launch_bounds__(256)
void ff_ln(float* __restrict__ Hp,
           const float* __restrict__ g, const float* __restrict__ bta,
           const float* __restrict__ w3, const float* __restrict__ w4){
  int wl = threadIdx.x & 31, fs = threadIdx.x >> 5;
  int w = blockIdx.x*32 + wl;
  int c = blockIdx.y, b = blockIdx.z;
  float* hcol = Hp + (size_t)b*OBS_ + (size_t)c*FW_ + w;
  float v[32];
  float sum = 0.f, sq = 0.f;
  #pragma unroll
  for (int i = 0; i < 32; ++i){
    v[i] = hcol[(size_t)(fs*32 + i)*W_];
    sum += v[i]; sq += v[i]*v[i];
  }
  __shared__ float Ss[8][32], Sq[8][32], Mu[32], Rs[32];
  Ss[fs][wl] = sum; Sq[fs][wl] = sq;
  __syncthreads();
  if (fs == 0){
    float s = 0.f, q = 0.f;
    #pragma unroll
    for (int j = 0; j < 8; ++j){ s += Ss[j][wl]; q += Sq[j][wl]; }
    float mu = s * (1.f/256.f);
    Mu[wl] = mu; Rs[wl] = rsqrtf(q * (1.f/256.f) - mu*mu + 1e-5f);
  }
  __syncthreads();
  float mu = Mu[wl], rs = Rs[wl];
  float u[4] = {0.f,0.f,0.f,0.f};
  #pragma unroll
  for (int i = 0; i < 32; ++i){
    int f = fs*32 + i;
    float z = (v[i] - mu)*rs*g[c*F_ + f] + bta[c*F_ + f];
    #pragma unroll
    for (int e = 0; e < 4; ++e) u[e] += w3[(c*4 + e)*F_ + f]*z;
  }
  __shared__ float Us[8][4][32];
  #pragma unroll
  for (int e = 0; e < 4; ++e) Us[fs][e][wl] = u[e];
  __syncthreads();
  float uf[4];
  #pragma unroll
  for (int e = 0; e < 4; ++e){
    float s = 0.f;
    #pragma unroll
    for (int j = 0; j < 8; ++j) s += Us[j][e][wl];
    float rr = s > 0.f ? s : 0.f;
    uf[e] = rr*rr;
  }
  #pragma unroll
  for (int i = 0; i < 32; ++i){
    int f = fs*32 + i;
    const float* w4r = w4 + (c*F_ + f)*4;
    hcol[(size_t)f*W_] = v[i] + w4r[0]*uf[0] + w4r[1]*uf[1] + w4r[2]*uf[2] + w4r[3]*uf[3];
  }
}

extern "C" void kernel_launch(void* const* d_in, const int* in_sizes, int n_in,
                              void* d_out, int out_size, void* d_ws, size_t ws_size,
                              hipStream_t stream){
  const float* x    = (const float*)d_in[0];
  const float* skip = (const float*)d_in[1];
  const float* Wq   = (const float*)d_in[2];
  const float* Kq   = (const float*)d_in[3];
  const float* bq   = (const float*)d_in[4];
  const float* Wk   = (const float*)d_in[5];
  const float* Kk   = (const float*)d_in[6];
  const float* bk   = (const float*)d_in[7];
  const float* Wv   = (const float*)d_in[8];
  const float* Kv   = (const float*)d_in[9];
  const float* bv   = (const float*)d_in[10];
  const float* Wo   = (const float*)d_in[11];
  const float* ng   = (const float*)d_in[12];
  const float* nb   = (const float*)d_in[13];
  const float* c1aw = (const float*)d_in[14];
  const float* c1ab = (const float*)d_in[15];
  const float* c1bw = (const float*)d_in[16];
  const float* c1bb = (const float*)d_in[17];
  const float* c2w  = (const float*)d_in[18];
  const float* c2b  = (const float*)d_in[19];
  const float* w3   = (const float*)d_in[20];
  const float* w4   = (const float*)d_in[21];

  float* out = (float*)d_out;
  float* hp  = out + CFW_;           // h at hp + b*OBS_ + c*FW_

  // ws layout (MiB): W 0..16, skT 16, zT 20, t 24..48 (6 slots x 2b),
  // q 48..56, k 56..64, v 64..72 (2 att x 2 b each), zf 72, sf 80 => 88 MiB
  char* wsb = (char*)d_ws;
  u16* WQb  = (u16*)(wsb);
  u16* WKb  = (u16*)(wsb + ((size_t)4  << 20));
  u16* WVb  = (u16*)(wsb + ((size_t)8  << 20));
  u16* WOb  = (u16*)(wsb + ((size_t)12 << 20));
  u16* skT  = (u16*)(wsb + ((size_t)16 << 20));  // skip^T bf16 [b][c][w][f]
  u16* zT   = (u16*)(wsb + ((size_t)20 << 20));  // z^T bf16 [b][c][w][f]
  u16* tqkv = (u16*)(wsb + ((size_t)24 << 20));  // t: (att*3+p)*2+b slots
  u16* qbB  = (u16*)(wsb + ((size_t)48 << 20));
  u16* kbB  = (u16*)(wsb + ((size_t)56 << 20));
  u16* vbB  = (u16*)(wsb + ((size_t)64 << 20));
  float* zf = (float*)(wsb + ((size_t)72 << 20));
  float* sf = (float*)(wsb + ((size_t)80 << 20));
  u16* aT   = tqkv;                  // attn out slots (att*2+b), aliases dead t

  float code = 0.f;
  if (n_in != 22) code += 20000.f;
  if (out_size != 4194304) code += 80000.f;
  if (ws_size < ((size_t)88 << 20)) code += 160000.f;

  dim3 gLn(16, 8, 2);
  dim3 gPix(2, F_, 16);
  dim3 gCvtT(8, 4, 16);
  const int attn_lds_bytes = (512*40 + 32*520 + 8*16*136) * 2;  // 109056

  init_out<<<8192, 256, 0, stream>>>(x, out);
  cvt4<<<dim3(2048, 4), 256, 0, stream>>>(Wq, Wk, Wv, Wo, WQb, WKb, WVb, WOb);
  cvtT<<<gCvtT, 256, 0, stream>>>(skip, skT);

  auto do_attn = [&](int i0, const u16* kv0, int i1, const u16* kv1, int natt){
    gemm_qkv_m<<<dim3(4, 4, 48*natt), 256, 0, stream>>>(
        WQb, WKb, WVb, zT, kv0, kv1, tqkv, i0, i1);
    conv_rope_m<<<768*natt, 512, 0, stream>>>(
        tqkv, Kq, bq, Kk, bk, Kv, bv, qbB, kbB, vbB, i0, i1);
    attn_m<<<dim3(128*natt, 4), 512, attn_lds_bytes, stream>>>(qbB, kbB, vbB, aT);
    gemm_wo_m<<<dim3(8, 4, 16), 256, 0, stream>>>(WOb, aT, hp, i0, i1, natt);
  };

  // z = LN0(x); h = x + att0(z,z) + att1(z,skip)  [att0 ∥ att1 merged]
  ln32T<<<gLn, 256, 0, stream>>>(x, CFW_, zT, CFW_, ng + 0*C_*F_, nb + 0*C_*F_);
  do_attn(0, zT, 1, skT, 2);

  // conv block (separate, high-occupancy kernels)
  ln32f<<<gLn, 256, 0, stream>>>(hp, OBS_, zf, CFW_, ng + 1*C_*F_, nb + 1*C_*F_);
  dw_fuse_b<<<gPix, 256, 0, stream>>>(zf, CFW_, c1aw, c1ab, c1bw, c1bb, sf, CFW_);
  ln32f<<<gLn, 256, 0, stream>>>(sf, CFW_, zf, CFW_, ng + 2*C_*F_, nb + 2*C_*F_);
  conv7_add_b<<<gPix, 256, 0, stream>>>(zf, CFW_, c2w, c2b, hp, OBS_);

  // att2 (self on LN3(h))
  ln32T<<<gLn, 256, 0, stream>>>(hp, OBS_, zT, CFW_, ng + 3*C_*F_, nb + 3*C_*F_);
  do_attn(2, zT, 2, zT, 1);

  // att3 (LN4(h) vs skip)
  ln32T<<<gLn, 256, 0, stream>>>(hp, OBS_, zT, CFW_, ng + 4*C_*F_, nb + 4*C_*F_);
  do_attn(3, skT, 3, skT, 1);

  // fused FF (in-place on h)
  ff_ln<<<gLn, 256, 0, stream>>>(hp, ng + 5*C_*F_, nb + 5*C_*F_, w3, w4);

  if (code != 0.f) put_val<<<1, 1, 0, stream>>>(out, code);
}